// Round 1
// baseline (1590.297 us; speedup 1.0000x reference)
//
#include <hip/hip_runtime.h>
#include <hip/hip_bf16.h>
#include <math.h>

// ---------------------------------------------------------------------------
// Sizes (fixed by the reference)
#define B 8
#define NP 1000        // protein length
#define NK 56          // drug vertices
#define DP 768         // prot_data feature
#define DV 43          // drug vertex feature
#define DD 256         // D
#define NT 999         // fused_matrix rows

__device__ inline float fast_tanh(float x) {
    x = fminf(fmaxf(x, -15.f), 15.f);
    float e = __expf(2.f * x);
    return (e - 1.f) / (e + 1.f);
}

// ---------------------------------------------------------------------------
// Tiled f32 GEMM: C[M,N] = act_in(A[M,K]) @ W[K,N] + bias[N]
// BM=BN=64, BK=16, 256 threads, 4x4 micro-tile. M%64==0, N%64==0, K%16==0.
template<bool RELU_IN>
__global__ __launch_bounds__(256) void gemm_bias_kernel(
    const float* __restrict__ A, const float* __restrict__ W,
    const float* __restrict__ bias, float* __restrict__ C,
    int M, int N, int K) {
    const int BM = 64, BN = 64, BK = 16;
    __shared__ float As[BK][BM + 1];
    __shared__ float Bs[BK][BN + 1];
    int bm = blockIdx.x, bn = blockIdx.y;
    int tid = threadIdx.x;
    int tr = tid / 16, tc = tid % 16;
    float acc[4][4] = {};
    int row0 = bm * BM, col0 = bn * BN;
    for (int k0 = 0; k0 < K; k0 += BK) {
        for (int l = tid; l < BM * BK; l += 256) {
            int m = l / BK, kk = l % BK;
            float v = A[(size_t)(row0 + m) * K + k0 + kk];
            if (RELU_IN) v = fmaxf(v, 0.f);
            As[kk][m] = v;
        }
        for (int l = tid; l < BK * BN; l += 256) {
            int kk = l / BN, n = l % BN;
            Bs[kk][n] = W[(size_t)(k0 + kk) * N + col0 + n];
        }
        __syncthreads();
        #pragma unroll
        for (int kk = 0; kk < BK; ++kk) {
            float a[4], b[4];
            #pragma unroll
            for (int i = 0; i < 4; i++) a[i] = As[kk][tr * 4 + i];
            #pragma unroll
            for (int j = 0; j < 4; j++) b[j] = Bs[kk][tc * 4 + j];
            #pragma unroll
            for (int i = 0; i < 4; i++)
                #pragma unroll
                for (int j = 0; j < 4; j++)
                    acc[i][j] = fmaf(a[i], b[j], acc[i][j]);
        }
        __syncthreads();
    }
    #pragma unroll
    for (int i = 0; i < 4; i++)
        #pragma unroll
        for (int j = 0; j < 4; j++) {
            int rr = row0 + tr * 4 + i, cc = col0 + tc * 4 + j;
            C[(size_t)rr * N + cc] = acc[i][j] + bias[cc];
        }
}

// ---------------------------------------------------------------------------
// Small row-matmul: out[r, 0..255] = act_in(in[r, 0..K)) @ W[K,256] + b
template<bool RELU_IN>
__global__ __launch_bounds__(256) void rowmm_kernel(
    const float* __restrict__ in, const float* __restrict__ W,
    const float* __restrict__ bias, float* __restrict__ out, int K) {
    extern __shared__ float srow[];
    int r = blockIdx.x, d = threadIdx.x;
    for (int k = d; k < K; k += 256) {
        float v = in[(size_t)r * K + k];
        if (RELU_IN) v = fmaxf(v, 0.f);
        srow[k] = v;
    }
    __syncthreads();
    float acc = bias[d];
    for (int k = 0; k < K; ++k)
        acc = fmaf(srow[k], W[(size_t)k * DD + d], acc);
    out[(size_t)r * DD + d] = acc;
}

// y[b,i,:] = relu( sum_j adj[b,i,j] * t[b,j,:] )
__global__ __launch_bounds__(256) void adjmul_relu_kernel(
    const float* __restrict__ adj, const float* __restrict__ t,
    float* __restrict__ y) {
    int b = blockIdx.x / NK, i = blockIdx.x % NK, d = threadIdx.x;
    __shared__ float arow[NK];
    if (d < NK) arow[d] = adj[((size_t)b * NK + i) * NK + d];
    __syncthreads();
    float acc = 0.f;
    #pragma unroll 8
    for (int j = 0; j < NK; ++j)
        acc = fmaf(arow[j], t[((size_t)b * NK + j) * DD + d], acc);
    y[((size_t)b * NK + i) * DD + d] = fmaxf(acc, 0.f);
}

// ---------------------------------------------------------------------------
// inter[b,i,k] = sigmoid( qp[b,i,:] . qc[b,k,:] ); atomic add batch sum
__global__ __launch_bounds__(256) void inter_kernel(
    const float* __restrict__ qp, const float* __restrict__ qc,
    float* __restrict__ inter, float* __restrict__ interSum) {
    int b = blockIdx.x / 125, chunk = blockIdx.x % 125;
    __shared__ float qcT[DD * 57];   // [d][k], pad 57
    int tid = threadIdx.x;
    for (int l = tid; l < NK * DD; l += 256) {
        int k = l / DD, d = l % DD;
        qcT[d * 57 + k] = qc[((size_t)b * NK + k) * DD + d];
    }
    __syncthreads();
    int wave = tid >> 6, lane = tid & 63;
    __shared__ float wsum[4];
    float lsum = 0.f;
    for (int ii = 0; ii < 2; ++ii) {
        int i = chunk * 8 + wave * 2 + ii;
        const float* qrow = qp + ((size_t)b * NP + i) * DD;
        if (lane < NK) {
            float acc = 0.f;
            for (int d = 0; d < DD; ++d)
                acc = fmaf(qrow[d], qcT[d * 57 + lane], acc);
            float sg = 1.f / (1.f + __expf(-acc));
            inter[((size_t)b * NP + i) * NK + lane] = sg;
            lsum += sg;
        }
    }
    #pragma unroll
    for (int off = 32; off; off >>= 1) lsum += __shfl_down(lsum, off);
    if (lane == 0) wsum[wave] = lsum;
    __syncthreads();
    if (tid == 0)
        atomicAdd(&interSum[b], wsum[0] + wsum[1] + wsum[2] + wsum[3]);
}

__global__ void normalize_inter_kernel(float* inter, const float* interSum) {
    int idx = blockIdx.x * 256 + threadIdx.x;
    if (idx < B * NP * NK) inter[idx] /= interSum[idx / (NP * NK)];
}

// per-row stats: s[b,i]=sum_k inter^2 ; l1Sum[b]+=sum inter ; bindSum[b]+=sum (inter-lab)^2
__global__ __launch_bounds__(256) void inter_stats_kernel(
    const float* __restrict__ inter, const float* __restrict__ prot_inter,
    const float* __restrict__ exist, float* __restrict__ s_bi,
    float* __restrict__ l1Sum, float* __restrict__ bindSum) {
    int b = blockIdx.x / 4, q = blockIdx.x % 4;
    int i = q * 250 + threadIdx.x;
    float l1 = 0.f, bind = 0.f;
    if (threadIdx.x < 250) {
        float ex = exist[b];
        float ss = 0.f;
        const float* row  = inter      + ((size_t)b * NP + i) * NK;
        const float* prow = prot_inter + ((size_t)b * NP + i) * NK;
        #pragma unroll 8
        for (int k = 0; k < NK; ++k) {
            float v = row[k];
            l1 += v; ss = fmaf(v, v, ss);
            float d = v - ex * prow[k];
            bind = fmaf(d, d, bind);
        }
        s_bi[b * NP + i] = ss;
    }
    __shared__ float r1[256], r2[256];
    r1[threadIdx.x] = l1; r2[threadIdx.x] = bind;
    __syncthreads();
    for (int s = 128; s; s >>= 1) {
        if (threadIdx.x < s) {
            r1[threadIdx.x] += r1[threadIdx.x + s];
            r2[threadIdx.x] += r2[threadIdx.x + s];
        }
        __syncthreads();
    }
    if (threadIdx.x == 0) {
        atomicAdd(&l1Sum[b], r1[0]);
        atomicAdd(&bindSum[b], r2[0]);
    }
}

// ---------------------------------------------------------------------------
// cp partials: part[b][chunk][d] = sum over 25 i's, 56 k's of tanh(prot*comp)*inter
__global__ __launch_bounds__(256) void cp_partial_kernel(
    const float* __restrict__ prot, const float* __restrict__ comp,
    const float* __restrict__ inter, float* __restrict__ part) {
    int b = blockIdx.x / 40, chunk = blockIdx.x % 40;
    int d = threadIdx.x;
    __shared__ float comp_s[NK * DD];   // 57 KB
    __shared__ float irow[NK];
    for (int l = d; l < NK * DD; l += 256)
        comp_s[l] = comp[(size_t)b * NK * DD + l];
    float acc = 0.f;
    for (int ii = 0; ii < 25; ++ii) {
        int i = chunk * 25 + ii;
        __syncthreads();
        if (d < NK) irow[d] = inter[((size_t)b * NP + i) * NK + d];
        __syncthreads();
        float p = prot[((size_t)b * NP + i) * DD + d];
        #pragma unroll 4
        for (int k = 0; k < NK; ++k) {
            float x = p * comp_s[k * DD + d];
            acc = fmaf(fast_tanh(x), irow[k], acc);
        }
    }
    part[((size_t)b * 40 + chunk) * DD + d] = acc;
}

__global__ void cp_reduce_kernel(const float* part, float* cp) {
    int b = blockIdx.x, d = threadIdx.x;
    float s = 0.f;
    for (int c = 0; c < 40; ++c) s += part[((size_t)b * 40 + c) * DD + d];
    cp[b * DD + d] = s;
}

// ---------------------------------------------------------------------------
// conv(k=4,s=2,pad=1) + bias + leaky + maxpool4 -> pooled[b][2048] (layout o*32+p)
__global__ __launch_bounds__(256) void conv_pool_kernel(
    const float* __restrict__ cp, const float* __restrict__ conv_w,
    const float* __restrict__ conv_b, float* __restrict__ pooled) {
    int b = blockIdx.x, t = threadIdx.x;
    __shared__ float x[258];
    __shared__ float convo[64 * 128];
    x[t + 1] = cp[b * DD + t];
    if (t == 0) { x[0] = 0.f; x[257] = 0.f; }
    __syncthreads();
    for (int l = t; l < 64 * 128; l += 256) {
        int o = l / 128, pos = l % 128;
        float acc = conv_b[o];
        int base = pos * 2;
        #pragma unroll
        for (int h = 0; h < 4; ++h)
            acc = fmaf(x[base + h], conv_w[o * 4 + h], acc);
        convo[l] = (acc > 0.f) ? acc : 0.1f * acc;
    }
    __syncthreads();
    for (int l = t; l < 64 * 32; l += 256) {
        int o = l / 32, p = l % 32;
        float m = -INFINITY;
        #pragma unroll
        for (int q = 0; q < 4; ++q)
            m = fmaxf(m, convo[o * 128 + p * 4 + q]);
        pooled[b * 2048 + l] = m;
    }
}

// FC: out[b,o] = act( bias[o] + in[b,:] . W[:,o] ), 64 o's x 8 b per block
template<bool LEAKY>
__global__ __launch_bounds__(256) void fc_kernel(
    const float* __restrict__ in, const float* __restrict__ W,
    const float* __restrict__ bias, float* __restrict__ out, int K, int N) {
    int tid = threadIdx.x;
    int o = blockIdx.x * 64 + (tid & 63);
    int bp = tid >> 6;
    if (o >= N) return;
    for (int rep = 0; rep < 2; ++rep) {
        int b = bp + rep * 4;
        float acc = bias[o];
        for (int k = 0; k < K; ++k)
            acc = fmaf(in[(size_t)b * K + k], W[(size_t)k * N + o], acc);
        if (LEAKY) acc = (acc > 0.f) ? acc : 0.1f * acc;
        out[(size_t)b * N + o] = acc;
    }
}

// ---------------------------------------------------------------------------
// fused regularizer.  fusedT[i][t] (stride NT).
// Partial: per (b, t-chunk64, i-quarter) single wave: acc[j] over 250 i's,
// atomicAdd into F[b][j][t].
__global__ __launch_bounds__(64) void fused_partial_kernel(
    const float* __restrict__ inter, const float* __restrict__ fusedT,
    float* __restrict__ F) {
    int bid = blockIdx.x;
    int b = bid / 64; int rem = bid % 64;
    int tc = rem / 4, iq = rem % 4;
    int lane = threadIdx.x;
    int t = tc * 64 + lane;
    bool tvalid = (t < NT);
    __shared__ float irow[NK];
    float acc[NK];
    #pragma unroll
    for (int j = 0; j < NK; ++j) acc[j] = 0.f;
    for (int i = iq * 250; i < iq * 250 + 250; ++i) {
        if (lane < NK) irow[lane] = inter[((size_t)b * NP + i) * NK + lane];
        __syncthreads();
        float fv = tvalid ? fusedT[(size_t)i * NT + t] : 0.f;
        #pragma unroll
        for (int j0 = 0; j0 < NK; j0 += 4) {
            float4 iv = *reinterpret_cast<const float4*>(&irow[j0]);
            acc[j0 + 0] = fmaf(fv, iv.x, acc[j0 + 0]);
            acc[j0 + 1] = fmaf(fv, iv.y, acc[j0 + 1]);
            acc[j0 + 2] = fmaf(fv, iv.z, acc[j0 + 2]);
            acc[j0 + 3] = fmaf(fv, iv.w, acc[j0 + 3]);
        }
        __syncthreads();
    }
    if (tvalid) {
        #pragma unroll
        for (int j = 0; j < NK; ++j)
            atomicAdd(&F[((size_t)b * NK + j) * NT + t], acc[j]);
    }
}

__global__ __launch_bounds__(256) void fused_abs_kernel(
    const float* __restrict__ F, float* __restrict__ fusedAbs) {
    int b = blockIdx.x;
    float s = 0.f;
    for (int l = threadIdx.x; l < NK * NT; l += 256)
        s += fabsf(F[(size_t)b * NK * NT + l]);
    __shared__ float r[256];
    r[threadIdx.x] = s;
    __syncthreads();
    for (int st = 128; st; st >>= 1) {
        if (threadIdx.x < st) r[threadIdx.x] += r[threadIdx.x + st];
        __syncthreads();
    }
    if (threadIdx.x == 0) fusedAbs[b] = r[0];
}

__global__ void transpose_fused_kernel(const float* __restrict__ src,
                                       float* __restrict__ dst) {
    __shared__ float tile[32][33];
    int tb = blockIdx.x % 32;
    int ib = blockIdx.x / 32;
    int tx = threadIdx.x % 32, ty = threadIdx.x / 32;
    for (int r = ty; r < 32; r += 8) {
        int t = tb * 32 + r, i = ib * 32 + tx;
        tile[r][tx] = (t < NT && i < NP) ? src[(size_t)t * NP + i] : 0.f;
    }
    __syncthreads();
    for (int r = ty; r < 32; r += 8) {
        int i = ib * 32 + r, t = tb * 32 + tx;
        if (i < NP && t < NT) dst[(size_t)i * NT + t] = tile[tx][r];
    }
}

// ---------------------------------------------------------------------------
// group: one wave per (b,k): g = contacts[b,k,:] . s[b,:], rs = row sum
__global__ __launch_bounds__(64) void group_kernel(
    const float* __restrict__ contacts, const float* __restrict__ s_bi,
    float* __restrict__ group_val) {
    int bk = blockIdx.x;
    int b = bk / NP, k = bk % NP;
    const float* row = contacts + ((size_t)b * NP + k) * NP;
    const float* sv = s_bi + b * NP;
    float g = 0.f, rs = 0.f;
    for (int i = threadIdx.x; i < NP; i += 64) {
        float c = row[i];
        g = fmaf(c, sv[i], g);
        rs += c;
    }
    #pragma unroll
    for (int off = 32; off; off >>= 1) {
        g += __shfl_down(g, off);
        rs += __shfl_down(rs, off);
    }
    if (threadIdx.x == 0) {
        if (g == 0.f) g += 1e10f;
        group_val[bk] = sqrtf(g) * sqrtf(rs);
    }
}

__global__ __launch_bounds__(256) void reduce1000_kernel(const float* in, float* out) {
    int b = blockIdx.x;
    float s = 0.f;
    for (int l = threadIdx.x; l < NP; l += 256) s += in[b * NP + l];
    __shared__ float r[256];
    r[threadIdx.x] = s;
    __syncthreads();
    for (int st = 128; st; st >>= 1) {
        if (threadIdx.x < st) r[threadIdx.x] += r[threadIdx.x + st];
        __syncthreads();
    }
    if (threadIdx.x == 0) out[b] = r[0];
}

// accums layout: [0..8)=interSum [8..16)=l1Sum [16..24)=bindSum [24..32)=fusedAbs [32..40)=groupReg
__global__ void final_kernel(const float* __restrict__ accums,
                             const float* __restrict__ affn,
                             const float* __restrict__ label,
                             float* __restrict__ out) {
    if (threadIdx.x == 0 && blockIdx.x == 0) {
        float l0 = 0.f, l1 = 0.f, l2 = 0.f;
        for (int b = 0; b < B; ++b) {
            l0 += accums[8 + b] + accums[24 + b] + accums[32 + b];
            l1 += sqrtf(accums[16 + b]);
            float d = affn[b] - label[b];
            l2 += d * d;
        }
        out[0] = (l0 + l1 + l2) * 0.125f;
    }
}

// ---------------------------------------------------------------------------
extern "C" void kernel_launch(void* const* d_in, const int* in_sizes, int n_in,
                              void* d_out, int out_size, void* d_ws, size_t ws_size,
                              hipStream_t stream) {
    const float* prot_data   = (const float*)d_in[0];
    const float* drug_ver    = (const float*)d_in[1];
    const float* drug_adj    = (const float*)d_in[2];
    const float* contacts    = (const float*)d_in[3];
    const float* prot_inter  = (const float*)d_in[4];
    const float* exist       = (const float*)d_in[5];
    const float* label       = (const float*)d_in[6];
    const float* fused       = (const float*)d_in[7];
    const float* W_prot      = (const float*)d_in[8];
    const float* b_prot      = (const float*)d_in[9];
    const float* gcn_W0      = (const float*)d_in[10];
    const float* gcn_b0      = (const float*)d_in[11];
    const float* gcn_W1      = (const float*)d_in[12];
    const float* gcn_b1      = (const float*)d_in[13];
    const float* gcn_W2      = (const float*)d_in[14];
    const float* gcn_b2      = (const float*)d_in[15];
    const float* gcn_Wf      = (const float*)d_in[16];
    const float* gcn_bf      = (const float*)d_in[17];
    const float* Wjp         = (const float*)d_in[18];
    const float* bjp         = (const float*)d_in[19];
    const float* Wjc         = (const float*)d_in[20];
    const float* bjc         = (const float*)d_in[21];
    const float* conv_w      = (const float*)d_in[22];
    const float* conv_b      = (const float*)d_in[23];
    const float* W_r1        = (const float*)d_in[24];
    const float* b_r1        = (const float*)d_in[25];
    const float* W_r2        = (const float*)d_in[26];
    const float* b_r2        = (const float*)d_in[27];
    const float* W_r3        = (const float*)d_in[28];
    const float* b_r3        = (const float*)d_in[29];

    float* ws = (float*)d_ws;
    size_t off = 0;
    auto alloc = [&](size_t n) { float* p = ws + off; off += n; return p; };
    float* prot     = alloc((size_t)B * NP * DD);   // 2,048,000
    float* qp       = alloc((size_t)B * NP * DD);   // 2,048,000
    float* tbuf     = alloc((size_t)B * NK * DD);
    float* ybuf     = alloc((size_t)B * NK * DD);
    float* comp     = alloc((size_t)B * NK * DD);
    float* qc       = alloc((size_t)B * NK * DD);
    float* inter    = alloc((size_t)B * NP * NK);   // 448,000
    float* s_bi     = alloc((size_t)B * NP);
    float* cp_part  = alloc((size_t)B * 40 * DD);
    float* cp       = alloc((size_t)B * DD);
    float* pooled   = alloc((size_t)B * 2048);
    float* fc1      = alloc((size_t)B * 600);
    float* fc2      = alloc((size_t)B * 300);
    float* affn     = alloc((size_t)B);
    float* groupv   = alloc((size_t)B * NP);
    float* fusedT   = alloc((size_t)NP * NT);       // 999,000
    float* F        = alloc((size_t)B * NK * NT);   // 447,552
    float* accums   = alloc(40);                    // contiguous with F

    // zero the atomic-accumulated buffers (F + accums are contiguous)
    hipMemsetAsync(F, 0, ((size_t)B * NK * NT + 40) * sizeof(float), stream);

    // fused matrix transpose (independent)
    transpose_fused_kernel<<<1024, 256, 0, stream>>>(fused, fusedT);

    // prot = prot_data @ W_prot + b_prot
    gemm_bias_kernel<false><<<dim3(125, 4), 256, 0, stream>>>(
        prot_data, W_prot, b_prot, prot, B * NP, DD, DP);

    // GCN stack
    rowmm_kernel<false><<<B * NK, 256, DV * sizeof(float), stream>>>(drug_ver, gcn_W0, gcn_b0, tbuf, DV);
    adjmul_relu_kernel<<<B * NK, 256, 0, stream>>>(drug_adj, tbuf, ybuf);
    rowmm_kernel<false><<<B * NK, 256, DD * sizeof(float), stream>>>(ybuf, gcn_W1, gcn_b1, tbuf, DD);
    adjmul_relu_kernel<<<B * NK, 256, 0, stream>>>(drug_adj, tbuf, ybuf);
    rowmm_kernel<false><<<B * NK, 256, DD * sizeof(float), stream>>>(ybuf, gcn_W2, gcn_b2, tbuf, DD);
    adjmul_relu_kernel<<<B * NK, 256, 0, stream>>>(drug_adj, tbuf, ybuf);
    rowmm_kernel<false><<<B * NK, 256, DD * sizeof(float), stream>>>(ybuf, gcn_Wf, gcn_bf, comp, DD);
    rowmm_kernel<true ><<<B * NK, 256, DD * sizeof(float), stream>>>(comp, Wjc, bjc, qc, DD);

    // qp = relu(prot) @ Wjp + bjp
    gemm_bias_kernel<true><<<dim3(125, 4), 256, 0, stream>>>(
        prot, Wjp, bjp, qp, B * NP, DD, DD);

    // inter + normalization
    inter_kernel<<<B * 125, 256, 0, stream>>>(qp, qc, inter, accums + 0);
    normalize_inter_kernel<<<(B * NP * NK + 255) / 256, 256, 0, stream>>>(inter, accums + 0);
    inter_stats_kernel<<<B * 4, 256, 0, stream>>>(inter, prot_inter, exist, s_bi,
                                                  accums + 8, accums + 16);

    // cp contraction
    cp_partial_kernel<<<B * 40, 256, 0, stream>>>(prot, comp, inter, cp_part);
    cp_reduce_kernel<<<B, 256, 0, stream>>>(cp_part, cp);

    // conv / pool / FCs
    conv_pool_kernel<<<B, 256, 0, stream>>>(cp, conv_w, conv_b, pooled);
    fc_kernel<true ><<<10, 256, 0, stream>>>(pooled, W_r1, b_r1, fc1, 2048, 600);
    fc_kernel<true ><<< 5, 256, 0, stream>>>(fc1, W_r2, b_r2, fc2, 600, 300);
    fc_kernel<false><<< 1, 256, 0, stream>>>(fc2, W_r3, b_r3, affn, 300, 1);

    // fused regularizer
    fused_partial_kernel<<<B * 64, 64, 0, stream>>>(inter, fusedT, F);
    fused_abs_kernel<<<B, 256, 0, stream>>>(F, accums + 24);

    // group regularizer
    group_kernel<<<B * NP, 64, 0, stream>>>(contacts, s_bi, groupv);
    reduce1000_kernel<<<B, 256, 0, stream>>>(groupv, accums + 32);

    // final loss
    final_kernel<<<1, 64, 0, stream>>>(accums, affn, label, (float*)d_out);
}

// Round 2
// 876.038 us; speedup vs baseline: 1.8153x; 1.8153x over previous
//
#include <hip/hip_runtime.h>
#include <hip/hip_bf16.h>
#include <math.h>

// ---------------------------------------------------------------------------
// Sizes (fixed by the reference)
#define B 8
#define NP 1000        // protein length
#define NK 56          // drug vertices
#define DP 768         // prot_data feature
#define DV 43          // drug vertex feature
#define DD 256         // D
#define NT 999         // fused_matrix rows

__device__ inline float fast_tanh(float x) {
    x = fminf(fmaxf(x, -15.f), 15.f);
    float e = __expf(2.f * x);
    return (e - 1.f) / (e + 1.f);
}

// ---------------------------------------------------------------------------
// Tiled f32 GEMM: C[M,N] = act_in(A[M,K]) @ W[K,N] + bias[N]
// BM=BN=64, BK=16, 256 threads, 4x4 micro-tile. M%64==0, N%64==0, K%16==0.
template<bool RELU_IN>
__global__ __launch_bounds__(256) void gemm_bias_kernel(
    const float* __restrict__ A, const float* __restrict__ W,
    const float* __restrict__ bias, float* __restrict__ C,
    int M, int N, int K) {
    const int BM = 64, BN = 64, BK = 16;
    __shared__ float As[BK][BM + 1];
    __shared__ float Bs[BK][BN + 1];
    int bm = blockIdx.x, bn = blockIdx.y;
    int tid = threadIdx.x;
    int tr = tid / 16, tc = tid % 16;
    float acc[4][4] = {};
    int row0 = bm * BM, col0 = bn * BN;
    for (int k0 = 0; k0 < K; k0 += BK) {
        for (int l = tid; l < BM * BK; l += 256) {
            int m = l / BK, kk = l % BK;
            float v = A[(size_t)(row0 + m) * K + k0 + kk];
            if (RELU_IN) v = fmaxf(v, 0.f);
            As[kk][m] = v;
        }
        for (int l = tid; l < BK * BN; l += 256) {
            int kk = l / BN, n = l % BN;
            Bs[kk][n] = W[(size_t)(k0 + kk) * N + col0 + n];
        }
        __syncthreads();
        #pragma unroll
        for (int kk = 0; kk < BK; ++kk) {
            float a[4], b[4];
            #pragma unroll
            for (int i = 0; i < 4; i++) a[i] = As[kk][tr * 4 + i];
            #pragma unroll
            for (int j = 0; j < 4; j++) b[j] = Bs[kk][tc * 4 + j];
            #pragma unroll
            for (int i = 0; i < 4; i++)
                #pragma unroll
                for (int j = 0; j < 4; j++)
                    acc[i][j] = fmaf(a[i], b[j], acc[i][j]);
        }
        __syncthreads();
    }
    #pragma unroll
    for (int i = 0; i < 4; i++)
        #pragma unroll
        for (int j = 0; j < 4; j++) {
            int rr = row0 + tr * 4 + i, cc = col0 + tc * 4 + j;
            C[(size_t)rr * N + cc] = acc[i][j] + bias[cc];
        }
}

// ---------------------------------------------------------------------------
// Small row-matmul: out[r, 0..255] = act_in(in[r, 0..K)) @ W[K,256] + b
template<bool RELU_IN>
__global__ __launch_bounds__(256) void rowmm_kernel(
    const float* __restrict__ in, const float* __restrict__ W,
    const float* __restrict__ bias, float* __restrict__ out, int K) {
    extern __shared__ float srow[];
    int r = blockIdx.x, d = threadIdx.x;
    for (int k = d; k < K; k += 256) {
        float v = in[(size_t)r * K + k];
        if (RELU_IN) v = fmaxf(v, 0.f);
        srow[k] = v;
    }
    __syncthreads();
    float acc = bias[d];
    for (int k = 0; k < K; ++k)
        acc = fmaf(srow[k], W[(size_t)k * DD + d], acc);
    out[(size_t)r * DD + d] = acc;
}

// y[b,i,:] = relu( sum_j adj[b,i,j] * t[b,j,:] )
__global__ __launch_bounds__(256) void adjmul_relu_kernel(
    const float* __restrict__ adj, const float* __restrict__ t,
    float* __restrict__ y) {
    int b = blockIdx.x / NK, i = blockIdx.x % NK, d = threadIdx.x;
    __shared__ float arow[NK];
    if (d < NK) arow[d] = adj[((size_t)b * NK + i) * NK + d];
    __syncthreads();
    float acc = 0.f;
    #pragma unroll 8
    for (int j = 0; j < NK; ++j)
        acc = fmaf(arow[j], t[((size_t)b * NK + j) * DD + d], acc);
    y[((size_t)b * NK + i) * DD + d] = fmaxf(acc, 0.f);
}

// ---------------------------------------------------------------------------
// inter[b,i,k] = sigmoid( qp[b,i,:] . qc[b,k,:] ); atomic add batch sum
__global__ __launch_bounds__(256) void inter_kernel(
    const float* __restrict__ qp, const float* __restrict__ qc,
    float* __restrict__ inter, float* __restrict__ interSum) {
    int b = blockIdx.x / 125, chunk = blockIdx.x % 125;
    __shared__ float qcT[DD * 57];   // [d][k], pad 57
    int tid = threadIdx.x;
    for (int l = tid; l < NK * DD; l += 256) {
        int k = l / DD, d = l % DD;
        qcT[d * 57 + k] = qc[((size_t)b * NK + k) * DD + d];
    }
    __syncthreads();
    int wave = tid >> 6, lane = tid & 63;
    __shared__ float wsum[4];
    float lsum = 0.f;
    for (int ii = 0; ii < 2; ++ii) {
        int i = chunk * 8 + wave * 2 + ii;
        const float* qrow = qp + ((size_t)b * NP + i) * DD;
        if (lane < NK) {
            float acc = 0.f;
            for (int d = 0; d < DD; ++d)
                acc = fmaf(qrow[d], qcT[d * 57 + lane], acc);
            float sg = 1.f / (1.f + __expf(-acc));
            inter[((size_t)b * NP + i) * NK + lane] = sg;
            lsum += sg;
        }
    }
    #pragma unroll
    for (int off = 32; off; off >>= 1) lsum += __shfl_down(lsum, off);
    if (lane == 0) wsum[wave] = lsum;
    __syncthreads();
    if (tid == 0)
        atomicAdd(&interSum[b], wsum[0] + wsum[1] + wsum[2] + wsum[3]);
}

__global__ void normalize_inter_kernel(float* inter, const float* interSum) {
    int idx = blockIdx.x * 256 + threadIdx.x;
    if (idx < B * NP * NK) inter[idx] /= interSum[idx / (NP * NK)];
}

// per-row stats: s[b,i]=sum_k inter^2 ; l1Sum[b]+=sum inter ; bindSum[b]+=sum (inter-lab)^2
__global__ __launch_bounds__(256) void inter_stats_kernel(
    const float* __restrict__ inter, const float* __restrict__ prot_inter,
    const float* __restrict__ exist, float* __restrict__ s_bi,
    float* __restrict__ l1Sum, float* __restrict__ bindSum) {
    int b = blockIdx.x / 4, q = blockIdx.x % 4;
    int i = q * 250 + threadIdx.x;
    float l1 = 0.f, bind = 0.f;
    if (threadIdx.x < 250) {
        float ex = exist[b];
        float ss = 0.f;
        const float* row  = inter      + ((size_t)b * NP + i) * NK;
        const float* prow = prot_inter + ((size_t)b * NP + i) * NK;
        #pragma unroll 8
        for (int k = 0; k < NK; ++k) {
            float v = row[k];
            l1 += v; ss = fmaf(v, v, ss);
            float d = v - ex * prow[k];
            bind = fmaf(d, d, bind);
        }
        s_bi[b * NP + i] = ss;
    }
    __shared__ float r1[256], r2[256];
    r1[threadIdx.x] = l1; r2[threadIdx.x] = bind;
    __syncthreads();
    for (int s = 128; s; s >>= 1) {
        if (threadIdx.x < s) {
            r1[threadIdx.x] += r1[threadIdx.x + s];
            r2[threadIdx.x] += r2[threadIdx.x + s];
        }
        __syncthreads();
    }
    if (threadIdx.x == 0) {
        atomicAdd(&l1Sum[b], r1[0]);
        atomicAdd(&bindSum[b], r2[0]);
    }
}

// ---------------------------------------------------------------------------
// cp partials: part[b][chunk][d] = sum over 25 i's, 56 k's of tanh(prot*comp)*inter
__global__ __launch_bounds__(256) void cp_partial_kernel(
    const float* __restrict__ prot, const float* __restrict__ comp,
    const float* __restrict__ inter, float* __restrict__ part) {
    int b = blockIdx.x / 40, chunk = blockIdx.x % 40;
    int d = threadIdx.x;
    __shared__ float comp_s[NK * DD];   // 57 KB
    __shared__ float irow[NK];
    for (int l = d; l < NK * DD; l += 256)
        comp_s[l] = comp[(size_t)b * NK * DD + l];
    float acc = 0.f;
    for (int ii = 0; ii < 25; ++ii) {
        int i = chunk * 25 + ii;
        __syncthreads();
        if (d < NK) irow[d] = inter[((size_t)b * NP + i) * NK + d];
        __syncthreads();
        float p = prot[((size_t)b * NP + i) * DD + d];
        #pragma unroll 4
        for (int k = 0; k < NK; ++k) {
            float x = p * comp_s[k * DD + d];
            acc = fmaf(fast_tanh(x), irow[k], acc);
        }
    }
    part[((size_t)b * 40 + chunk) * DD + d] = acc;
}

__global__ void cp_reduce_kernel(const float* part, float* cp) {
    int b = blockIdx.x, d = threadIdx.x;
    float s = 0.f;
    for (int c = 0; c < 40; ++c) s += part[((size_t)b * 40 + c) * DD + d];
    cp[b * DD + d] = s;
}

// ---------------------------------------------------------------------------
// conv(k=4,s=2,pad=1) + bias + leaky + maxpool4 -> pooled[b][2048] (layout o*32+p)
__global__ __launch_bounds__(256) void conv_pool_kernel(
    const float* __restrict__ cp, const float* __restrict__ conv_w,
    const float* __restrict__ conv_b, float* __restrict__ pooled) {
    int b = blockIdx.x, t = threadIdx.x;
    __shared__ float x[258];
    __shared__ float convo[64 * 128];
    x[t + 1] = cp[b * DD + t];
    if (t == 0) { x[0] = 0.f; x[257] = 0.f; }
    __syncthreads();
    for (int l = t; l < 64 * 128; l += 256) {
        int o = l / 128, pos = l % 128;
        float acc = conv_b[o];
        int base = pos * 2;
        #pragma unroll
        for (int h = 0; h < 4; ++h)
            acc = fmaf(x[base + h], conv_w[o * 4 + h], acc);
        convo[l] = (acc > 0.f) ? acc : 0.1f * acc;
    }
    __syncthreads();
    for (int l = t; l < 64 * 32; l += 256) {
        int o = l / 32, p = l % 32;
        float m = -INFINITY;
        #pragma unroll
        for (int q = 0; q < 4; ++q)
            m = fmaxf(m, convo[o * 128 + p * 4 + q]);
        pooled[b * 2048 + l] = m;
    }
}

// ---------------------------------------------------------------------------
// FC tile kernel: out[b, o] = act( bias[o] + sum_k in[b,k] * W[k,o] )
// 64 outputs per block (coalesced W rows), 4 waves split K, 8 batch
// accumulators per thread (independent FMA chains), LDS reduce.
template<bool LEAKY>
__global__ __launch_bounds__(256) void fc_tile_kernel(
    const float* __restrict__ in, const float* __restrict__ W,
    const float* __restrict__ bias, float* __restrict__ out, int K, int N) {
    int t = threadIdx.x;
    int ol = t & 63;
    int o = blockIdx.x * 64 + ol;
    int oc = (o < N) ? o : (N - 1);       // clamp for safe loads
    int w = t >> 6;                        // wave id 0..3
    int kb = (K + 3) / 4;
    int k0 = w * kb, k1 = (k0 + kb < K) ? (k0 + kb) : K;
    float acc[B];
    #pragma unroll
    for (int b = 0; b < B; ++b) acc[b] = 0.f;
    for (int k = k0; k < k1; ++k) {
        float wv = W[(size_t)k * N + oc];
        #pragma unroll
        for (int b = 0; b < B; ++b)
            acc[b] = fmaf(in[(size_t)b * K + k], wv, acc[b]);
    }
    __shared__ float red[4][64][B];
    #pragma unroll
    for (int b = 0; b < B; ++b) red[w][ol][b] = acc[b];
    __syncthreads();
    for (int p = t; p < 64 * B; p += 256) {
        int oo = p / B, b = p % B;
        int o2 = blockIdx.x * 64 + oo;
        if (o2 < N) {
            float s = red[0][oo][b] + red[1][oo][b] + red[2][oo][b] + red[3][oo][b]
                    + bias[o2];
            if (LEAKY) s = (s > 0.f) ? s : 0.1f * s;
            out[(size_t)b * N + o2] = s;
        }
    }
}

// ---------------------------------------------------------------------------
// fused regularizer.  fusedT[i][t] (stride NT).
// Partial: per (b, t-chunk64, i-quarter) single wave: acc[j] over 250 i's,
// atomicAdd into F[b][j][t].
__global__ __launch_bounds__(64) void fused_partial_kernel(
    const float* __restrict__ inter, const float* __restrict__ fusedT,
    float* __restrict__ F) {
    int bid = blockIdx.x;
    int b = bid / 64; int rem = bid % 64;
    int tc = rem / 4, iq = rem % 4;
    int lane = threadIdx.x;
    int t = tc * 64 + lane;
    bool tvalid = (t < NT);
    __shared__ float irow[NK];
    float acc[NK];
    #pragma unroll
    for (int j = 0; j < NK; ++j) acc[j] = 0.f;
    for (int i = iq * 250; i < iq * 250 + 250; ++i) {
        if (lane < NK) irow[lane] = inter[((size_t)b * NP + i) * NK + lane];
        __syncthreads();
        float fv = tvalid ? fusedT[(size_t)i * NT + t] : 0.f;
        #pragma unroll
        for (int j0 = 0; j0 < NK; j0 += 4) {
            float4 iv = *reinterpret_cast<const float4*>(&irow[j0]);
            acc[j0 + 0] = fmaf(fv, iv.x, acc[j0 + 0]);
            acc[j0 + 1] = fmaf(fv, iv.y, acc[j0 + 1]);
            acc[j0 + 2] = fmaf(fv, iv.z, acc[j0 + 2]);
            acc[j0 + 3] = fmaf(fv, iv.w, acc[j0 + 3]);
        }
        __syncthreads();
    }
    if (tvalid) {
        #pragma unroll
        for (int j = 0; j < NK; ++j)
            atomicAdd(&F[((size_t)b * NK + j) * NT + t], acc[j]);
    }
}

__global__ __launch_bounds__(256) void fused_abs_kernel(
    const float* __restrict__ F, float* __restrict__ fusedAbs) {
    int b = blockIdx.x;
    float s = 0.f;
    for (int l = threadIdx.x; l < NK * NT; l += 256)
        s += fabsf(F[(size_t)b * NK * NT + l]);
    __shared__ float r[256];
    r[threadIdx.x] = s;
    __syncthreads();
    for (int st = 128; st; st >>= 1) {
        if (threadIdx.x < st) r[threadIdx.x] += r[threadIdx.x + st];
        __syncthreads();
    }
    if (threadIdx.x == 0) fusedAbs[b] = r[0];
}

__global__ void transpose_fused_kernel(const float* __restrict__ src,
                                       float* __restrict__ dst) {
    __shared__ float tile[32][33];
    int tb = blockIdx.x % 32;
    int ib = blockIdx.x / 32;
    int tx = threadIdx.x % 32, ty = threadIdx.x / 32;
    for (int r = ty; r < 32; r += 8) {
        int t = tb * 32 + r, i = ib * 32 + tx;
        tile[r][tx] = (t < NT && i < NP) ? src[(size_t)t * NP + i] : 0.f;
    }
    __syncthreads();
    for (int r = ty; r < 32; r += 8) {
        int i = ib * 32 + r, t = tb * 32 + tx;
        if (i < NP && t < NT) dst[(size_t)i * NT + t] = tile[tx][r];
    }
}

// ---------------------------------------------------------------------------
// group: one wave per (b,k): g = contacts[b,k,:] . s[b,:], rs = row sum
__global__ __launch_bounds__(64) void group_kernel(
    const float* __restrict__ contacts, const float* __restrict__ s_bi,
    float* __restrict__ group_val) {
    int bk = blockIdx.x;
    int b = bk / NP, k = bk % NP;
    const float* row = contacts + ((size_t)b * NP + k) * NP;
    const float* sv = s_bi + b * NP;
    float g = 0.f, rs = 0.f;
    for (int i = threadIdx.x; i < NP; i += 64) {
        float c = row[i];
        g = fmaf(c, sv[i], g);
        rs += c;
    }
    #pragma unroll
    for (int off = 32; off; off >>= 1) {
        g += __shfl_down(g, off);
        rs += __shfl_down(rs, off);
    }
    if (threadIdx.x == 0) {
        if (g == 0.f) g += 1e10f;
        group_val[bk] = sqrtf(g) * sqrtf(rs);
    }
}

__global__ __launch_bounds__(256) void reduce1000_kernel(const float* in, float* out) {
    int b = blockIdx.x;
    float s = 0.f;
    for (int l = threadIdx.x; l < NP; l += 256) s += in[b * NP + l];
    __shared__ float r[256];
    r[threadIdx.x] = s;
    __syncthreads();
    for (int st = 128; st; st >>= 1) {
        if (threadIdx.x < st) r[threadIdx.x] += r[threadIdx.x + st];
        __syncthreads();
    }
    if (threadIdx.x == 0) out[b] = r[0];
}

// accums layout: [0..8)=interSum [8..16)=l1Sum [16..24)=bindSum [24..32)=fusedAbs [32..40)=groupReg
__global__ void final_kernel(const float* __restrict__ accums,
                             const float* __restrict__ affn,
                             const float* __restrict__ label,
                             float* __restrict__ out) {
    if (threadIdx.x == 0 && blockIdx.x == 0) {
        float l0 = 0.f, l1 = 0.f, l2 = 0.f;
        for (int b = 0; b < B; ++b) {
            l0 += accums[8 + b] + accums[24 + b] + accums[32 + b];
            l1 += sqrtf(accums[16 + b]);
            float d = affn[b] - label[b];
            l2 += d * d;
        }
        out[0] = (l0 + l1 + l2) * 0.125f;
    }
}

// ---------------------------------------------------------------------------
extern "C" void kernel_launch(void* const* d_in, const int* in_sizes, int n_in,
                              void* d_out, int out_size, void* d_ws, size_t ws_size,
                              hipStream_t stream) {
    const float* prot_data   = (const float*)d_in[0];
    const float* drug_ver    = (const float*)d_in[1];
    const float* drug_adj    = (const float*)d_in[2];
    const float* contacts    = (const float*)d_in[3];
    const float* prot_inter  = (const float*)d_in[4];
    const float* exist       = (const float*)d_in[5];
    const float* label       = (const float*)d_in[6];
    const float* fused       = (const float*)d_in[7];
    const float* W_prot      = (const float*)d_in[8];
    const float* b_prot      = (const float*)d_in[9];
    const float* gcn_W0      = (const float*)d_in[10];
    const float* gcn_b0      = (const float*)d_in[11];
    const float* gcn_W1      = (const float*)d_in[12];
    const float* gcn_b1      = (const float*)d_in[13];
    const float* gcn_W2      = (const float*)d_in[14];
    const float* gcn_b2      = (const float*)d_in[15];
    const float* gcn_Wf      = (const float*)d_in[16];
    const float* gcn_bf      = (const float*)d_in[17];
    const float* Wjp         = (const float*)d_in[18];
    const float* bjp         = (const float*)d_in[19];
    const float* Wjc         = (const float*)d_in[20];
    const float* bjc         = (const float*)d_in[21];
    const float* conv_w      = (const float*)d_in[22];
    const float* conv_b      = (const float*)d_in[23];
    const float* W_r1        = (const float*)d_in[24];
    const float* b_r1        = (const float*)d_in[25];
    const float* W_r2        = (const float*)d_in[26];
    const float* b_r2        = (const float*)d_in[27];
    const float* W_r3        = (const float*)d_in[28];
    const float* b_r3        = (const float*)d_in[29];

    float* ws = (float*)d_ws;
    size_t off = 0;
    auto alloc = [&](size_t n) { float* p = ws + off; off += n; return p; };
    float* prot     = alloc((size_t)B * NP * DD);   // 2,048,000
    float* qp       = alloc((size_t)B * NP * DD);   // 2,048,000
    float* tbuf     = alloc((size_t)B * NK * DD);
    float* ybuf     = alloc((size_t)B * NK * DD);
    float* comp     = alloc((size_t)B * NK * DD);
    float* qc       = alloc((size_t)B * NK * DD);
    float* inter    = alloc((size_t)B * NP * NK);   // 448,000
    float* s_bi     = alloc((size_t)B * NP);
    float* cp_part  = alloc((size_t)B * 40 * DD);
    float* cp       = alloc((size_t)B * DD);
    float* pooled   = alloc((size_t)B * 2048);
    float* fc1      = alloc((size_t)B * 600);
    float* fc2      = alloc((size_t)B * 300);
    float* affn     = alloc((size_t)B);
    float* groupv   = alloc((size_t)B * NP);
    float* fusedT   = alloc((size_t)NP * NT);       // 999,000
    float* F        = alloc((size_t)B * NK * NT);   // 447,552
    float* accums   = alloc(40);                    // contiguous with F

    // zero the atomic-accumulated buffers (F + accums are contiguous)
    hipMemsetAsync(F, 0, ((size_t)B * NK * NT + 40) * sizeof(float), stream);

    // fused matrix transpose (independent)
    transpose_fused_kernel<<<1024, 256, 0, stream>>>(fused, fusedT);

    // prot = prot_data @ W_prot + b_prot
    gemm_bias_kernel<false><<<dim3(125, 4), 256, 0, stream>>>(
        prot_data, W_prot, b_prot, prot, B * NP, DD, DP);

    // GCN stack
    rowmm_kernel<false><<<B * NK, 256, DV * sizeof(float), stream>>>(drug_ver, gcn_W0, gcn_b0, tbuf, DV);
    adjmul_relu_kernel<<<B * NK, 256, 0, stream>>>(drug_adj, tbuf, ybuf);
    rowmm_kernel<false><<<B * NK, 256, DD * sizeof(float), stream>>>(ybuf, gcn_W1, gcn_b1, tbuf, DD);
    adjmul_relu_kernel<<<B * NK, 256, 0, stream>>>(drug_adj, tbuf, ybuf);
    rowmm_kernel<false><<<B * NK, 256, DD * sizeof(float), stream>>>(ybuf, gcn_W2, gcn_b2, tbuf, DD);
    adjmul_relu_kernel<<<B * NK, 256, 0, stream>>>(drug_adj, tbuf, ybuf);
    rowmm_kernel<false><<<B * NK, 256, DD * sizeof(float), stream>>>(ybuf, gcn_Wf, gcn_bf, comp, DD);
    rowmm_kernel<true ><<<B * NK, 256, DD * sizeof(float), stream>>>(comp, Wjc, bjc, qc, DD);

    // qp = relu(prot) @ Wjp + bjp
    gemm_bias_kernel<true><<<dim3(125, 4), 256, 0, stream>>>(
        prot, Wjp, bjp, qp, B * NP, DD, DD);

    // inter + normalization
    inter_kernel<<<B * 125, 256, 0, stream>>>(qp, qc, inter, accums + 0);
    normalize_inter_kernel<<<(B * NP * NK + 255) / 256, 256, 0, stream>>>(inter, accums + 0);
    inter_stats_kernel<<<B * 4, 256, 0, stream>>>(inter, prot_inter, exist, s_bi,
                                                  accums + 8, accums + 16);

    // cp contraction
    cp_partial_kernel<<<B * 40, 256, 0, stream>>>(prot, comp, inter, cp_part);
    cp_reduce_kernel<<<B, 256, 0, stream>>>(cp_part, cp);

    // conv / pool / FCs
    conv_pool_kernel<<<B, 256, 0, stream>>>(cp, conv_w, conv_b, pooled);
    fc_tile_kernel<true ><<<10, 256, 0, stream>>>(pooled, W_r1, b_r1, fc1, 2048, 600);
    fc_tile_kernel<true ><<< 5, 256, 0, stream>>>(fc1, W_r2, b_r2, fc2, 600, 300);
    fc_tile_kernel<false><<< 1, 256, 0, stream>>>(fc2, W_r3, b_r3, affn, 300, 1);

    // fused regularizer
    fused_partial_kernel<<<B * 64, 64, 0, stream>>>(inter, fusedT, F);
    fused_abs_kernel<<<B, 256, 0, stream>>>(F, accums + 24);

    // group regularizer
    group_kernel<<<B * NP, 64, 0, stream>>>(contacts, s_bi, groupv);
    reduce1000_kernel<<<B, 256, 0, stream>>>(groupv, accums + 32);

    // final loss
    final_kernel<<<1, 64, 0, stream>>>(accums, affn, label, (float*)d_out);
}

// Round 3
// 654.327 us; speedup vs baseline: 2.4304x; 1.3388x over previous
//
#include <hip/hip_runtime.h>
#include <hip/hip_bf16.h>
#include <math.h>

// ---------------------------------------------------------------------------
// Sizes (fixed by the reference)
#define B 8
#define NP 1000        // protein length
#define NK 56          // drug vertices
#define DP 768         // prot_data feature
#define DV 43          // drug vertex feature
#define DD 256         // D
#define NT 999         // fused_matrix rows

__device__ inline float fast_tanh(float x) {
    x = fminf(fmaxf(x, -15.f), 15.f);
    float e = __expf(2.f * x);
    return (e - 1.f) / (e + 1.f);
}

// ---------------------------------------------------------------------------
// Tiled f32 GEMM: C[M,N] = act_in(A[M,K]) @ W[K,N] + bias[N]
// BM=BN=64, BK=16, 256 threads, 4x4 micro-tile. M%64==0, N%64==0, K%16==0.
template<bool RELU_IN>
__global__ __launch_bounds__(256) void gemm_bias_kernel(
    const float* __restrict__ A, const float* __restrict__ W,
    const float* __restrict__ bias, float* __restrict__ C,
    int M, int N, int K) {
    const int BM = 64, BN = 64, BK = 16;
    __shared__ float As[BK][BM + 1];
    __shared__ float Bs[BK][BN + 1];
    int bm = blockIdx.x, bn = blockIdx.y;
    int tid = threadIdx.x;
    int tr = tid / 16, tc = tid % 16;
    float acc[4][4] = {};
    int row0 = bm * BM, col0 = bn * BN;
    for (int k0 = 0; k0 < K; k0 += BK) {
        for (int l = tid; l < BM * BK; l += 256) {
            int m = l / BK, kk = l % BK;
            float v = A[(size_t)(row0 + m) * K + k0 + kk];
            if (RELU_IN) v = fmaxf(v, 0.f);
            As[kk][m] = v;
        }
        for (int l = tid; l < BK * BN; l += 256) {
            int kk = l / BN, n = l % BN;
            Bs[kk][n] = W[(size_t)(k0 + kk) * N + col0 + n];
        }
        __syncthreads();
        #pragma unroll
        for (int kk = 0; kk < BK; ++kk) {
            float a[4], b[4];
            #pragma unroll
            for (int i = 0; i < 4; i++) a[i] = As[kk][tr * 4 + i];
            #pragma unroll
            for (int j = 0; j < 4; j++) b[j] = Bs[kk][tc * 4 + j];
            #pragma unroll
            for (int i = 0; i < 4; i++)
                #pragma unroll
                for (int j = 0; j < 4; j++)
                    acc[i][j] = fmaf(a[i], b[j], acc[i][j]);
        }
        __syncthreads();
    }
    #pragma unroll
    for (int i = 0; i < 4; i++)
        #pragma unroll
        for (int j = 0; j < 4; j++) {
            int rr = row0 + tr * 4 + i, cc = col0 + tc * 4 + j;
            C[(size_t)rr * N + cc] = acc[i][j] + bias[cc];
        }
}

// ---------------------------------------------------------------------------
// Small row-matmul: out[r, 0..255] = act_in(in[r, 0..K)) @ W[K,256] + b
template<bool RELU_IN>
__global__ __launch_bounds__(256) void rowmm_kernel(
    const float* __restrict__ in, const float* __restrict__ W,
    const float* __restrict__ bias, float* __restrict__ out, int K) {
    extern __shared__ float srow[];
    int r = blockIdx.x, d = threadIdx.x;
    for (int k = d; k < K; k += 256) {
        float v = in[(size_t)r * K + k];
        if (RELU_IN) v = fmaxf(v, 0.f);
        srow[k] = v;
    }
    __syncthreads();
    float acc = bias[d];
    for (int k = 0; k < K; ++k)
        acc = fmaf(srow[k], W[(size_t)k * DD + d], acc);
    out[(size_t)r * DD + d] = acc;
}

// y[b,i,:] = relu( sum_j adj[b,i,j] * t[b,j,:] )
__global__ __launch_bounds__(256) void adjmul_relu_kernel(
    const float* __restrict__ adj, const float* __restrict__ t,
    float* __restrict__ y) {
    int b = blockIdx.x / NK, i = blockIdx.x % NK, d = threadIdx.x;
    __shared__ float arow[NK];
    if (d < NK) arow[d] = adj[((size_t)b * NK + i) * NK + d];
    __syncthreads();
    float acc = 0.f;
    #pragma unroll 8
    for (int j = 0; j < NK; ++j)
        acc = fmaf(arow[j], t[((size_t)b * NK + j) * DD + d], acc);
    y[((size_t)b * NK + i) * DD + d] = fmaxf(acc, 0.f);
}

// ---------------------------------------------------------------------------
// inter[b,i,k] = sigmoid( qp[b,i,:] . qc[b,k,:] ); atomic add batch sum
__global__ __launch_bounds__(256) void inter_kernel(
    const float* __restrict__ qp, const float* __restrict__ qc,
    float* __restrict__ inter, float* __restrict__ interSum) {
    int b = blockIdx.x / 125, chunk = blockIdx.x % 125;
    __shared__ float qcT[DD * 57];   // [d][k], pad 57
    int tid = threadIdx.x;
    for (int l = tid; l < NK * DD; l += 256) {
        int k = l / DD, d = l % DD;
        qcT[d * 57 + k] = qc[((size_t)b * NK + k) * DD + d];
    }
    __syncthreads();
    int wave = tid >> 6, lane = tid & 63;
    __shared__ float wsum[4];
    float lsum = 0.f;
    for (int ii = 0; ii < 2; ++ii) {
        int i = chunk * 8 + wave * 2 + ii;
        const float* qrow = qp + ((size_t)b * NP + i) * DD;
        if (lane < NK) {
            float acc = 0.f;
            for (int d = 0; d < DD; ++d)
                acc = fmaf(qrow[d], qcT[d * 57 + lane], acc);
            float sg = 1.f / (1.f + __expf(-acc));
            inter[((size_t)b * NP + i) * NK + lane] = sg;
            lsum += sg;
        }
    }
    #pragma unroll
    for (int off = 32; off; off >>= 1) lsum += __shfl_down(lsum, off);
    if (lane == 0) wsum[wave] = lsum;
    __syncthreads();
    if (tid == 0)
        atomicAdd(&interSum[b], wsum[0] + wsum[1] + wsum[2] + wsum[3]);
}

__global__ void normalize_inter_kernel(float* inter, const float* interSum) {
    int idx = blockIdx.x * 256 + threadIdx.x;
    if (idx < B * NP * NK) inter[idx] /= interSum[idx / (NP * NK)];
}

// per-row stats: s[b,i]=sum_k inter^2 ; l1Sum[b]+=sum inter ; bindSum[b]+=sum (inter-lab)^2
__global__ __launch_bounds__(256) void inter_stats_kernel(
    const float* __restrict__ inter, const float* __restrict__ prot_inter,
    const float* __restrict__ exist, float* __restrict__ s_bi,
    float* __restrict__ l1Sum, float* __restrict__ bindSum) {
    int b = blockIdx.x / 4, q = blockIdx.x % 4;
    int i = q * 250 + threadIdx.x;
    float l1 = 0.f, bind = 0.f;
    if (threadIdx.x < 250) {
        float ex = exist[b];
        float ss = 0.f;
        const float* row  = inter      + ((size_t)b * NP + i) * NK;
        const float* prow = prot_inter + ((size_t)b * NP + i) * NK;
        #pragma unroll 8
        for (int k = 0; k < NK; ++k) {
            float v = row[k];
            l1 += v; ss = fmaf(v, v, ss);
            float d = v - ex * prow[k];
            bind = fmaf(d, d, bind);
        }
        s_bi[b * NP + i] = ss;
    }
    __shared__ float r1[256], r2[256];
    r1[threadIdx.x] = l1; r2[threadIdx.x] = bind;
    __syncthreads();
    for (int s = 128; s; s >>= 1) {
        if (threadIdx.x < s) {
            r1[threadIdx.x] += r1[threadIdx.x + s];
            r2[threadIdx.x] += r2[threadIdx.x + s];
        }
        __syncthreads();
    }
    if (threadIdx.x == 0) {
        atomicAdd(&l1Sum[b], r1[0]);
        atomicAdd(&bindSum[b], r2[0]);
    }
}

// ---------------------------------------------------------------------------
// cp partials: part[b][chunk][d] = sum over 25 i's, 56 k's of tanh(prot*comp)*inter
__global__ __launch_bounds__(256) void cp_partial_kernel(
    const float* __restrict__ prot, const float* __restrict__ comp,
    const float* __restrict__ inter, float* __restrict__ part) {
    int b = blockIdx.x / 40, chunk = blockIdx.x % 40;
    int d = threadIdx.x;
    __shared__ float comp_s[NK * DD];   // 57 KB
    __shared__ float irow[NK];
    for (int l = d; l < NK * DD; l += 256)
        comp_s[l] = comp[(size_t)b * NK * DD + l];
    float acc = 0.f;
    for (int ii = 0; ii < 25; ++ii) {
        int i = chunk * 25 + ii;
        __syncthreads();
        if (d < NK) irow[d] = inter[((size_t)b * NP + i) * NK + d];
        __syncthreads();
        float p = prot[((size_t)b * NP + i) * DD + d];
        #pragma unroll 4
        for (int k = 0; k < NK; ++k) {
            float x = p * comp_s[k * DD + d];
            acc = fmaf(fast_tanh(x), irow[k], acc);
        }
    }
    part[((size_t)b * 40 + chunk) * DD + d] = acc;
}

__global__ void cp_reduce_kernel(const float* part, float* cp) {
    int b = blockIdx.x, d = threadIdx.x;
    float s = 0.f;
    for (int c = 0; c < 40; ++c) s += part[((size_t)b * 40 + c) * DD + d];
    cp[b * DD + d] = s;
}

// ---------------------------------------------------------------------------
// conv(k=4,s=2,pad=1) + bias + leaky + maxpool4 -> pooled[b][2048] (layout o*32+p)
__global__ __launch_bounds__(256) void conv_pool_kernel(
    const float* __restrict__ cp, const float* __restrict__ conv_w,
    const float* __restrict__ conv_b, float* __restrict__ pooled) {
    int b = blockIdx.x, t = threadIdx.x;
    __shared__ float x[258];
    __shared__ float convo[64 * 128];
    x[t + 1] = cp[b * DD + t];
    if (t == 0) { x[0] = 0.f; x[257] = 0.f; }
    __syncthreads();
    for (int l = t; l < 64 * 128; l += 256) {
        int o = l / 128, pos = l % 128;
        float acc = conv_b[o];
        int base = pos * 2;
        #pragma unroll
        for (int h = 0; h < 4; ++h)
            acc = fmaf(x[base + h], conv_w[o * 4 + h], acc);
        convo[l] = (acc > 0.f) ? acc : 0.1f * acc;
    }
    __syncthreads();
    for (int l = t; l < 64 * 32; l += 256) {
        int o = l / 32, p = l % 32;
        float m = -INFINITY;
        #pragma unroll
        for (int q = 0; q < 4; ++q)
            m = fmaxf(m, convo[o * 128 + p * 4 + q]);
        pooled[b * 2048 + l] = m;
    }
}

// ---------------------------------------------------------------------------
// FC partial: grid (o_tiles, k_splits). Stage in[b][kchunk] into LDS, 64
// outputs/block coalesced W loads, waves interleave k, 8 batch accumulators,
// LDS cross-wave reduce, atomicAdd into pre-zeroed raw[b*N+o].
__global__ __launch_bounds__(256) void fc_partial_kernel(
    const float* __restrict__ in, const float* __restrict__ W,
    float* __restrict__ raw, int K, int N, int kchunk) {
    int t = threadIdx.x;
    int ol = t & 63;
    int o = blockIdx.x * 64 + ol;
    int w = t >> 6;
    int kbeg = blockIdx.y * kchunk;
    int kend = kbeg + kchunk; if (kend > K) kend = K;
    int len = kend - kbeg;
    __shared__ float sin_[B][128];   // kchunk <= 128
    for (int l = t; l < B * len; l += 256) {
        int b = l / len, k = l % len;
        sin_[b][k] = in[(size_t)b * K + kbeg + k];
    }
    __syncthreads();
    float acc[B];
    #pragma unroll
    for (int b = 0; b < B; ++b) acc[b] = 0.f;
    if (o < N) {
        for (int k = kbeg + w; k < kend; k += 4) {
            float wv = W[(size_t)k * N + o];
            int kl = k - kbeg;
            #pragma unroll
            for (int b = 0; b < B; ++b)
                acc[b] = fmaf(sin_[b][kl], wv, acc[b]);
        }
    }
    __shared__ float red[4][64][B];
    #pragma unroll
    for (int b = 0; b < B; ++b) red[w][ol][b] = acc[b];
    __syncthreads();
    for (int p = t; p < 64 * B; p += 256) {
        int oo = p / B, b = p % B;
        int o2 = blockIdx.x * 64 + oo;
        if (o2 < N) {
            float s = red[0][oo][b] + red[1][oo][b] + red[2][oo][b] + red[3][oo][b];
            atomicAdd(&raw[(size_t)b * N + o2], s);
        }
    }
}

template<bool LEAKY>
__global__ void fc_finish_kernel(const float* __restrict__ raw,
                                 const float* __restrict__ bias,
                                 float* __restrict__ out, int N) {
    int idx = blockIdx.x * 256 + threadIdx.x;
    if (idx < B * N) {
        int b = idx / N, o = idx % N;
        float s = raw[(size_t)b * N + o] + bias[o];
        if (LEAKY) s = (s > 0.f) ? s : 0.1f * s;
        out[(size_t)b * N + o] = s;
    }
}

// fc3: N=1, K=300. One block, 8 waves, wave = batch, shuffle reduce.
__global__ __launch_bounds__(512) void fc3_kernel(
    const float* __restrict__ in, const float* __restrict__ W,
    const float* __restrict__ bias, float* __restrict__ affn) {
    int wv = threadIdx.x >> 6, lane = threadIdx.x & 63;
    float acc = 0.f;
    for (int k = lane; k < 300; k += 64)
        acc = fmaf(in[(size_t)wv * 300 + k], W[k], acc);
    #pragma unroll
    for (int off = 32; off; off >>= 1) acc += __shfl_down(acc, off);
    if (lane == 0) affn[wv] = acc + bias[0];
}

// ---------------------------------------------------------------------------
// fused regularizer.  fusedT[i][t] (stride NT).
// Partial: per (b, t-chunk64, i-quarter) single wave: acc[j] over 250 i's,
// atomicAdd into F[b][j][t].
__global__ __launch_bounds__(64) void fused_partial_kernel(
    const float* __restrict__ inter, const float* __restrict__ fusedT,
    float* __restrict__ F) {
    int bid = blockIdx.x;
    int b = bid / 64; int rem = bid % 64;
    int tc = rem / 4, iq = rem % 4;
    int lane = threadIdx.x;
    int t = tc * 64 + lane;
    bool tvalid = (t < NT);
    __shared__ float irow[NK];
    float acc[NK];
    #pragma unroll
    for (int j = 0; j < NK; ++j) acc[j] = 0.f;
    for (int i = iq * 250; i < iq * 250 + 250; ++i) {
        if (lane < NK) irow[lane] = inter[((size_t)b * NP + i) * NK + lane];
        __syncthreads();
        float fv = tvalid ? fusedT[(size_t)i * NT + t] : 0.f;
        #pragma unroll
        for (int j0 = 0; j0 < NK; j0 += 4) {
            float4 iv = *reinterpret_cast<const float4*>(&irow[j0]);
            acc[j0 + 0] = fmaf(fv, iv.x, acc[j0 + 0]);
            acc[j0 + 1] = fmaf(fv, iv.y, acc[j0 + 1]);
            acc[j0 + 2] = fmaf(fv, iv.z, acc[j0 + 2]);
            acc[j0 + 3] = fmaf(fv, iv.w, acc[j0 + 3]);
        }
        __syncthreads();
    }
    if (tvalid) {
        #pragma unroll
        for (int j = 0; j < NK; ++j)
            atomicAdd(&F[((size_t)b * NK + j) * NT + t], acc[j]);
    }
}

__global__ __launch_bounds__(256) void fused_abs_kernel(
    const float* __restrict__ F, float* __restrict__ fusedAbs) {
    int b = blockIdx.x;
    float s = 0.f;
    for (int l = threadIdx.x; l < NK * NT; l += 256)
        s += fabsf(F[(size_t)b * NK * NT + l]);
    __shared__ float r[256];
    r[threadIdx.x] = s;
    __syncthreads();
    for (int st = 128; st; st >>= 1) {
        if (threadIdx.x < st) r[threadIdx.x] += r[threadIdx.x + st];
        __syncthreads();
    }
    if (threadIdx.x == 0) fusedAbs[b] = r[0];
}

__global__ void transpose_fused_kernel(const float* __restrict__ src,
                                       float* __restrict__ dst) {
    __shared__ float tile[32][33];
    int tb = blockIdx.x % 32;
    int ib = blockIdx.x / 32;
    int tx = threadIdx.x % 32, ty = threadIdx.x / 32;
    for (int r = ty; r < 32; r += 8) {
        int t = tb * 32 + r, i = ib * 32 + tx;
        tile[r][tx] = (t < NT && i < NP) ? src[(size_t)t * NP + i] : 0.f;
    }
    __syncthreads();
    for (int r = ty; r < 32; r += 8) {
        int i = ib * 32 + r, t = tb * 32 + tx;
        if (i < NP && t < NT) dst[(size_t)i * NT + t] = tile[tx][r];
    }
}

// ---------------------------------------------------------------------------
// group: one wave per (b,k): g = contacts[b,k,:] . s[b,:], rs = row sum
__global__ __launch_bounds__(64) void group_kernel(
    const float* __restrict__ contacts, const float* __restrict__ s_bi,
    float* __restrict__ group_val) {
    int bk = blockIdx.x;
    int b = bk / NP, k = bk % NP;
    const float* row = contacts + ((size_t)b * NP + k) * NP;
    const float* sv = s_bi + b * NP;
    float g = 0.f, rs = 0.f;
    for (int i = threadIdx.x; i < NP; i += 64) {
        float c = row[i];
        g = fmaf(c, sv[i], g);
        rs += c;
    }
    #pragma unroll
    for (int off = 32; off; off >>= 1) {
        g += __shfl_down(g, off);
        rs += __shfl_down(rs, off);
    }
    if (threadIdx.x == 0) {
        if (g == 0.f) g += 1e10f;
        group_val[bk] = sqrtf(g) * sqrtf(rs);
    }
}

__global__ __launch_bounds__(256) void reduce1000_kernel(const float* in, float* out) {
    int b = blockIdx.x;
    float s = 0.f;
    for (int l = threadIdx.x; l < NP; l += 256) s += in[b * NP + l];
    __shared__ float r[256];
    r[threadIdx.x] = s;
    __syncthreads();
    for (int st = 128; st; st >>= 1) {
        if (threadIdx.x < st) r[threadIdx.x] += r[threadIdx.x + st];
        __syncthreads();
    }
    if (threadIdx.x == 0) out[b] = r[0];
}

// accums layout: [0..8)=interSum [8..16)=l1Sum [16..24)=bindSum [24..32)=fusedAbs [32..40)=groupReg
__global__ void final_kernel(const float* __restrict__ accums,
                             const float* __restrict__ affn,
                             const float* __restrict__ label,
                             float* __restrict__ out) {
    if (threadIdx.x == 0 && blockIdx.x == 0) {
        float l0 = 0.f, l1 = 0.f, l2 = 0.f;
        for (int b = 0; b < B; ++b) {
            l0 += accums[8 + b] + accums[24 + b] + accums[32 + b];
            l1 += sqrtf(accums[16 + b]);
            float d = affn[b] - label[b];
            l2 += d * d;
        }
        out[0] = (l0 + l1 + l2) * 0.125f;
    }
}

// ---------------------------------------------------------------------------
extern "C" void kernel_launch(void* const* d_in, const int* in_sizes, int n_in,
                              void* d_out, int out_size, void* d_ws, size_t ws_size,
                              hipStream_t stream) {
    const float* prot_data   = (const float*)d_in[0];
    const float* drug_ver    = (const float*)d_in[1];
    const float* drug_adj    = (const float*)d_in[2];
    const float* contacts    = (const float*)d_in[3];
    const float* prot_inter  = (const float*)d_in[4];
    const float* exist       = (const float*)d_in[5];
    const float* label       = (const float*)d_in[6];
    const float* fused       = (const float*)d_in[7];
    const float* W_prot      = (const float*)d_in[8];
    const float* b_prot      = (const float*)d_in[9];
    const float* gcn_W0      = (const float*)d_in[10];
    const float* gcn_b0      = (const float*)d_in[11];
    const float* gcn_W1      = (const float*)d_in[12];
    const float* gcn_b1      = (const float*)d_in[13];
    const float* gcn_W2      = (const float*)d_in[14];
    const float* gcn_b2      = (const float*)d_in[15];
    const float* gcn_Wf      = (const float*)d_in[16];
    const float* gcn_bf      = (const float*)d_in[17];
    const float* Wjp         = (const float*)d_in[18];
    const float* bjp         = (const float*)d_in[19];
    const float* Wjc         = (const float*)d_in[20];
    const float* bjc         = (const float*)d_in[21];
    const float* conv_w      = (const float*)d_in[22];
    const float* conv_b      = (const float*)d_in[23];
    const float* W_r1        = (const float*)d_in[24];
    const float* b_r1        = (const float*)d_in[25];
    const float* W_r2        = (const float*)d_in[26];
    const float* b_r2        = (const float*)d_in[27];
    const float* W_r3        = (const float*)d_in[28];
    const float* b_r3        = (const float*)d_in[29];

    float* ws = (float*)d_ws;
    size_t off = 0;
    auto alloc = [&](size_t n) { float* p = ws + off; off += n; return p; };
    float* prot     = alloc((size_t)B * NP * DD);   // 2,048,000
    float* qp       = alloc((size_t)B * NP * DD);   // 2,048,000
    float* tbuf     = alloc((size_t)B * NK * DD);
    float* ybuf     = alloc((size_t)B * NK * DD);
    float* comp     = alloc((size_t)B * NK * DD);
    float* qc       = alloc((size_t)B * NK * DD);
    float* inter    = alloc((size_t)B * NP * NK);   // 448,000
    float* s_bi     = alloc((size_t)B * NP);
    float* cp_part  = alloc((size_t)B * 40 * DD);
    float* cp       = alloc((size_t)B * DD);
    float* pooled   = alloc((size_t)B * 2048);
    float* fc1      = alloc((size_t)B * 600);
    float* fc2      = alloc((size_t)B * 300);
    float* affn     = alloc((size_t)B);
    float* groupv   = alloc((size_t)B * NP);
    float* fusedT   = alloc((size_t)NP * NT);       // 999,000
    // zero-region: F, accums, raw1, raw2 contiguous
    float* F        = alloc((size_t)B * NK * NT);   // 447,552
    float* accums   = alloc(40);
    float* raw1     = alloc((size_t)B * 600);
    float* raw2     = alloc((size_t)B * 300);

    // zero the atomic-accumulated buffers (F, accums, raw1, raw2 contiguous)
    hipMemsetAsync(F, 0,
        ((size_t)B * NK * NT + 40 + (size_t)B * 600 + (size_t)B * 300) * sizeof(float),
        stream);

    // fused matrix transpose (independent)
    transpose_fused_kernel<<<1024, 256, 0, stream>>>(fused, fusedT);

    // prot = prot_data @ W_prot + b_prot
    gemm_bias_kernel<false><<<dim3(125, 4), 256, 0, stream>>>(
        prot_data, W_prot, b_prot, prot, B * NP, DD, DP);

    // GCN stack
    rowmm_kernel<false><<<B * NK, 256, DV * sizeof(float), stream>>>(drug_ver, gcn_W0, gcn_b0, tbuf, DV);
    adjmul_relu_kernel<<<B * NK, 256, 0, stream>>>(drug_adj, tbuf, ybuf);
    rowmm_kernel<false><<<B * NK, 256, DD * sizeof(float), stream>>>(ybuf, gcn_W1, gcn_b1, tbuf, DD);
    adjmul_relu_kernel<<<B * NK, 256, 0, stream>>>(drug_adj, tbuf, ybuf);
    rowmm_kernel<false><<<B * NK, 256, DD * sizeof(float), stream>>>(ybuf, gcn_W2, gcn_b2, tbuf, DD);
    adjmul_relu_kernel<<<B * NK, 256, 0, stream>>>(drug_adj, tbuf, ybuf);
    rowmm_kernel<false><<<B * NK, 256, DD * sizeof(float), stream>>>(ybuf, gcn_Wf, gcn_bf, comp, DD);
    rowmm_kernel<true ><<<B * NK, 256, DD * sizeof(float), stream>>>(comp, Wjc, bjc, qc, DD);

    // qp = relu(prot) @ Wjp + bjp
    gemm_bias_kernel<true><<<dim3(125, 4), 256, 0, stream>>>(
        prot, Wjp, bjp, qp, B * NP, DD, DD);

    // inter + normalization
    inter_kernel<<<B * 125, 256, 0, stream>>>(qp, qc, inter, accums + 0);
    normalize_inter_kernel<<<(B * NP * NK + 255) / 256, 256, 0, stream>>>(inter, accums + 0);
    inter_stats_kernel<<<B * 4, 256, 0, stream>>>(inter, prot_inter, exist, s_bi,
                                                  accums + 8, accums + 16);

    // cp contraction
    cp_partial_kernel<<<B * 40, 256, 0, stream>>>(prot, comp, inter, cp_part);
    cp_reduce_kernel<<<B, 256, 0, stream>>>(cp_part, cp);

    // conv / pool / FCs
    conv_pool_kernel<<<B, 256, 0, stream>>>(cp, conv_w, conv_b, pooled);
    fc_partial_kernel<<<dim3(10, 16), 256, 0, stream>>>(pooled, W_r1, raw1, 2048, 600, 128);
    fc_finish_kernel<true><<<(B * 600 + 255) / 256, 256, 0, stream>>>(raw1, b_r1, fc1, 600);
    fc_partial_kernel<<<dim3(5, 8), 256, 0, stream>>>(fc1, W_r2, raw2, 600, 300, 75);
    fc_finish_kernel<true><<<(B * 300 + 255) / 256, 256, 0, stream>>>(raw2, b_r2, fc2, 300);
    fc3_kernel<<<1, 512, 0, stream>>>(fc2, W_r3, b_r3, affn);

    // fused regularizer
    fused_partial_kernel<<<B * 64, 64, 0, stream>>>(inter, fusedT, F);
    fused_abs_kernel<<<B, 256, 0, stream>>>(F, accums + 24);

    // group regularizer
    group_kernel<<<B * NP, 64, 0, stream>>>(contacts, s_bi, groupv);
    reduce1000_kernel<<<B, 256, 0, stream>>>(groupv, accums + 32);

    // final loss
    final_kernel<<<1, 64, 0, stream>>>(accums, affn, label, (float*)d_out);
}

// Round 4
// 520.939 us; speedup vs baseline: 3.0527x; 1.2561x over previous
//
#include <hip/hip_runtime.h>
#include <hip/hip_bf16.h>
#include <math.h>

// ---------------------------------------------------------------------------
// Sizes (fixed by the reference)
#define B 8
#define NP 1000        // protein length
#define NK 56          // drug vertices
#define DP 768         // prot_data feature
#define DV 43          // drug vertex feature
#define DD 256         // D
#define NT 999         // fused_matrix rows

__device__ inline float fast_tanh(float x) {
    x = fminf(fmaxf(x, -15.f), 15.f);
    float e = __expf(2.f * x);
    return (e - 1.f) / (e + 1.f);
}

// ---------------------------------------------------------------------------
// Tiled f32 GEMM: C[M,N] = act_in(A[M,K]) @ W[K,N] + bias[N]
// BM=BN=64, BK=32, 256 threads, 4x4 micro-tile, float4 LDS fragment reads.
// M%64==0, N%64==0, K%32==0.
template<bool RELU_IN>
__global__ __launch_bounds__(256) void gemm_bias_kernel(
    const float* __restrict__ A, const float* __restrict__ W,
    const float* __restrict__ bias, float* __restrict__ C,
    int M, int N, int K) {
    const int BM = 64, BN = 64, BK = 32;
    __shared__ float As[BK][68];   // [kk][m], pad 68 keeps 16B alignment
    __shared__ float Bs[BK][68];   // [kk][n]
    int bm = blockIdx.x, bn = blockIdx.y;
    int tid = threadIdx.x;
    int tr = tid >> 4, tc = tid & 15;
    float acc[4][4] = {};
    int row0 = bm * BM, col0 = bn * BN;
    for (int k0 = 0; k0 < K; k0 += BK) {
        #pragma unroll
        for (int it = 0; it < 8; ++it) {
            int l = tid + it * 256;
            int m = l >> 5, kk = l & 31;
            float v = A[(size_t)(row0 + m) * K + k0 + kk];
            if (RELU_IN) v = fmaxf(v, 0.f);
            As[kk][m] = v;
        }
        #pragma unroll
        for (int it = 0; it < 8; ++it) {
            int l = tid + it * 256;
            int kk = l >> 6, n = l & 63;
            Bs[kk][n] = W[(size_t)(k0 + kk) * N + col0 + n];
        }
        __syncthreads();
        #pragma unroll
        for (int kk = 0; kk < BK; ++kk) {
            float4 av = *reinterpret_cast<const float4*>(&As[kk][tr * 4]);
            float4 bv = *reinterpret_cast<const float4*>(&Bs[kk][tc * 4]);
            float a[4] = {av.x, av.y, av.z, av.w};
            float b[4] = {bv.x, bv.y, bv.z, bv.w};
            #pragma unroll
            for (int i = 0; i < 4; i++)
                #pragma unroll
                for (int j = 0; j < 4; j++)
                    acc[i][j] = fmaf(a[i], b[j], acc[i][j]);
        }
        __syncthreads();
    }
    #pragma unroll
    for (int i = 0; i < 4; i++)
        #pragma unroll
        for (int j = 0; j < 4; j++) {
            int rr = row0 + tr * 4 + i, cc = col0 + tc * 4 + j;
            C[(size_t)rr * N + cc] = acc[i][j] + bias[cc];
        }
}

// ---------------------------------------------------------------------------
// Small row-matmul: out[r, 0..255] = act_in(in[r, 0..K)) @ W[K,256] + b
template<bool RELU_IN>
__global__ __launch_bounds__(256) void rowmm_kernel(
    const float* __restrict__ in, const float* __restrict__ W,
    const float* __restrict__ bias, float* __restrict__ out, int K) {
    extern __shared__ float srow[];
    int r = blockIdx.x, d = threadIdx.x;
    for (int k = d; k < K; k += 256) {
        float v = in[(size_t)r * K + k];
        if (RELU_IN) v = fmaxf(v, 0.f);
        srow[k] = v;
    }
    __syncthreads();
    float acc = bias[d];
    for (int k = 0; k < K; ++k)
        acc = fmaf(srow[k], W[(size_t)k * DD + d], acc);
    out[(size_t)r * DD + d] = acc;
}

// y[b,i,:] = relu( sum_j adj[b,i,j] * t[b,j,:] )
__global__ __launch_bounds__(256) void adjmul_relu_kernel(
    const float* __restrict__ adj, const float* __restrict__ t,
    float* __restrict__ y) {
    int b = blockIdx.x / NK, i = blockIdx.x % NK, d = threadIdx.x;
    __shared__ float arow[NK];
    if (d < NK) arow[d] = adj[((size_t)b * NK + i) * NK + d];
    __syncthreads();
    float acc = 0.f;
    #pragma unroll 8
    for (int j = 0; j < NK; ++j)
        acc = fmaf(arow[j], t[((size_t)b * NK + j) * DD + d], acc);
    y[((size_t)b * NK + i) * DD + d] = fmaxf(acc, 0.f);
}

// ---------------------------------------------------------------------------
// inter[b,i,k] = sigmoid( qp[b,i,:] . qc[b,k,:] ); atomic add batch sum
__global__ __launch_bounds__(256) void inter_kernel(
    const float* __restrict__ qp, const float* __restrict__ qc,
    float* __restrict__ inter, float* __restrict__ interSum) {
    int b = blockIdx.x / 125, chunk = blockIdx.x % 125;
    __shared__ float qcT[DD * 57];   // [d][k], pad 57
    int tid = threadIdx.x;
    for (int l = tid; l < NK * DD; l += 256) {
        int k = l / DD, d = l % DD;
        qcT[d * 57 + k] = qc[((size_t)b * NK + k) * DD + d];
    }
    __syncthreads();
    int wave = tid >> 6, lane = tid & 63;
    __shared__ float wsum[4];
    float lsum = 0.f;
    for (int ii = 0; ii < 2; ++ii) {
        int i = chunk * 8 + wave * 2 + ii;
        const float* qrow = qp + ((size_t)b * NP + i) * DD;
        if (lane < NK) {
            float acc = 0.f;
            for (int d = 0; d < DD; ++d)
                acc = fmaf(qrow[d], qcT[d * 57 + lane], acc);
            float sg = 1.f / (1.f + __expf(-acc));
            inter[((size_t)b * NP + i) * NK + lane] = sg;
            lsum += sg;
        }
    }
    #pragma unroll
    for (int off = 32; off; off >>= 1) lsum += __shfl_down(lsum, off);
    if (lane == 0) wsum[wave] = lsum;
    __syncthreads();
    if (tid == 0)
        atomicAdd(&interSum[b], wsum[0] + wsum[1] + wsum[2] + wsum[3]);
}

__global__ void normalize_inter_kernel(float* inter, const float* interSum) {
    int idx = blockIdx.x * 256 + threadIdx.x;
    if (idx < B * NP * NK) inter[idx] /= interSum[idx / (NP * NK)];
}

// per-row stats: s[b,i]=sum_k inter^2 ; l1Sum[b]+=sum inter ; bindSum[b]+=sum (inter-lab)^2
__global__ __launch_bounds__(256) void inter_stats_kernel(
    const float* __restrict__ inter, const float* __restrict__ prot_inter,
    const float* __restrict__ exist, float* __restrict__ s_bi,
    float* __restrict__ l1Sum, float* __restrict__ bindSum) {
    int b = blockIdx.x / 4, q = blockIdx.x % 4;
    int i = q * 250 + threadIdx.x;
    float l1 = 0.f, bind = 0.f;
    if (threadIdx.x < 250) {
        float ex = exist[b];
        float ss = 0.f;
        const float* row  = inter      + ((size_t)b * NP + i) * NK;
        const float* prow = prot_inter + ((size_t)b * NP + i) * NK;
        #pragma unroll 8
        for (int k = 0; k < NK; ++k) {
            float v = row[k];
            l1 += v; ss = fmaf(v, v, ss);
            float d = v - ex * prow[k];
            bind = fmaf(d, d, bind);
        }
        s_bi[b * NP + i] = ss;
    }
    __shared__ float r1[256], r2[256];
    r1[threadIdx.x] = l1; r2[threadIdx.x] = bind;
    __syncthreads();
    for (int s = 128; s; s >>= 1) {
        if (threadIdx.x < s) {
            r1[threadIdx.x] += r1[threadIdx.x + s];
            r2[threadIdx.x] += r2[threadIdx.x + s];
        }
        __syncthreads();
    }
    if (threadIdx.x == 0) {
        atomicAdd(&l1Sum[b], r1[0]);
        atomicAdd(&bindSum[b], r2[0]);
    }
}

// ---------------------------------------------------------------------------
// cp partials: part[b][chunk][d] = sum over 25 i's, 56 k's of tanh(prot*comp)*inter
__global__ __launch_bounds__(256) void cp_partial_kernel(
    const float* __restrict__ prot, const float* __restrict__ comp,
    const float* __restrict__ inter, float* __restrict__ part) {
    int b = blockIdx.x / 40, chunk = blockIdx.x % 40;
    int d = threadIdx.x;
    __shared__ float comp_s[NK * DD];   // 57 KB
    __shared__ float irow[NK];
    for (int l = d; l < NK * DD; l += 256)
        comp_s[l] = comp[(size_t)b * NK * DD + l];
    float acc = 0.f;
    for (int ii = 0; ii < 25; ++ii) {
        int i = chunk * 25 + ii;
        __syncthreads();
        if (d < NK) irow[d] = inter[((size_t)b * NP + i) * NK + d];
        __syncthreads();
        float p = prot[((size_t)b * NP + i) * DD + d];
        #pragma unroll 4
        for (int k = 0; k < NK; ++k) {
            float x = p * comp_s[k * DD + d];
            acc = fmaf(fast_tanh(x), irow[k], acc);
        }
    }
    part[((size_t)b * 40 + chunk) * DD + d] = acc;
}

__global__ void cp_reduce_kernel(const float* part, float* cp) {
    int b = blockIdx.x, d = threadIdx.x;
    float s = 0.f;
    for (int c = 0; c < 40; ++c) s += part[((size_t)b * 40 + c) * DD + d];
    cp[b * DD + d] = s;
}

// ---------------------------------------------------------------------------
// conv(k=4,s=2,pad=1) + bias + leaky + maxpool4 -> pooled[b][2048] (layout o*32+p)
__global__ __launch_bounds__(256) void conv_pool_kernel(
    const float* __restrict__ cp, const float* __restrict__ conv_w,
    const float* __restrict__ conv_b, float* __restrict__ pooled) {
    int b = blockIdx.x, t = threadIdx.x;
    __shared__ float x[258];
    __shared__ float convo[64 * 128];
    x[t + 1] = cp[b * DD + t];
    if (t == 0) { x[0] = 0.f; x[257] = 0.f; }
    __syncthreads();
    for (int l = t; l < 64 * 128; l += 256) {
        int o = l / 128, pos = l % 128;
        float acc = conv_b[o];
        int base = pos * 2;
        #pragma unroll
        for (int h = 0; h < 4; ++h)
            acc = fmaf(x[base + h], conv_w[o * 4 + h], acc);
        convo[l] = (acc > 0.f) ? acc : 0.1f * acc;
    }
    __syncthreads();
    for (int l = t; l < 64 * 32; l += 256) {
        int o = l / 32, p = l % 32;
        float m = -INFINITY;
        #pragma unroll
        for (int q = 0; q < 4; ++q)
            m = fmaxf(m, convo[o * 128 + p * 4 + q]);
        pooled[b * 2048 + l] = m;
    }
}

// ---------------------------------------------------------------------------
// FC partial: grid (o_tiles, k_splits). Stage in[b][kchunk] into LDS, 64
// outputs/block coalesced W loads, waves interleave k, 8 batch accumulators,
// LDS cross-wave reduce, atomicAdd into pre-zeroed raw[b*N+o].
__global__ __launch_bounds__(256) void fc_partial_kernel(
    const float* __restrict__ in, const float* __restrict__ W,
    float* __restrict__ raw, int K, int N, int kchunk) {
    int t = threadIdx.x;
    int ol = t & 63;
    int o = blockIdx.x * 64 + ol;
    int w = t >> 6;
    int kbeg = blockIdx.y * kchunk;
    int kend = kbeg + kchunk; if (kend > K) kend = K;
    int len = kend - kbeg;
    __shared__ float sin_[B][128];   // kchunk <= 128
    for (int l = t; l < B * len; l += 256) {
        int b = l / len, k = l % len;
        sin_[b][k] = in[(size_t)b * K + kbeg + k];
    }
    __syncthreads();
    float acc[B];
    #pragma unroll
    for (int b = 0; b < B; ++b) acc[b] = 0.f;
    if (o < N) {
        for (int k = kbeg + w; k < kend; k += 4) {
            float wv = W[(size_t)k * N + o];
            int kl = k - kbeg;
            #pragma unroll
            for (int b = 0; b < B; ++b)
                acc[b] = fmaf(sin_[b][kl], wv, acc[b]);
        }
    }
    __shared__ float red[4][64][B];
    #pragma unroll
    for (int b = 0; b < B; ++b) red[w][ol][b] = acc[b];
    __syncthreads();
    for (int p = t; p < 64 * B; p += 256) {
        int oo = p / B, b = p % B;
        int o2 = blockIdx.x * 64 + oo;
        if (o2 < N) {
            float s = red[0][oo][b] + red[1][oo][b] + red[2][oo][b] + red[3][oo][b];
            atomicAdd(&raw[(size_t)b * N + o2], s);
        }
    }
}

template<bool LEAKY>
__global__ void fc_finish_kernel(const float* __restrict__ raw,
                                 const float* __restrict__ bias,
                                 float* __restrict__ out, int N) {
    int idx = blockIdx.x * 256 + threadIdx.x;
    if (idx < B * N) {
        int b = idx / N, o = idx % N;
        float s = raw[(size_t)b * N + o] + bias[o];
        if (LEAKY) s = (s > 0.f) ? s : 0.1f * s;
        out[(size_t)b * N + o] = s;
    }
}

// fc3: N=1, K=300. One block, 8 waves, wave = batch, shuffle reduce.
__global__ __launch_bounds__(512) void fc3_kernel(
    const float* __restrict__ in, const float* __restrict__ W,
    const float* __restrict__ bias, float* __restrict__ affn) {
    int wv = threadIdx.x >> 6, lane = threadIdx.x & 63;
    float acc = 0.f;
    for (int k = lane; k < 300; k += 64)
        acc = fmaf(in[(size_t)wv * 300 + k], W[k], acc);
    #pragma unroll
    for (int off = 32; off; off >>= 1) acc += __shfl_down(acc, off);
    if (lane == 0) affn[wv] = acc + bias[0];
}

// ---------------------------------------------------------------------------
// fused regularizer as per-batch GEMM + abs-reduce:
// fusedAbs[b] += sum_{t,j} | sum_i fused[t,i] * inter[b,i,j] |
// grid (t_tiles=16, b=8), 64x64 tile (j padded 56->64 with zeros), BK=40.
__global__ __launch_bounds__(256) void fused_gemm_abs_kernel(
    const float* __restrict__ fusedM,   // [NT][NP]
    const float* __restrict__ inter,    // [B][NP][NK]
    float* __restrict__ fusedAbs) {     // [B], pre-zeroed
    const int BK = 40;
    int b = blockIdx.y;
    int t0 = blockIdx.x * 64;
    __shared__ float Ft[BK][68];   // [kk][t_local]
    __shared__ float It[BK][64];   // [kk][j], j>=56 zeroed
    int tid = threadIdx.x;
    int tr = tid >> 4, tc = tid & 15;
    float acc[4][4] = {};
    for (int i0 = 0; i0 < NP; i0 += BK) {
        for (int l = tid; l < 64 * BK; l += 256) {
            int tl = l / BK, kk = l % BK;
            int tt = t0 + tl;
            Ft[kk][tl] = (tt < NT) ? fusedM[(size_t)tt * NP + i0 + kk] : 0.f;
        }
        for (int l = tid; l < BK * 64; l += 256) {
            int ii = l >> 6, j = l & 63;
            It[ii][j] = (j < NK) ? inter[((size_t)b * NP + i0 + ii) * NK + j] : 0.f;
        }
        __syncthreads();
        #pragma unroll 8
        for (int kk = 0; kk < BK; ++kk) {
            float4 av = *reinterpret_cast<const float4*>(&Ft[kk][tr * 4]);
            float4 bv = *reinterpret_cast<const float4*>(&It[kk][tc * 4]);
            float a[4] = {av.x, av.y, av.z, av.w};
            float bb[4] = {bv.x, bv.y, bv.z, bv.w};
            #pragma unroll
            for (int i = 0; i < 4; i++)
                #pragma unroll
                for (int j = 0; j < 4; j++)
                    acc[i][j] = fmaf(a[i], bb[j], acc[i][j]);
        }
        __syncthreads();
    }
    float s = 0.f;
    #pragma unroll
    for (int i = 0; i < 4; i++)
        #pragma unroll
        for (int j = 0; j < 4; j++)
            s += fabsf(acc[i][j]);
    int wave = tid >> 6, lane = tid & 63;
    #pragma unroll
    for (int off = 32; off; off >>= 1) s += __shfl_down(s, off);
    __shared__ float ws[4];
    if (lane == 0) ws[wave] = s;
    __syncthreads();
    if (tid == 0)
        atomicAdd(&fusedAbs[b], ws[0] + ws[1] + ws[2] + ws[3]);
}

// ---------------------------------------------------------------------------
// group: one wave per (b,k): g = contacts[b,k,:] . s[b,:], rs = row sum
__global__ __launch_bounds__(64) void group_kernel(
    const float* __restrict__ contacts, const float* __restrict__ s_bi,
    float* __restrict__ group_val) {
    int bk = blockIdx.x;
    int b = bk / NP, k = bk % NP;
    const float* row = contacts + ((size_t)b * NP + k) * NP;
    const float* sv = s_bi + b * NP;
    float g = 0.f, rs = 0.f;
    for (int i = threadIdx.x; i < NP; i += 64) {
        float c = row[i];
        g = fmaf(c, sv[i], g);
        rs += c;
    }
    #pragma unroll
    for (int off = 32; off; off >>= 1) {
        g += __shfl_down(g, off);
        rs += __shfl_down(rs, off);
    }
    if (threadIdx.x == 0) {
        if (g == 0.f) g += 1e10f;
        group_val[bk] = sqrtf(g) * sqrtf(rs);
    }
}

__global__ __launch_bounds__(256) void reduce1000_kernel(const float* in, float* out) {
    int b = blockIdx.x;
    float s = 0.f;
    for (int l = threadIdx.x; l < NP; l += 256) s += in[b * NP + l];
    __shared__ float r[256];
    r[threadIdx.x] = s;
    __syncthreads();
    for (int st = 128; st; st >>= 1) {
        if (threadIdx.x < st) r[threadIdx.x] += r[threadIdx.x + st];
        __syncthreads();
    }
    if (threadIdx.x == 0) out[b] = r[0];
}

// accums layout: [0..8)=interSum [8..16)=l1Sum [16..24)=bindSum [24..32)=fusedAbs [32..40)=groupReg
__global__ void final_kernel(const float* __restrict__ accums,
                             const float* __restrict__ affn,
                             const float* __restrict__ label,
                             float* __restrict__ out) {
    if (threadIdx.x == 0 && blockIdx.x == 0) {
        float l0 = 0.f, l1 = 0.f, l2 = 0.f;
        for (int b = 0; b < B; ++b) {
            l0 += accums[8 + b] + accums[24 + b] + accums[32 + b];
            l1 += sqrtf(accums[16 + b]);
            float d = affn[b] - label[b];
            l2 += d * d;
        }
        out[0] = (l0 + l1 + l2) * 0.125f;
    }
}

// ---------------------------------------------------------------------------
extern "C" void kernel_launch(void* const* d_in, const int* in_sizes, int n_in,
                              void* d_out, int out_size, void* d_ws, size_t ws_size,
                              hipStream_t stream) {
    const float* prot_data   = (const float*)d_in[0];
    const float* drug_ver    = (const float*)d_in[1];
    const float* drug_adj    = (const float*)d_in[2];
    const float* contacts    = (const float*)d_in[3];
    const float* prot_inter  = (const float*)d_in[4];
    const float* exist       = (const float*)d_in[5];
    const float* label       = (const float*)d_in[6];
    const float* fused       = (const float*)d_in[7];
    const float* W_prot      = (const float*)d_in[8];
    const float* b_prot      = (const float*)d_in[9];
    const float* gcn_W0      = (const float*)d_in[10];
    const float* gcn_b0      = (const float*)d_in[11];
    const float* gcn_W1      = (const float*)d_in[12];
    const float* gcn_b1      = (const float*)d_in[13];
    const float* gcn_W2      = (const float*)d_in[14];
    const float* gcn_b2      = (const float*)d_in[15];
    const float* gcn_Wf      = (const float*)d_in[16];
    const float* gcn_bf      = (const float*)d_in[17];
    const float* Wjp         = (const float*)d_in[18];
    const float* bjp         = (const float*)d_in[19];
    const float* Wjc         = (const float*)d_in[20];
    const float* bjc         = (const float*)d_in[21];
    const float* conv_w      = (const float*)d_in[22];
    const float* conv_b      = (const float*)d_in[23];
    const float* W_r1        = (const float*)d_in[24];
    const float* b_r1        = (const float*)d_in[25];
    const float* W_r2        = (const float*)d_in[26];
    const float* b_r2        = (const float*)d_in[27];
    const float* W_r3        = (const float*)d_in[28];
    const float* b_r3        = (const float*)d_in[29];

    float* ws = (float*)d_ws;
    size_t off = 0;
    auto alloc = [&](size_t n) { float* p = ws + off; off += n; return p; };
    float* prot     = alloc((size_t)B * NP * DD);   // 2,048,000
    float* qp       = alloc((size_t)B * NP * DD);   // 2,048,000
    float* tbuf     = alloc((size_t)B * NK * DD);
    float* ybuf     = alloc((size_t)B * NK * DD);
    float* comp     = alloc((size_t)B * NK * DD);
    float* qc       = alloc((size_t)B * NK * DD);
    float* inter    = alloc((size_t)B * NP * NK);   // 448,000
    float* s_bi     = alloc((size_t)B * NP);
    float* cp_part  = alloc((size_t)B * 40 * DD);
    float* cp       = alloc((size_t)B * DD);
    float* pooled   = alloc((size_t)B * 2048);
    float* fc1      = alloc((size_t)B * 600);
    float* fc2      = alloc((size_t)B * 300);
    float* affn     = alloc((size_t)B);
    float* groupv   = alloc((size_t)B * NP);
    // zero-region: accums, raw1, raw2 contiguous
    float* accums   = alloc(40);
    float* raw1     = alloc((size_t)B * 600);
    float* raw2     = alloc((size_t)B * 300);

    // zero the atomic-accumulated buffers (accums, raw1, raw2 contiguous)
    hipMemsetAsync(accums, 0,
        (40 + (size_t)B * 600 + (size_t)B * 300) * sizeof(float), stream);

    // prot = prot_data @ W_prot + b_prot
    gemm_bias_kernel<false><<<dim3(125, 4), 256, 0, stream>>>(
        prot_data, W_prot, b_prot, prot, B * NP, DD, DP);

    // GCN stack
    rowmm_kernel<false><<<B * NK, 256, DV * sizeof(float), stream>>>(drug_ver, gcn_W0, gcn_b0, tbuf, DV);
    adjmul_relu_kernel<<<B * NK, 256, 0, stream>>>(drug_adj, tbuf, ybuf);
    rowmm_kernel<false><<<B * NK, 256, DD * sizeof(float), stream>>>(ybuf, gcn_W1, gcn_b1, tbuf, DD);
    adjmul_relu_kernel<<<B * NK, 256, 0, stream>>>(drug_adj, tbuf, ybuf);
    rowmm_kernel<false><<<B * NK, 256, DD * sizeof(float), stream>>>(ybuf, gcn_W2, gcn_b2, tbuf, DD);
    adjmul_relu_kernel<<<B * NK, 256, 0, stream>>>(drug_adj, tbuf, ybuf);
    rowmm_kernel<false><<<B * NK, 256, DD * sizeof(float), stream>>>(ybuf, gcn_Wf, gcn_bf, comp, DD);
    rowmm_kernel<true ><<<B * NK, 256, DD * sizeof(float), stream>>>(comp, Wjc, bjc, qc, DD);

    // qp = relu(prot) @ Wjp + bjp
    gemm_bias_kernel<true><<<dim3(125, 4), 256, 0, stream>>>(
        prot, Wjp, bjp, qp, B * NP, DD, DD);

    // inter + normalization
    inter_kernel<<<B * 125, 256, 0, stream>>>(qp, qc, inter, accums + 0);
    normalize_inter_kernel<<<(B * NP * NK + 255) / 256, 256, 0, stream>>>(inter, accums + 0);
    inter_stats_kernel<<<B * 4, 256, 0, stream>>>(inter, prot_inter, exist, s_bi,
                                                  accums + 8, accums + 16);

    // cp contraction
    cp_partial_kernel<<<B * 40, 256, 0, stream>>>(prot, comp, inter, cp_part);
    cp_reduce_kernel<<<B, 256, 0, stream>>>(cp_part, cp);

    // conv / pool / FCs
    conv_pool_kernel<<<B, 256, 0, stream>>>(cp, conv_w, conv_b, pooled);
    fc_partial_kernel<<<dim3(10, 16), 256, 0, stream>>>(pooled, W_r1, raw1, 2048, 600, 128);
    fc_finish_kernel<true><<<(B * 600 + 255) / 256, 256, 0, stream>>>(raw1, b_r1, fc1, 600);
    fc_partial_kernel<<<dim3(5, 8), 256, 0, stream>>>(fc1, W_r2, raw2, 600, 300, 75);
    fc_finish_kernel<true><<<(B * 300 + 255) / 256, 256, 0, stream>>>(raw2, b_r2, fc2, 300);
    fc3_kernel<<<1, 512, 0, stream>>>(fc2, W_r3, b_r3, affn);

    // fused regularizer (GEMM + abs reduce, no intermediates)
    fused_gemm_abs_kernel<<<dim3(16, B), 256, 0, stream>>>(fused, inter, accums + 24);

    // group regularizer
    group_kernel<<<B * NP, 64, 0, stream>>>(contacts, s_bi, groupv);
    reduce1000_kernel<<<B, 256, 0, stream>>>(groupv, accums + 32);

    // final loss
    final_kernel<<<1, 64, 0, stream>>>(accums, affn, label, (float*)d_out);
}

// Round 5
// 410.350 us; speedup vs baseline: 3.8755x; 1.2695x over previous
//
#include <hip/hip_runtime.h>
#include <hip/hip_bf16.h>
#include <math.h>

// ---------------------------------------------------------------------------
// Sizes (fixed by the reference)
#define B 8
#define NP 1000        // protein length
#define NK 56          // drug vertices
#define DP 768         // prot_data feature
#define DV 43          // drug vertex feature
#define DD 256         // D
#define NT 999         // fused_matrix rows

__device__ inline float fast_tanh(float x) {
    x = fminf(fmaxf(x, -15.f), 15.f);
    float e = __expf(2.f * x);
    return (e - 1.f) / (e + 1.f);
}

// ---------------------------------------------------------------------------
// Tiled f32 GEMM: C[M,N] = act_in(A[M,K]) @ W[K,N] + bias[N]
// BM=BN=64, BK=32, 256 threads, 4x4 micro-tile, float4 LDS fragment reads.
// M%64==0, N%64==0, K%32==0.
template<bool RELU_IN>
__global__ __launch_bounds__(256) void gemm_bias_kernel(
    const float* __restrict__ A, const float* __restrict__ W,
    const float* __restrict__ bias, float* __restrict__ C,
    int M, int N, int K) {
    const int BM = 64, BN = 64, BK = 32;
    __shared__ float As[BK][68];   // [kk][m], pad 68 keeps 16B alignment
    __shared__ float Bs[BK][68];   // [kk][n]
    int bm = blockIdx.x, bn = blockIdx.y;
    int tid = threadIdx.x;
    int tr = tid >> 4, tc = tid & 15;
    float acc[4][4] = {};
    int row0 = bm * BM, col0 = bn * BN;
    for (int k0 = 0; k0 < K; k0 += BK) {
        #pragma unroll
        for (int it = 0; it < 8; ++it) {
            int l = tid + it * 256;
            int m = l >> 5, kk = l & 31;
            float v = A[(size_t)(row0 + m) * K + k0 + kk];
            if (RELU_IN) v = fmaxf(v, 0.f);
            As[kk][m] = v;
        }
        #pragma unroll
        for (int it = 0; it < 8; ++it) {
            int l = tid + it * 256;
            int kk = l >> 6, n = l & 63;
            Bs[kk][n] = W[(size_t)(k0 + kk) * N + col0 + n];
        }
        __syncthreads();
        #pragma unroll
        for (int kk = 0; kk < BK; ++kk) {
            float4 av = *reinterpret_cast<const float4*>(&As[kk][tr * 4]);
            float4 bv = *reinterpret_cast<const float4*>(&Bs[kk][tc * 4]);
            float a[4] = {av.x, av.y, av.z, av.w};
            float b[4] = {bv.x, bv.y, bv.z, bv.w};
            #pragma unroll
            for (int i = 0; i < 4; i++)
                #pragma unroll
                for (int j = 0; j < 4; j++)
                    acc[i][j] = fmaf(a[i], b[j], acc[i][j]);
        }
        __syncthreads();
    }
    #pragma unroll
    for (int i = 0; i < 4; i++)
        #pragma unroll
        for (int j = 0; j < 4; j++) {
            int rr = row0 + tr * 4 + i, cc = col0 + tc * 4 + j;
            C[(size_t)rr * N + cc] = acc[i][j] + bias[cc];
        }
}

// ---------------------------------------------------------------------------
// Small row-matmul: out[r, 0..255] = act_in(in[r, 0..K)) @ W[K,256] + b
template<bool RELU_IN>
__global__ __launch_bounds__(256) void rowmm_kernel(
    const float* __restrict__ in, const float* __restrict__ W,
    const float* __restrict__ bias, float* __restrict__ out, int K) {
    extern __shared__ float srow[];
    int r = blockIdx.x, d = threadIdx.x;
    for (int k = d; k < K; k += 256) {
        float v = in[(size_t)r * K + k];
        if (RELU_IN) v = fmaxf(v, 0.f);
        srow[k] = v;
    }
    __syncthreads();
    float acc = bias[d];
    for (int k = 0; k < K; ++k)
        acc = fmaf(srow[k], W[(size_t)k * DD + d], acc);
    out[(size_t)r * DD + d] = acc;
}

// y[b,i,:] = relu( sum_j adj[b,i,j] * t[b,j,:] )
__global__ __launch_bounds__(256) void adjmul_relu_kernel(
    const float* __restrict__ adj, const float* __restrict__ t,
    float* __restrict__ y) {
    int b = blockIdx.x / NK, i = blockIdx.x % NK, d = threadIdx.x;
    __shared__ float arow[NK];
    if (d < NK) arow[d] = adj[((size_t)b * NK + i) * NK + d];
    __syncthreads();
    float acc = 0.f;
    #pragma unroll 8
    for (int j = 0; j < NK; ++j)
        acc = fmaf(arow[j], t[((size_t)b * NK + j) * DD + d], acc);
    y[((size_t)b * NK + i) * DD + d] = fmaxf(acc, 0.f);
}

// ---------------------------------------------------------------------------
// inter[b,i,k] = sigmoid( qp[b,i,:] . qc[b,k,:] ); atomic add batch sum
__global__ __launch_bounds__(256) void inter_kernel(
    const float* __restrict__ qp, const float* __restrict__ qc,
    float* __restrict__ inter, float* __restrict__ interSum) {
    int b = blockIdx.x / 125, chunk = blockIdx.x % 125;
    __shared__ float qcT[DD * 57];   // [d][k], pad 57
    int tid = threadIdx.x;
    for (int l = tid; l < NK * DD; l += 256) {
        int k = l / DD, d = l % DD;
        qcT[d * 57 + k] = qc[((size_t)b * NK + k) * DD + d];
    }
    __syncthreads();
    int wave = tid >> 6, lane = tid & 63;
    __shared__ float wsum[4];
    float lsum = 0.f;
    for (int ii = 0; ii < 2; ++ii) {
        int i = chunk * 8 + wave * 2 + ii;
        const float* qrow = qp + ((size_t)b * NP + i) * DD;
        if (lane < NK) {
            float acc = 0.f;
            for (int d = 0; d < DD; ++d)
                acc = fmaf(qrow[d], qcT[d * 57 + lane], acc);
            float sg = 1.f / (1.f + __expf(-acc));
            inter[((size_t)b * NP + i) * NK + lane] = sg;
            lsum += sg;
        }
    }
    #pragma unroll
    for (int off = 32; off; off >>= 1) lsum += __shfl_down(lsum, off);
    if (lane == 0) wsum[wave] = lsum;
    __syncthreads();
    if (tid == 0)
        atomicAdd(&interSum[b], wsum[0] + wsum[1] + wsum[2] + wsum[3]);
}

__global__ void normalize_inter_kernel(float* inter, const float* interSum) {
    int idx = blockIdx.x * 256 + threadIdx.x;
    if (idx < B * NP * NK) inter[idx] /= interSum[idx / (NP * NK)];
}

// per-row stats: s[b,i]=sum_k inter^2 ; l1Sum[b]+=sum inter ; bindSum[b]+=sum (inter-lab)^2
__global__ __launch_bounds__(256) void inter_stats_kernel(
    const float* __restrict__ inter, const float* __restrict__ prot_inter,
    const float* __restrict__ exist, float* __restrict__ s_bi,
    float* __restrict__ l1Sum, float* __restrict__ bindSum) {
    int b = blockIdx.x / 4, q = blockIdx.x % 4;
    int i = q * 250 + threadIdx.x;
    float l1 = 0.f, bind = 0.f;
    if (threadIdx.x < 250) {
        float ex = exist[b];
        float ss = 0.f;
        const float* row  = inter      + ((size_t)b * NP + i) * NK;
        const float* prow = prot_inter + ((size_t)b * NP + i) * NK;
        #pragma unroll 8
        for (int k = 0; k < NK; ++k) {
            float v = row[k];
            l1 += v; ss = fmaf(v, v, ss);
            float d = v - ex * prow[k];
            bind = fmaf(d, d, bind);
        }
        s_bi[b * NP + i] = ss;
    }
    __shared__ float r1[256], r2[256];
    r1[threadIdx.x] = l1; r2[threadIdx.x] = bind;
    __syncthreads();
    for (int s = 128; s; s >>= 1) {
        if (threadIdx.x < s) {
            r1[threadIdx.x] += r1[threadIdx.x + s];
            r2[threadIdx.x] += r2[threadIdx.x + s];
        }
        __syncthreads();
    }
    if (threadIdx.x == 0) {
        atomicAdd(&l1Sum[b], r1[0]);
        atomicAdd(&bindSum[b], r2[0]);
    }
}

// ---------------------------------------------------------------------------
// cp partials: part[b][chunk][d] = sum over 25 i's, 56 k's of tanh(prot*comp)*inter
__global__ __launch_bounds__(256) void cp_partial_kernel(
    const float* __restrict__ prot, const float* __restrict__ comp,
    const float* __restrict__ inter, float* __restrict__ part) {
    int b = blockIdx.x / 40, chunk = blockIdx.x % 40;
    int d = threadIdx.x;
    __shared__ float comp_s[NK * DD];   // 57 KB
    __shared__ float irow[NK];
    for (int l = d; l < NK * DD; l += 256)
        comp_s[l] = comp[(size_t)b * NK * DD + l];
    float acc = 0.f;
    for (int ii = 0; ii < 25; ++ii) {
        int i = chunk * 25 + ii;
        __syncthreads();
        if (d < NK) irow[d] = inter[((size_t)b * NP + i) * NK + d];
        __syncthreads();
        float p = prot[((size_t)b * NP + i) * DD + d];
        #pragma unroll 4
        for (int k = 0; k < NK; ++k) {
            float x = p * comp_s[k * DD + d];
            acc = fmaf(fast_tanh(x), irow[k], acc);
        }
    }
    part[((size_t)b * 40 + chunk) * DD + d] = acc;
}

__global__ void cp_reduce_kernel(const float* part, float* cp) {
    int b = blockIdx.x, d = threadIdx.x;
    float s = 0.f;
    for (int c = 0; c < 40; ++c) s += part[((size_t)b * 40 + c) * DD + d];
    cp[b * DD + d] = s;
}

// ---------------------------------------------------------------------------
// conv(k=4,s=2,pad=1) + bias + leaky + maxpool4 -> pooled[b][2048] (layout o*32+p)
__global__ __launch_bounds__(256) void conv_pool_kernel(
    const float* __restrict__ cp, const float* __restrict__ conv_w,
    const float* __restrict__ conv_b, float* __restrict__ pooled) {
    int b = blockIdx.x, t = threadIdx.x;
    __shared__ float x[258];
    __shared__ float convo[64 * 128];
    x[t + 1] = cp[b * DD + t];
    if (t == 0) { x[0] = 0.f; x[257] = 0.f; }
    __syncthreads();
    for (int l = t; l < 64 * 128; l += 256) {
        int o = l / 128, pos = l % 128;
        float acc = conv_b[o];
        int base = pos * 2;
        #pragma unroll
        for (int h = 0; h < 4; ++h)
            acc = fmaf(x[base + h], conv_w[o * 4 + h], acc);
        convo[l] = (acc > 0.f) ? acc : 0.1f * acc;
    }
    __syncthreads();
    for (int l = t; l < 64 * 32; l += 256) {
        int o = l / 32, p = l % 32;
        float m = -INFINITY;
        #pragma unroll
        for (int q = 0; q < 4; ++q)
            m = fmaxf(m, convo[o * 128 + p * 4 + q]);
        pooled[b * 2048 + l] = m;
    }
}

// ---------------------------------------------------------------------------
// FC partial: grid (o_tiles, k_splits). Stage in[b][kchunk] into LDS, 64
// outputs/block coalesced W loads, waves interleave k, 8 batch accumulators,
// LDS cross-wave reduce, atomicAdd into pre-zeroed raw[b*N+o].
__global__ __launch_bounds__(256) void fc_partial_kernel(
    const float* __restrict__ in, const float* __restrict__ W,
    float* __restrict__ raw, int K, int N, int kchunk) {
    int t = threadIdx.x;
    int ol = t & 63;
    int o = blockIdx.x * 64 + ol;
    int w = t >> 6;
    int kbeg = blockIdx.y * kchunk;
    int kend = kbeg + kchunk; if (kend > K) kend = K;
    int len = kend - kbeg;
    __shared__ float sin_[B][128];   // kchunk <= 128
    for (int l = t; l < B * len; l += 256) {
        int b = l / len, k = l % len;
        sin_[b][k] = in[(size_t)b * K + kbeg + k];
    }
    __syncthreads();
    float acc[B];
    #pragma unroll
    for (int b = 0; b < B; ++b) acc[b] = 0.f;
    if (o < N) {
        for (int k = kbeg + w; k < kend; k += 4) {
            float wv = W[(size_t)k * N + o];
            int kl = k - kbeg;
            #pragma unroll
            for (int b = 0; b < B; ++b)
                acc[b] = fmaf(sin_[b][kl], wv, acc[b]);
        }
    }
    __shared__ float red[4][64][B];
    #pragma unroll
    for (int b = 0; b < B; ++b) red[w][ol][b] = acc[b];
    __syncthreads();
    for (int p = t; p < 64 * B; p += 256) {
        int oo = p / B, b = p % B;
        int o2 = blockIdx.x * 64 + oo;
        if (o2 < N) {
            float s = red[0][oo][b] + red[1][oo][b] + red[2][oo][b] + red[3][oo][b];
            atomicAdd(&raw[(size_t)b * N + o2], s);
        }
    }
}

template<bool LEAKY>
__global__ void fc_finish_kernel(const float* __restrict__ raw,
                                 const float* __restrict__ bias,
                                 float* __restrict__ out, int N) {
    int idx = blockIdx.x * 256 + threadIdx.x;
    if (idx < B * N) {
        int b = idx / N, o = idx % N;
        float s = raw[(size_t)b * N + o] + bias[o];
        if (LEAKY) s = (s > 0.f) ? s : 0.1f * s;
        out[(size_t)b * N + o] = s;
    }
}

// fc3: N=1, K=300. One block, 8 waves, wave = batch, shuffle reduce.
__global__ __launch_bounds__(512) void fc3_kernel(
    const float* __restrict__ in, const float* __restrict__ W,
    const float* __restrict__ bias, float* __restrict__ affn) {
    int wv = threadIdx.x >> 6, lane = threadIdx.x & 63;
    float acc = 0.f;
    for (int k = lane; k < 300; k += 64)
        acc = fmaf(in[(size_t)wv * 300 + k], W[k], acc);
    #pragma unroll
    for (int off = 32; off; off >>= 1) acc += __shfl_down(acc, off);
    if (lane == 0) affn[wv] = acc + bias[0];
}

// ---------------------------------------------------------------------------
// fused regularizer, stage 1: transpose inter -> interT[(b*56+j)][i] (448x1000)
__global__ __launch_bounds__(256) void transpose_inter_kernel(
    const float* __restrict__ inter, float* __restrict__ interT) {
    __shared__ float tile[32][33];
    int i0 = blockIdx.x * 32;        // 32 i-tiles
    int j0 = blockIdx.y * 32;        // 2 j-tiles (56)
    int b  = blockIdx.z;
    int tx = threadIdx.x & 31, ty = threadIdx.x >> 5;
    for (int r = ty; r < 32; r += 8) {
        int i = i0 + r, j = j0 + tx;
        tile[r][tx] = (i < NP && j < NK) ? inter[((size_t)b * NP + i) * NK + j] : 0.f;
    }
    __syncthreads();
    for (int r = ty; r < 32; r += 8) {
        int j = j0 + r, i = i0 + tx;
        if (j < NK && i < NP)
            interT[(size_t)(b * NK + j) * NP + i] = tile[tx][r];
    }
}

// fused stage 2: E[448][999] = interT @ fused^T, K split in 4 chunks of 250.
// Epart[ks][448][1024] tiles written privately (no atomics, deterministic).
__global__ __launch_bounds__(256) void fusedE_gemm_kernel(
    const float* __restrict__ interT,   // [448][1000]
    const float* __restrict__ fusedM,   // [999][1000]
    float* __restrict__ Epart) {        // [4][448][1024]
    const int BK = 50;
    int m0  = blockIdx.x * 64;          // 7 tiles (448)
    int t0  = blockIdx.y * 64;          // 16 tiles (999 pad 1024)
    int ks  = blockIdx.z;               // 4 k-chunks of 250
    int kbase = ks * 250;
    int tid = threadIdx.x;
    int tr = tid >> 4, tc = tid & 15;
    __shared__ float As[BK][68];        // [kk][m_local]
    __shared__ float Bs[BK][68];        // [kk][t_local]
    float acc[4][4] = {};
    for (int step = 0; step < 5; ++step) {
        int i0 = kbase + step * BK;
        for (int l = tid; l < 64 * BK; l += 256) {
            int ml = l / BK, kk = l % BK;
            As[kk][ml] = interT[(size_t)(m0 + ml) * NP + i0 + kk];
        }
        for (int l = tid; l < 64 * BK; l += 256) {
            int tl = l / BK, kk = l % BK;
            int t = t0 + tl;
            Bs[kk][tl] = (t < NT) ? fusedM[(size_t)t * NP + i0 + kk] : 0.f;
        }
        __syncthreads();
        #pragma unroll 10
        for (int kk = 0; kk < BK; ++kk) {
            float4 av = *reinterpret_cast<const float4*>(&As[kk][tr * 4]);
            float4 bv = *reinterpret_cast<const float4*>(&Bs[kk][tc * 4]);
            float a[4] = {av.x, av.y, av.z, av.w};
            float bb[4] = {bv.x, bv.y, bv.z, bv.w};
            #pragma unroll
            for (int i = 0; i < 4; i++)
                #pragma unroll
                for (int j = 0; j < 4; j++)
                    acc[i][j] = fmaf(a[i], bb[j], acc[i][j]);
        }
        __syncthreads();
    }
    #pragma unroll
    for (int i = 0; i < 4; i++) {
        size_t row = (size_t)ks * 448 + m0 + tr * 4 + i;
        *reinterpret_cast<float4*>(&Epart[row * 1024 + t0 + tc * 4]) =
            make_float4(acc[i][0], acc[i][1], acc[i][2], acc[i][3]);
    }
}

// fused stage 3: fusedAbs[b] += sum_t | sum_ks Epart[ks][row][t] |  (row=b*56+j)
__global__ __launch_bounds__(256) void fusedE_abs_kernel(
    const float* __restrict__ Epart, float* __restrict__ fusedAbs) {
    int row = blockIdx.x;               // 0..447
    int b = row / NK;
    const size_t KS = (size_t)448 * 1024;
    const float* p = Epart + (size_t)row * 1024;
    float s = 0.f;
    for (int t = threadIdx.x; t < NT; t += 256) {
        float v = p[t] + p[KS + t] + p[2 * KS + t] + p[3 * KS + t];
        s += fabsf(v);
    }
    __shared__ float r[256];
    r[threadIdx.x] = s;
    __syncthreads();
    for (int st = 128; st; st >>= 1) {
        if (threadIdx.x < st) r[threadIdx.x] += r[threadIdx.x + st];
        __syncthreads();
    }
    if (threadIdx.x == 0) atomicAdd(&fusedAbs[b], r[0]);
}

// ---------------------------------------------------------------------------
// group: one wave per (b,k): g = contacts[b,k,:] . s[b,:], rs = row sum
__global__ __launch_bounds__(64) void group_kernel(
    const float* __restrict__ contacts, const float* __restrict__ s_bi,
    float* __restrict__ group_val) {
    int bk = blockIdx.x;
    int b = bk / NP, k = bk % NP;
    const float* row = contacts + ((size_t)b * NP + k) * NP;
    const float* sv = s_bi + b * NP;
    float g = 0.f, rs = 0.f;
    for (int i = threadIdx.x; i < NP; i += 64) {
        float c = row[i];
        g = fmaf(c, sv[i], g);
        rs += c;
    }
    #pragma unroll
    for (int off = 32; off; off >>= 1) {
        g += __shfl_down(g, off);
        rs += __shfl_down(rs, off);
    }
    if (threadIdx.x == 0) {
        if (g == 0.f) g += 1e10f;
        group_val[bk] = sqrtf(g) * sqrtf(rs);
    }
}

__global__ __launch_bounds__(256) void reduce1000_kernel(const float* in, float* out) {
    int b = blockIdx.x;
    float s = 0.f;
    for (int l = threadIdx.x; l < NP; l += 256) s += in[b * NP + l];
    __shared__ float r[256];
    r[threadIdx.x] = s;
    __syncthreads();
    for (int st = 128; st; st >>= 1) {
        if (threadIdx.x < st) r[threadIdx.x] += r[threadIdx.x + st];
        __syncthreads();
    }
    if (threadIdx.x == 0) out[b] = r[0];
}

// accums layout: [0..8)=interSum [8..16)=l1Sum [16..24)=bindSum [24..32)=fusedAbs [32..40)=groupReg
__global__ void final_kernel(const float* __restrict__ accums,
                             const float* __restrict__ affn,
                             const float* __restrict__ label,
                             float* __restrict__ out) {
    if (threadIdx.x == 0 && blockIdx.x == 0) {
        float l0 = 0.f, l1 = 0.f, l2 = 0.f;
        for (int b = 0; b < B; ++b) {
            l0 += accums[8 + b] + accums[24 + b] + accums[32 + b];
            l1 += sqrtf(accums[16 + b]);
            float d = affn[b] - label[b];
            l2 += d * d;
        }
        out[0] = (l0 + l1 + l2) * 0.125f;
    }
}

// ---------------------------------------------------------------------------
extern "C" void kernel_launch(void* const* d_in, const int* in_sizes, int n_in,
                              void* d_out, int out_size, void* d_ws, size_t ws_size,
                              hipStream_t stream) {
    const float* prot_data   = (const float*)d_in[0];
    const float* drug_ver    = (const float*)d_in[1];
    const float* drug_adj    = (const float*)d_in[2];
    const float* contacts    = (const float*)d_in[3];
    const float* prot_inter  = (const float*)d_in[4];
    const float* exist       = (const float*)d_in[5];
    const float* label       = (const float*)d_in[6];
    const float* fused       = (const float*)d_in[7];
    const float* W_prot      = (const float*)d_in[8];
    const float* b_prot      = (const float*)d_in[9];
    const float* gcn_W0      = (const float*)d_in[10];
    const float* gcn_b0      = (const float*)d_in[11];
    const float* gcn_W1      = (const float*)d_in[12];
    const float* gcn_b1      = (const float*)d_in[13];
    const float* gcn_W2      = (const float*)d_in[14];
    const float* gcn_b2      = (const float*)d_in[15];
    const float* gcn_Wf      = (const float*)d_in[16];
    const float* gcn_bf      = (const float*)d_in[17];
    const float* Wjp         = (const float*)d_in[18];
    const float* bjp         = (const float*)d_in[19];
    const float* Wjc         = (const float*)d_in[20];
    const float* bjc         = (const float*)d_in[21];
    const float* conv_w      = (const float*)d_in[22];
    const float* conv_b      = (const float*)d_in[23];
    const float* W_r1        = (const float*)d_in[24];
    const float* b_r1        = (const float*)d_in[25];
    const float* W_r2        = (const float*)d_in[26];
    const float* b_r2        = (const float*)d_in[27];
    const float* W_r3        = (const float*)d_in[28];
    const float* b_r3        = (const float*)d_in[29];

    float* ws = (float*)d_ws;
    size_t off = 0;
    auto alloc = [&](size_t n) { float* p = ws + off; off += n; return p; };
    float* prot     = alloc((size_t)B * NP * DD);   // 2,048,000
    float* qp       = alloc((size_t)B * NP * DD);   // 2,048,000
    float* tbuf     = alloc((size_t)B * NK * DD);
    float* ybuf     = alloc((size_t)B * NK * DD);
    float* comp     = alloc((size_t)B * NK * DD);
    float* qc       = alloc((size_t)B * NK * DD);
    float* inter    = alloc((size_t)B * NP * NK);   // 448,000
    float* s_bi     = alloc((size_t)B * NP);
    float* cp_part  = alloc((size_t)B * 40 * DD);
    float* cp       = alloc((size_t)B * DD);
    float* pooled   = alloc((size_t)B * 2048);
    float* fc1      = alloc((size_t)B * 600);
    float* fc2      = alloc((size_t)B * 300);
    float* affn     = alloc((size_t)B);
    float* groupv   = alloc((size_t)B * NP);
    // zero-region: accums, raw1, raw2 contiguous
    float* accums   = alloc(40);
    float* raw1     = alloc((size_t)B * 600);
    float* raw2     = alloc((size_t)B * 300);

    // Aliases (lifetime-disjoint reuse, no extra workspace):
    //   interT[448][1000]  lives in qp   (qp dead after inter_kernel)
    //   Epart[4][448][1024] lives in prot (prot dead after cp_partial)
    float* interT = qp;     // 448,000 <= 2,048,000
    float* Epart  = prot;   // 1,835,008 <= 2,048,000

    // zero the atomic-accumulated buffers (accums, raw1, raw2 contiguous)
    hipMemsetAsync(accums, 0,
        (40 + (size_t)B * 600 + (size_t)B * 300) * sizeof(float), stream);

    // prot = prot_data @ W_prot + b_prot
    gemm_bias_kernel<false><<<dim3(125, 4), 256, 0, stream>>>(
        prot_data, W_prot, b_prot, prot, B * NP, DD, DP);

    // GCN stack
    rowmm_kernel<false><<<B * NK, 256, DV * sizeof(float), stream>>>(drug_ver, gcn_W0, gcn_b0, tbuf, DV);
    adjmul_relu_kernel<<<B * NK, 256, 0, stream>>>(drug_adj, tbuf, ybuf);
    rowmm_kernel<false><<<B * NK, 256, DD * sizeof(float), stream>>>(ybuf, gcn_W1, gcn_b1, tbuf, DD);
    adjmul_relu_kernel<<<B * NK, 256, 0, stream>>>(drug_adj, tbuf, ybuf);
    rowmm_kernel<false><<<B * NK, 256, DD * sizeof(float), stream>>>(ybuf, gcn_W2, gcn_b2, tbuf, DD);
    adjmul_relu_kernel<<<B * NK, 256, 0, stream>>>(drug_adj, tbuf, ybuf);
    rowmm_kernel<false><<<B * NK, 256, DD * sizeof(float), stream>>>(ybuf, gcn_Wf, gcn_bf, comp, DD);
    rowmm_kernel<true ><<<B * NK, 256, DD * sizeof(float), stream>>>(comp, Wjc, bjc, qc, DD);

    // qp = relu(prot) @ Wjp + bjp
    gemm_bias_kernel<true><<<dim3(125, 4), 256, 0, stream>>>(
        prot, Wjp, bjp, qp, B * NP, DD, DD);

    // inter + normalization  (last use of qp)
    inter_kernel<<<B * 125, 256, 0, stream>>>(qp, qc, inter, accums + 0);
    normalize_inter_kernel<<<(B * NP * NK + 255) / 256, 256, 0, stream>>>(inter, accums + 0);
    inter_stats_kernel<<<B * 4, 256, 0, stream>>>(inter, prot_inter, exist, s_bi,
                                                  accums + 8, accums + 16);

    // cp contraction (last use of prot)
    cp_partial_kernel<<<B * 40, 256, 0, stream>>>(prot, comp, inter, cp_part);
    cp_reduce_kernel<<<B, 256, 0, stream>>>(cp_part, cp);

    // fused regularizer: transpose -> k-split GEMM -> abs reduce
    transpose_inter_kernel<<<dim3(32, 2, B), 256, 0, stream>>>(inter, interT);
    fusedE_gemm_kernel<<<dim3(7, 16, 4), 256, 0, stream>>>(interT, fused, Epart);
    fusedE_abs_kernel<<<448, 256, 0, stream>>>(Epart, accums + 24);

    // conv / pool / FCs
    conv_pool_kernel<<<B, 256, 0, stream>>>(cp, conv_w, conv_b, pooled);
    fc_partial_kernel<<<dim3(10, 16), 256, 0, stream>>>(pooled, W_r1, raw1, 2048, 600, 128);
    fc_finish_kernel<true><<<(B * 600 + 255) / 256, 256, 0, stream>>>(raw1, b_r1, fc1, 600);
    fc_partial_kernel<<<dim3(5, 8), 256, 0, stream>>>(fc1, W_r2, raw2, 600, 300, 75);
    fc_finish_kernel<true><<<(B * 300 + 255) / 256, 256, 0, stream>>>(raw2, b_r2, fc2, 300);
    fc3_kernel<<<1, 512, 0, stream>>>(fc2, W_r3, b_r3, affn);

    // group regularizer
    group_kernel<<<B * NP, 64, 0, stream>>>(contacts, s_bi, groupv);
    reduce1000_kernel<<<B, 256, 0, stream>>>(groupv, accums + 32);

    // final loss
    final_kernel<<<1, 64, 0, stream>>>(accums, affn, label, (float*)d_out);
}

// Round 6
// 351.943 us; speedup vs baseline: 4.5186x; 1.1660x over previous
//
#include <hip/hip_runtime.h>
#include <hip/hip_bf16.h>
#include <math.h>

// ---------------------------------------------------------------------------
// Sizes (fixed by the reference)
#define B 8
#define NP 1000        // protein length
#define NK 56          // drug vertices
#define DP 768         // prot_data feature
#define DV 43          // drug vertex feature
#define DD 256         // D
#define NT 999         // fused_matrix rows

// ---------------------------------------------------------------------------
// Tiled f32 GEMM: C[M,N] = act_in(A[M,K]) @ W[K,N] + bias[N]
// BM=BN=64, BK=32, 256 threads, 4x4 micro-tile, float4 LDS fragment reads.
// M%64==0, N%64==0, K%32==0.
template<bool RELU_IN>
__global__ __launch_bounds__(256) void gemm_bias_kernel(
    const float* __restrict__ A, const float* __restrict__ W,
    const float* __restrict__ bias, float* __restrict__ C,
    int M, int N, int K) {
    const int BM = 64, BN = 64, BK = 32;
    __shared__ float As[BK][68];   // [kk][m], pad 68 keeps 16B alignment
    __shared__ float Bs[BK][68];   // [kk][n]
    int bm = blockIdx.x, bn = blockIdx.y;
    int tid = threadIdx.x;
    int tr = tid >> 4, tc = tid & 15;
    float acc[4][4] = {};
    int row0 = bm * BM, col0 = bn * BN;
    for (int k0 = 0; k0 < K; k0 += BK) {
        #pragma unroll
        for (int it = 0; it < 8; ++it) {
            int l = tid + it * 256;
            int m = l >> 5, kk = l & 31;
            float v = A[(size_t)(row0 + m) * K + k0 + kk];
            if (RELU_IN) v = fmaxf(v, 0.f);
            As[kk][m] = v;
        }
        #pragma unroll
        for (int it = 0; it < 8; ++it) {
            int l = tid + it * 256;
            int kk = l >> 6, n = l & 63;
            Bs[kk][n] = W[(size_t)(k0 + kk) * N + col0 + n];
        }
        __syncthreads();
        #pragma unroll
        for (int kk = 0; kk < BK; ++kk) {
            float4 av = *reinterpret_cast<const float4*>(&As[kk][tr * 4]);
            float4 bv = *reinterpret_cast<const float4*>(&Bs[kk][tc * 4]);
            float a[4] = {av.x, av.y, av.z, av.w};
            float b[4] = {bv.x, bv.y, bv.z, bv.w};
            #pragma unroll
            for (int i = 0; i < 4; i++)
                #pragma unroll
                for (int j = 0; j < 4; j++)
                    acc[i][j] = fmaf(a[i], b[j], acc[i][j]);
        }
        __syncthreads();
    }
    #pragma unroll
    for (int i = 0; i < 4; i++)
        #pragma unroll
        for (int j = 0; j < 4; j++) {
            int rr = row0 + tr * 4 + i, cc = col0 + tc * 4 + j;
            C[(size_t)rr * N + cc] = acc[i][j] + bias[cc];
        }
}

// ---------------------------------------------------------------------------
// Small row-matmul: out[r, 0..255] = act_in(in[r, 0..K)) @ W[K,256] + b
template<bool RELU_IN>
__global__ __launch_bounds__(256) void rowmm_kernel(
    const float* __restrict__ in, const float* __restrict__ W,
    const float* __restrict__ bias, float* __restrict__ out, int K) {
    extern __shared__ float srow[];
    int r = blockIdx.x, d = threadIdx.x;
    for (int k = d; k < K; k += 256) {
        float v = in[(size_t)r * K + k];
        if (RELU_IN) v = fmaxf(v, 0.f);
        srow[k] = v;
    }
    __syncthreads();
    float acc = bias[d];
    for (int k = 0; k < K; ++k)
        acc = fmaf(srow[k], W[(size_t)k * DD + d], acc);
    out[(size_t)r * DD + d] = acc;
}

// y[b,i,:] = relu( sum_j adj[b,i,j] * t[b,j,:] )
__global__ __launch_bounds__(256) void adjmul_relu_kernel(
    const float* __restrict__ adj, const float* __restrict__ t,
    float* __restrict__ y) {
    int b = blockIdx.x / NK, i = blockIdx.x % NK, d = threadIdx.x;
    __shared__ float arow[NK];
    if (d < NK) arow[d] = adj[((size_t)b * NK + i) * NK + d];
    __syncthreads();
    float acc = 0.f;
    #pragma unroll 8
    for (int j = 0; j < NK; ++j)
        acc = fmaf(arow[j], t[((size_t)b * NK + j) * DD + d], acc);
    y[((size_t)b * NK + i) * DD + d] = fmaxf(acc, 0.f);
}

// ---------------------------------------------------------------------------
// inter[b,i,k] = sigmoid( qp[b,i,:] . qc[b,k,:] ); atomic add batch sum
__global__ __launch_bounds__(256) void inter_kernel(
    const float* __restrict__ qp, const float* __restrict__ qc,
    float* __restrict__ inter, float* __restrict__ interSum) {
    int b = blockIdx.x / 125, chunk = blockIdx.x % 125;
    __shared__ float qcT[DD * 57];   // [d][k], pad 57
    int tid = threadIdx.x;
    for (int l = tid; l < NK * DD; l += 256) {
        int k = l / DD, d = l % DD;
        qcT[d * 57 + k] = qc[((size_t)b * NK + k) * DD + d];
    }
    __syncthreads();
    int wave = tid >> 6, lane = tid & 63;
    __shared__ float wsum[4];
    float lsum = 0.f;
    for (int ii = 0; ii < 2; ++ii) {
        int i = chunk * 8 + wave * 2 + ii;
        const float* qrow = qp + ((size_t)b * NP + i) * DD;
        if (lane < NK) {
            float acc = 0.f;
            for (int d = 0; d < DD; ++d)
                acc = fmaf(qrow[d], qcT[d * 57 + lane], acc);
            float sg = 1.f / (1.f + __expf(-acc));
            inter[((size_t)b * NP + i) * NK + lane] = sg;
            lsum += sg;
        }
    }
    #pragma unroll
    for (int off = 32; off; off >>= 1) lsum += __shfl_down(lsum, off);
    if (lane == 0) wsum[wave] = lsum;
    __syncthreads();
    if (tid == 0)
        atomicAdd(&interSum[b], wsum[0] + wsum[1] + wsum[2] + wsum[3]);
}

__global__ void normalize_inter_kernel(float* inter, const float* interSum) {
    int idx = blockIdx.x * 256 + threadIdx.x;
    if (idx < B * NP * NK) inter[idx] /= interSum[idx / (NP * NK)];
}

// per-row stats: s[b,i]=sum_k inter^2 ; l1Sum[b]+=sum inter ; bindSum[b]+=sum (inter-lab)^2
__global__ __launch_bounds__(256) void inter_stats_kernel(
    const float* __restrict__ inter, const float* __restrict__ prot_inter,
    const float* __restrict__ exist, float* __restrict__ s_bi,
    float* __restrict__ l1Sum, float* __restrict__ bindSum) {
    int b = blockIdx.x / 4, q = blockIdx.x % 4;
    int i = q * 250 + threadIdx.x;
    float l1 = 0.f, bind = 0.f;
    if (threadIdx.x < 250) {
        float ex = exist[b];
        float ss = 0.f;
        const float* row  = inter      + ((size_t)b * NP + i) * NK;
        const float* prow = prot_inter + ((size_t)b * NP + i) * NK;
        #pragma unroll 8
        for (int k = 0; k < NK; ++k) {
            float v = row[k];
            l1 += v; ss = fmaf(v, v, ss);
            float d = v - ex * prow[k];
            bind = fmaf(d, d, bind);
        }
        s_bi[b * NP + i] = ss;
    }
    __shared__ float r1[256], r2[256];
    r1[threadIdx.x] = l1; r2[threadIdx.x] = bind;
    __syncthreads();
    for (int s = 128; s; s >>= 1) {
        if (threadIdx.x < s) {
            r1[threadIdx.x] += r1[threadIdx.x + s];
            r2[threadIdx.x] += r2[threadIdx.x + s];
        }
        __syncthreads();
    }
    if (threadIdx.x == 0) {
        atomicAdd(&l1Sum[b], r1[0]);
        atomicAdd(&bindSum[b], r2[0]);
    }
}

// ---------------------------------------------------------------------------
// cp partials, v2: grid (B*125 chunks of 8 i's, 2 d-halves), 128 threads.
// LDS 30KB -> 5 blocks/CU. tanh via exp + HW rcp: t = 1 - 2/(e^{2x}+1).
__global__ __launch_bounds__(128) void cp_partial_kernel(
    const float* __restrict__ prot, const float* __restrict__ comp,
    const float* __restrict__ inter, float* __restrict__ part) {
    int bc = blockIdx.x;
    int b = bc / 125, chunk = bc % 125;
    int dh = blockIdx.y;
    int tid = threadIdx.x;
    int d = dh * 128 + tid;
    __shared__ float comp_s[NK][128];
    __shared__ float irow[8][NK];
    for (int l = tid; l < NK * 128; l += 128) {
        int k = l >> 7, dd = l & 127;
        comp_s[k][dd] = comp[((size_t)b * NK + k) * DD + dh * 128 + dd];
    }
    for (int l = tid; l < 8 * NK; l += 128) {
        int ii = l / NK, k = l % NK;
        irow[ii][k] = inter[((size_t)b * NP + chunk * 8 + ii) * NK + k];
    }
    // preload 8 prot values (independent loads in flight), fold in the 2x
    float p2[8];
    #pragma unroll
    for (int ii = 0; ii < 8; ++ii)
        p2[ii] = 2.f * prot[((size_t)b * NP + chunk * 8 + ii) * DD + d];
    __syncthreads();
    float acc0 = 0.f, acc1 = 0.f;
    for (int ii = 0; ii < 8; ++ii) {
        float p = p2[ii];
        #pragma unroll 8
        for (int k = 0; k < NK; k += 2) {
            float x0 = fminf(fmaxf(p * comp_s[k][tid],     -30.f), 30.f);
            float x1 = fminf(fmaxf(p * comp_s[k + 1][tid], -30.f), 30.f);
            float r0 = __builtin_amdgcn_rcpf(__expf(x0) + 1.f);
            float r1 = __builtin_amdgcn_rcpf(__expf(x1) + 1.f);
            acc0 = fmaf(fmaf(-2.f, r0, 1.f), irow[ii][k],     acc0);
            acc1 = fmaf(fmaf(-2.f, r1, 1.f), irow[ii][k + 1], acc1);
        }
    }
    part[((size_t)b * 125 + chunk) * DD + d] = acc0 + acc1;
}

__global__ void cp_reduce_kernel(const float* part, float* cp) {
    int b = blockIdx.x, d = threadIdx.x;
    float s = 0.f;
    for (int c = 0; c < 125; ++c) s += part[((size_t)b * 125 + c) * DD + d];
    cp[b * DD + d] = s;
}

// ---------------------------------------------------------------------------
// conv(k=4,s=2,pad=1) + bias + leaky + maxpool4 -> pooled[b][2048] (layout o*32+p)
__global__ __launch_bounds__(256) void conv_pool_kernel(
    const float* __restrict__ cp, const float* __restrict__ conv_w,
    const float* __restrict__ conv_b, float* __restrict__ pooled) {
    int b = blockIdx.x, t = threadIdx.x;
    __shared__ float x[258];
    __shared__ float convo[64 * 128];
    x[t + 1] = cp[b * DD + t];
    if (t == 0) { x[0] = 0.f; x[257] = 0.f; }
    __syncthreads();
    for (int l = t; l < 64 * 128; l += 256) {
        int o = l / 128, pos = l % 128;
        float acc = conv_b[o];
        int base = pos * 2;
        #pragma unroll
        for (int h = 0; h < 4; ++h)
            acc = fmaf(x[base + h], conv_w[o * 4 + h], acc);
        convo[l] = (acc > 0.f) ? acc : 0.1f * acc;
    }
    __syncthreads();
    for (int l = t; l < 64 * 32; l += 256) {
        int o = l / 32, p = l % 32;
        float m = -INFINITY;
        #pragma unroll
        for (int q = 0; q < 4; ++q)
            m = fmaxf(m, convo[o * 128 + p * 4 + q]);
        pooled[b * 2048 + l] = m;
    }
}

// ---------------------------------------------------------------------------
// FC partial: grid (o_tiles, k_splits). Stage in[b][kchunk] into LDS, 64
// outputs/block coalesced W loads, waves interleave k, 8 batch accumulators,
// LDS cross-wave reduce, atomicAdd into pre-zeroed raw[b*N+o].
__global__ __launch_bounds__(256) void fc_partial_kernel(
    const float* __restrict__ in, const float* __restrict__ W,
    float* __restrict__ raw, int K, int N, int kchunk) {
    int t = threadIdx.x;
    int ol = t & 63;
    int o = blockIdx.x * 64 + ol;
    int w = t >> 6;
    int kbeg = blockIdx.y * kchunk;
    int kend = kbeg + kchunk; if (kend > K) kend = K;
    int len = kend - kbeg;
    __shared__ float sin_[B][128];   // kchunk <= 128
    for (int l = t; l < B * len; l += 256) {
        int b = l / len, k = l % len;
        sin_[b][k] = in[(size_t)b * K + kbeg + k];
    }
    __syncthreads();
    float acc[B];
    #pragma unroll
    for (int b = 0; b < B; ++b) acc[b] = 0.f;
    if (o < N) {
        for (int k = kbeg + w; k < kend; k += 4) {
            float wv = W[(size_t)k * N + o];
            int kl = k - kbeg;
            #pragma unroll
            for (int b = 0; b < B; ++b)
                acc[b] = fmaf(sin_[b][kl], wv, acc[b]);
        }
    }
    __shared__ float red[4][64][B];
    #pragma unroll
    for (int b = 0; b < B; ++b) red[w][ol][b] = acc[b];
    __syncthreads();
    for (int p = t; p < 64 * B; p += 256) {
        int oo = p / B, b = p % B;
        int o2 = blockIdx.x * 64 + oo;
        if (o2 < N) {
            float s = red[0][oo][b] + red[1][oo][b] + red[2][oo][b] + red[3][oo][b];
            atomicAdd(&raw[(size_t)b * N + o2], s);
        }
    }
}

template<bool LEAKY>
__global__ void fc_finish_kernel(const float* __restrict__ raw,
                                 const float* __restrict__ bias,
                                 float* __restrict__ out, int N) {
    int idx = blockIdx.x * 256 + threadIdx.x;
    if (idx < B * N) {
        int b = idx / N, o = idx % N;
        float s = raw[(size_t)b * N + o] + bias[o];
        if (LEAKY) s = (s > 0.f) ? s : 0.1f * s;
        out[(size_t)b * N + o] = s;
    }
}

// fc3: N=1, K=300. One block, 8 waves, wave = batch, shuffle reduce.
__global__ __launch_bounds__(512) void fc3_kernel(
    const float* __restrict__ in, const float* __restrict__ W,
    const float* __restrict__ bias, float* __restrict__ affn) {
    int wv = threadIdx.x >> 6, lane = threadIdx.x & 63;
    float acc = 0.f;
    for (int k = lane; k < 300; k += 64)
        acc = fmaf(in[(size_t)wv * 300 + k], W[k], acc);
    #pragma unroll
    for (int off = 32; off; off >>= 1) acc += __shfl_down(acc, off);
    if (lane == 0) affn[wv] = acc + bias[0];
}

// ---------------------------------------------------------------------------
// fused regularizer, stage 1: transpose inter -> interT[(b*56+j)][i] (448x1000)
__global__ __launch_bounds__(256) void transpose_inter_kernel(
    const float* __restrict__ inter, float* __restrict__ interT) {
    __shared__ float tile[32][33];
    int i0 = blockIdx.x * 32;        // 32 i-tiles
    int j0 = blockIdx.y * 32;        // 2 j-tiles (56)
    int b  = blockIdx.z;
    int tx = threadIdx.x & 31, ty = threadIdx.x >> 5;
    for (int r = ty; r < 32; r += 8) {
        int i = i0 + r, j = j0 + tx;
        tile[r][tx] = (i < NP && j < NK) ? inter[((size_t)b * NP + i) * NK + j] : 0.f;
    }
    __syncthreads();
    for (int r = ty; r < 32; r += 8) {
        int j = j0 + r, i = i0 + tx;
        if (j < NK && i < NP)
            interT[(size_t)(b * NK + j) * NP + i] = tile[tx][r];
    }
}

// fused stage 2: E[448][999] = interT @ fused^T, K split in 4 chunks of 250.
// Epart[ks][448][1024] tiles written privately (no atomics, deterministic).
__global__ __launch_bounds__(256) void fusedE_gemm_kernel(
    const float* __restrict__ interT,   // [448][1000]
    const float* __restrict__ fusedM,   // [999][1000]
    float* __restrict__ Epart) {        // [4][448][1024]
    const int BK = 50;
    int m0  = blockIdx.x * 64;          // 7 tiles (448)
    int t0  = blockIdx.y * 64;          // 16 tiles (999 pad 1024)
    int ks  = blockIdx.z;               // 4 k-chunks of 250
    int kbase = ks * 250;
    int tid = threadIdx.x;
    int tr = tid >> 4, tc = tid & 15;
    __shared__ float As[BK][68];        // [kk][m_local]
    __shared__ float Bs[BK][68];        // [kk][t_local]
    float acc[4][4] = {};
    for (int step = 0; step < 5; ++step) {
        int i0 = kbase + step * BK;
        for (int l = tid; l < 64 * BK; l += 256) {
            int ml = l / BK, kk = l % BK;
            As[kk][ml] = interT[(size_t)(m0 + ml) * NP + i0 + kk];
        }
        for (int l = tid; l < 64 * BK; l += 256) {
            int tl = l / BK, kk = l % BK;
            int t = t0 + tl;
            Bs[kk][tl] = (t < NT) ? fusedM[(size_t)t * NP + i0 + kk] : 0.f;
        }
        __syncthreads();
        #pragma unroll 10
        for (int kk = 0; kk < BK; ++kk) {
            float4 av = *reinterpret_cast<const float4*>(&As[kk][tr * 4]);
            float4 bv = *reinterpret_cast<const float4*>(&Bs[kk][tc * 4]);
            float a[4] = {av.x, av.y, av.z, av.w};
            float bb[4] = {bv.x, bv.y, bv.z, bv.w};
            #pragma unroll
            for (int i = 0; i < 4; i++)
                #pragma unroll
                for (int j = 0; j < 4; j++)
                    acc[i][j] = fmaf(a[i], bb[j], acc[i][j]);
        }
        __syncthreads();
    }
    #pragma unroll
    for (int i = 0; i < 4; i++) {
        size_t row = (size_t)ks * 448 + m0 + tr * 4 + i;
        *reinterpret_cast<float4*>(&Epart[row * 1024 + t0 + tc * 4]) =
            make_float4(acc[i][0], acc[i][1], acc[i][2], acc[i][3]);
    }
}

// fused stage 3: fusedAbs[b] += sum_t | sum_ks Epart[ks][row][t] |  (row=b*56+j)
__global__ __launch_bounds__(256) void fusedE_abs_kernel(
    const float* __restrict__ Epart, float* __restrict__ fusedAbs) {
    int row = blockIdx.x;               // 0..447
    int b = row / NK;
    const size_t KS = (size_t)448 * 1024;
    const float* p = Epart + (size_t)row * 1024;
    float s = 0.f;
    for (int t = threadIdx.x; t < NT; t += 256) {
        float v = p[t] + p[KS + t] + p[2 * KS + t] + p[3 * KS + t];
        s += fabsf(v);
    }
    __shared__ float r[256];
    r[threadIdx.x] = s;
    __syncthreads();
    for (int st = 128; st; st >>= 1) {
        if (threadIdx.x < st) r[threadIdx.x] += r[threadIdx.x + st];
        __syncthreads();
    }
    if (threadIdx.x == 0) atomicAdd(&fusedAbs[b], r[0]);
}

// ---------------------------------------------------------------------------
// group: one wave per (b,k): g = contacts[b,k,:] . s[b,:], rs = row sum
__global__ __launch_bounds__(64) void group_kernel(
    const float* __restrict__ contacts, const float* __restrict__ s_bi,
    float* __restrict__ group_val) {
    int bk = blockIdx.x;
    int b = bk / NP, k = bk % NP;
    const float* row = contacts + ((size_t)b * NP + k) * NP;
    const float* sv = s_bi + b * NP;
    float g = 0.f, rs = 0.f;
    for (int i = threadIdx.x; i < NP; i += 64) {
        float c = row[i];
        g = fmaf(c, sv[i], g);
        rs += c;
    }
    #pragma unroll
    for (int off = 32; off; off >>= 1) {
        g += __shfl_down(g, off);
        rs += __shfl_down(rs, off);
    }
    if (threadIdx.x == 0) {
        if (g == 0.f) g += 1e10f;
        group_val[bk] = sqrtf(g) * sqrtf(rs);
    }
}

__global__ __launch_bounds__(256) void reduce1000_kernel(const float* in, float* out) {
    int b = blockIdx.x;
    float s = 0.f;
    for (int l = threadIdx.x; l < NP; l += 256) s += in[b * NP + l];
    __shared__ float r[256];
    r[threadIdx.x] = s;
    __syncthreads();
    for (int st = 128; st; st >>= 1) {
        if (threadIdx.x < st) r[threadIdx.x] += r[threadIdx.x + st];
        __syncthreads();
    }
    if (threadIdx.x == 0) out[b] = r[0];
}

// accums layout: [0..8)=interSum [8..16)=l1Sum [16..24)=bindSum [24..32)=fusedAbs [32..40)=groupReg
__global__ void final_kernel(const float* __restrict__ accums,
                             const float* __restrict__ affn,
                             const float* __restrict__ label,
                             float* __restrict__ out) {
    if (threadIdx.x == 0 && blockIdx.x == 0) {
        float l0 = 0.f, l1 = 0.f, l2 = 0.f;
        for (int b = 0; b < B; ++b) {
            l0 += accums[8 + b] + accums[24 + b] + accums[32 + b];
            l1 += sqrtf(accums[16 + b]);
            float d = affn[b] - label[b];
            l2 += d * d;
        }
        out[0] = (l0 + l1 + l2) * 0.125f;
    }
}

// ---------------------------------------------------------------------------
extern "C" void kernel_launch(void* const* d_in, const int* in_sizes, int n_in,
                              void* d_out, int out_size, void* d_ws, size_t ws_size,
                              hipStream_t stream) {
    const float* prot_data   = (const float*)d_in[0];
    const float* drug_ver    = (const float*)d_in[1];
    const float* drug_adj    = (const float*)d_in[2];
    const float* contacts    = (const float*)d_in[3];
    const float* prot_inter  = (const float*)d_in[4];
    const float* exist       = (const float*)d_in[5];
    const float* label       = (const float*)d_in[6];
    const float* fused       = (const float*)d_in[7];
    const float* W_prot      = (const float*)d_in[8];
    const float* b_prot      = (const float*)d_in[9];
    const float* gcn_W0      = (const float*)d_in[10];
    const float* gcn_b0      = (const float*)d_in[11];
    const float* gcn_W1      = (const float*)d_in[12];
    const float* gcn_b1      = (const float*)d_in[13];
    const float* gcn_W2      = (const float*)d_in[14];
    const float* gcn_b2      = (const float*)d_in[15];
    const float* gcn_Wf      = (const float*)d_in[16];
    const float* gcn_bf      = (const float*)d_in[17];
    const float* Wjp         = (const float*)d_in[18];
    const float* bjp         = (const float*)d_in[19];
    const float* Wjc         = (const float*)d_in[20];
    const float* bjc         = (const float*)d_in[21];
    const float* conv_w      = (const float*)d_in[22];
    const float* conv_b      = (const float*)d_in[23];
    const float* W_r1        = (const float*)d_in[24];
    const float* b_r1        = (const float*)d_in[25];
    const float* W_r2        = (const float*)d_in[26];
    const float* b_r2        = (const float*)d_in[27];
    const float* W_r3        = (const float*)d_in[28];
    const float* b_r3        = (const float*)d_in[29];

    float* ws = (float*)d_ws;
    size_t off = 0;
    auto alloc = [&](size_t n) { float* p = ws + off; off += n; return p; };
    float* prot     = alloc((size_t)B * NP * DD);   // 2,048,000
    float* qp       = alloc((size_t)B * NP * DD);   // 2,048,000
    float* tbuf     = alloc((size_t)B * NK * DD);
    float* ybuf     = alloc((size_t)B * NK * DD);
    float* comp     = alloc((size_t)B * NK * DD);
    float* qc       = alloc((size_t)B * NK * DD);
    float* inter    = alloc((size_t)B * NP * NK);   // 448,000
    float* s_bi     = alloc((size_t)B * NP);
    float* cp_part  = alloc((size_t)B * 125 * DD);  // 256,000
    float* cp       = alloc((size_t)B * DD);
    float* pooled   = alloc((size_t)B * 2048);
    float* fc1      = alloc((size_t)B * 600);
    float* fc2      = alloc((size_t)B * 300);
    float* affn     = alloc((size_t)B);
    float* groupv   = alloc((size_t)B * NP);
    // zero-region: accums, raw1, raw2 contiguous
    float* accums   = alloc(40);
    float* raw1     = alloc((size_t)B * 600);
    float* raw2     = alloc((size_t)B * 300);

    // Aliases (lifetime-disjoint reuse, no extra workspace):
    //   interT[448][1000]  lives in qp   (qp dead after inter_kernel)
    //   Epart[4][448][1024] lives in prot (prot dead after cp_partial)
    float* interT = qp;     // 448,000 <= 2,048,000
    float* Epart  = prot;   // 1,835,008 <= 2,048,000

    // zero the atomic-accumulated buffers (accums, raw1, raw2 contiguous)
    hipMemsetAsync(accums, 0,
        (40 + (size_t)B * 600 + (size_t)B * 300) * sizeof(float), stream);

    // prot = prot_data @ W_prot + b_prot
    gemm_bias_kernel<false><<<dim3(125, 4), 256, 0, stream>>>(
        prot_data, W_prot, b_prot, prot, B * NP, DD, DP);

    // GCN stack
    rowmm_kernel<false><<<B * NK, 256, DV * sizeof(float), stream>>>(drug_ver, gcn_W0, gcn_b0, tbuf, DV);
    adjmul_relu_kernel<<<B * NK, 256, 0, stream>>>(drug_adj, tbuf, ybuf);
    rowmm_kernel<false><<<B * NK, 256, DD * sizeof(float), stream>>>(ybuf, gcn_W1, gcn_b1, tbuf, DD);
    adjmul_relu_kernel<<<B * NK, 256, 0, stream>>>(drug_adj, tbuf, ybuf);
    rowmm_kernel<false><<<B * NK, 256, DD * sizeof(float), stream>>>(ybuf, gcn_W2, gcn_b2, tbuf, DD);
    adjmul_relu_kernel<<<B * NK, 256, 0, stream>>>(drug_adj, tbuf, ybuf);
    rowmm_kernel<false><<<B * NK, 256, DD * sizeof(float), stream>>>(ybuf, gcn_Wf, gcn_bf, comp, DD);
    rowmm_kernel<true ><<<B * NK, 256, DD * sizeof(float), stream>>>(comp, Wjc, bjc, qc, DD);

    // qp = relu(prot) @ Wjp + bjp
    gemm_bias_kernel<true><<<dim3(125, 4), 256, 0, stream>>>(
        prot, Wjp, bjp, qp, B * NP, DD, DD);

    // inter + normalization  (last use of qp)
    inter_kernel<<<B * 125, 256, 0, stream>>>(qp, qc, inter, accums + 0);
    normalize_inter_kernel<<<(B * NP * NK + 255) / 256, 256, 0, stream>>>(inter, accums + 0);
    inter_stats_kernel<<<B * 4, 256, 0, stream>>>(inter, prot_inter, exist, s_bi,
                                                  accums + 8, accums + 16);

    // cp contraction (last use of prot)
    cp_partial_kernel<<<dim3(B * 125, 2), 128, 0, stream>>>(prot, comp, inter, cp_part);
    cp_reduce_kernel<<<B, 256, 0, stream>>>(cp_part, cp);

    // fused regularizer: transpose -> k-split GEMM -> abs reduce
    transpose_inter_kernel<<<dim3(32, 2, B), 256, 0, stream>>>(inter, interT);
    fusedE_gemm_kernel<<<dim3(7, 16, 4), 256, 0, stream>>>(interT, fused, Epart);
    fusedE_abs_kernel<<<448, 256, 0, stream>>>(Epart, accums + 24);

    // conv / pool / FCs
    conv_pool_kernel<<<B, 256, 0, stream>>>(cp, conv_w, conv_b, pooled);
    fc_partial_kernel<<<dim3(10, 16), 256, 0, stream>>>(pooled, W_r1, raw1, 2048, 600, 128);
    fc_finish_kernel<true><<<(B * 600 + 255) / 256, 256, 0, stream>>>(raw1, b_r1, fc1, 600);
    fc_partial_kernel<<<dim3(5, 8), 256, 0, stream>>>(fc1, W_r2, raw2, 600, 300, 75);
    fc_finish_kernel<true><<<(B * 300 + 255) / 256, 256, 0, stream>>>(raw2, b_r2, fc2, 300);
    fc3_kernel<<<1, 512, 0, stream>>>(fc2, W_r3, b_r3, affn);

    // group regularizer
    group_kernel<<<B * NP, 64, 0, stream>>>(contacts, s_bi, groupv);
    reduce1000_kernel<<<B, 256, 0, stream>>>(groupv, accums + 32);

    // final loss
    final_kernel<<<1, 64, 0, stream>>>(accums, affn, label, (float*)d_out);
}

// Round 7
// 277.533 us; speedup vs baseline: 5.7301x; 1.2681x over previous
//
#include <hip/hip_runtime.h>
#include <hip/hip_bf16.h>
#include <math.h>

// ---------------------------------------------------------------------------
// Sizes (fixed by the reference)
#define B 8
#define NP 1000        // protein length
#define NK 56          // drug vertices
#define DP 768         // prot_data feature
#define DV 43          // drug vertex feature
#define DD 256         // D
#define NT 999         // fused_matrix rows

typedef __attribute__((ext_vector_type(8))) short bf16x8;
typedef __attribute__((ext_vector_type(4))) float f32x4;

__device__ inline short f2bf(float x) {
    __hip_bfloat16 h = __float2bfloat16(x);   // RTE via v_cvt_pk_bf16_f32
    return __builtin_bit_cast(short, h);
}

// ---------------------------------------------------------------------------
// W pre-convert: W[K][N] f32 -> Wb[K/8][N][8] bf16 (each lane-frag = 16B chunk)
__global__ __launch_bounds__(256) void wcvt_kernel(
    const float* __restrict__ W, short* __restrict__ Wb, int K, int N) {
    int idx = blockIdx.x * 256 + threadIdx.x;
    int total = (K >> 3) * N;
    if (idx >= total) return;
    int koct = idx / N, n = idx % N;
    bf16x8 v;
    #pragma unroll
    for (int e = 0; e < 8; ++e)
        v[e] = f2bf(W[(size_t)(koct * 8 + e) * N + n]);
    *reinterpret_cast<bf16x8*>(Wb + (size_t)idx * 8) = v;
}

// ---------------------------------------------------------------------------
// MFMA GEMM: C[M,N] = act_in(A[M,K]) @ W + bias.  A f32 [M][K]; Wb swizzled bf16.
// Block 256 thr = 4 waves; block tile 32(M) x 128(N); wave: 16x64 (4 n-tiles).
// M%32==0, N%128==0, K%32==0.
template<bool RELU_IN>
__global__ __launch_bounds__(256) void mfma_gemm_bias_kernel(
    const float* __restrict__ A, const short* __restrict__ Wb,
    const float* __restrict__ bias, float* __restrict__ C,
    int M, int N, int K) {
    int tid = threadIdx.x;
    int lane = tid & 63, w = tid >> 6;
    int m0 = blockIdx.x * 32 + (w >> 1) * 16;
    int n0 = blockIdx.y * 128 + (w & 1) * 64;
    int lrow = lane & 15, lk = lane >> 4;       // lk in 0..3
    f32x4 acc[4] = {{0.f,0.f,0.f,0.f},{0.f,0.f,0.f,0.f},
                    {0.f,0.f,0.f,0.f},{0.f,0.f,0.f,0.f}};
    const float* arow = A + (size_t)(m0 + lrow) * K + lk * 8;
    for (int k0 = 0; k0 < K; k0 += 32) {
        f32x4 a0 = *reinterpret_cast<const f32x4*>(arow + k0);
        f32x4 a1 = *reinterpret_cast<const f32x4*>(arow + k0 + 4);
        bf16x8 af;
        #pragma unroll
        for (int e = 0; e < 4; ++e) {
            float v0 = a0[e], v1 = a1[e];
            if (RELU_IN) { v0 = fmaxf(v0, 0.f); v1 = fmaxf(v1, 0.f); }
            af[e] = f2bf(v0); af[4 + e] = f2bf(v1);
        }
        const short* bbase = Wb + ((size_t)((k0 >> 3) + lk) * N + n0 + lrow) * 8;
        #pragma unroll
        for (int nt = 0; nt < 4; ++nt) {
            bf16x8 bf = *reinterpret_cast<const bf16x8*>(bbase + nt * 128);
            acc[nt] = __builtin_amdgcn_mfma_f32_16x16x32_bf16(af, bf, acc[nt], 0, 0, 0);
        }
    }
    #pragma unroll
    for (int nt = 0; nt < 4; ++nt) {
        int col = n0 + nt * 16 + lrow;
        float bv = bias[col];
        #pragma unroll
        for (int r = 0; r < 4; ++r) {
            int row = m0 + lk * 4 + r;
            C[(size_t)row * N + col] = acc[nt][r] + bv;
        }
    }
}

// ---------------------------------------------------------------------------
// Small row-matmul: out[r, 0..255] = act_in(in[r, 0..K)) @ W[K,256] + b
template<bool RELU_IN>
__global__ __launch_bounds__(256) void rowmm_kernel(
    const float* __restrict__ in, const float* __restrict__ W,
    const float* __restrict__ bias, float* __restrict__ out, int K) {
    extern __shared__ float srow[];
    int r = blockIdx.x, d = threadIdx.x;
    for (int k = d; k < K; k += 256) {
        float v = in[(size_t)r * K + k];
        if (RELU_IN) v = fmaxf(v, 0.f);
        srow[k] = v;
    }
    __syncthreads();
    float acc = bias[d];
    for (int k = 0; k < K; ++k)
        acc = fmaf(srow[k], W[(size_t)k * DD + d], acc);
    out[(size_t)r * DD + d] = acc;
}

// y[b,i,:] = relu( sum_j adj[b,i,j] * t[b,j,:] )
__global__ __launch_bounds__(256) void adjmul_relu_kernel(
    const float* __restrict__ adj, const float* __restrict__ t,
    float* __restrict__ y) {
    int b = blockIdx.x / NK, i = blockIdx.x % NK, d = threadIdx.x;
    __shared__ float arow[NK];
    if (d < NK) arow[d] = adj[((size_t)b * NK + i) * NK + d];
    __syncthreads();
    float acc = 0.f;
    #pragma unroll 8
    for (int j = 0; j < NK; ++j)
        acc = fmaf(arow[j], t[((size_t)b * NK + j) * DD + d], acc);
    y[((size_t)b * NK + i) * DD + d] = fmaxf(acc, 0.f);
}

// ---------------------------------------------------------------------------
// inter[b,i,k] = sigmoid( qp[b,i,:] . qc[b,k,:] ); atomic add batch sum
__global__ __launch_bounds__(256) void inter_kernel(
    const float* __restrict__ qp, const float* __restrict__ qc,
    float* __restrict__ inter, float* __restrict__ interSum) {
    int b = blockIdx.x / 125, chunk = blockIdx.x % 125;
    __shared__ float qcT[DD * 57];   // [d][k], pad 57
    int tid = threadIdx.x;
    for (int l = tid; l < NK * DD; l += 256) {
        int k = l / DD, d = l % DD;
        qcT[d * 57 + k] = qc[((size_t)b * NK + k) * DD + d];
    }
    __syncthreads();
    int wave = tid >> 6, lane = tid & 63;
    __shared__ float wsum[4];
    float lsum = 0.f;
    for (int ii = 0; ii < 2; ++ii) {
        int i = chunk * 8 + wave * 2 + ii;
        const float* qrow = qp + ((size_t)b * NP + i) * DD;
        if (lane < NK) {
            float acc = 0.f;
            for (int d = 0; d < DD; ++d)
                acc = fmaf(qrow[d], qcT[d * 57 + lane], acc);
            float sg = 1.f / (1.f + __expf(-acc));
            inter[((size_t)b * NP + i) * NK + lane] = sg;
            lsum += sg;
        }
    }
    #pragma unroll
    for (int off = 32; off; off >>= 1) lsum += __shfl_down(lsum, off);
    if (lane == 0) wsum[wave] = lsum;
    __syncthreads();
    if (tid == 0)
        atomicAdd(&interSum[b], wsum[0] + wsum[1] + wsum[2] + wsum[3]);
}

__global__ void normalize_inter_kernel(float* inter, const float* interSum) {
    int idx = blockIdx.x * 256 + threadIdx.x;
    if (idx < B * NP * NK) inter[idx] /= interSum[idx / (NP * NK)];
}

// per-row stats: s[b,i]=sum_k inter^2 ; l1Sum[b]+=sum inter ; bindSum[b]+=sum (inter-lab)^2
__global__ __launch_bounds__(256) void inter_stats_kernel(
    const float* __restrict__ inter, const float* __restrict__ prot_inter,
    const float* __restrict__ exist, float* __restrict__ s_bi,
    float* __restrict__ l1Sum, float* __restrict__ bindSum) {
    int b = blockIdx.x / 4, q = blockIdx.x % 4;
    int i = q * 250 + threadIdx.x;
    float l1 = 0.f, bind = 0.f;
    if (threadIdx.x < 250) {
        float ex = exist[b];
        float ss = 0.f;
        const float* row  = inter      + ((size_t)b * NP + i) * NK;
        const float* prow = prot_inter + ((size_t)b * NP + i) * NK;
        #pragma unroll 8
        for (int k = 0; k < NK; ++k) {
            float v = row[k];
            l1 += v; ss = fmaf(v, v, ss);
            float d = v - ex * prow[k];
            bind = fmaf(d, d, bind);
        }
        s_bi[b * NP + i] = ss;
    }
    __shared__ float r1[256], r2[256];
    r1[threadIdx.x] = l1; r2[threadIdx.x] = bind;
    __syncthreads();
    for (int s = 128; s; s >>= 1) {
        if (threadIdx.x < s) {
            r1[threadIdx.x] += r1[threadIdx.x + s];
            r2[threadIdx.x] += r2[threadIdx.x + s];
        }
        __syncthreads();
    }
    if (threadIdx.x == 0) {
        atomicAdd(&l1Sum[b], r1[0]);
        atomicAdd(&bindSum[b], r2[0]);
    }
}

// ---------------------------------------------------------------------------
// cp partials: grid (B*125 chunks of 8 i's, 2 d-halves), 128 threads.
__global__ __launch_bounds__(128) void cp_partial_kernel(
    const float* __restrict__ prot, const float* __restrict__ comp,
    const float* __restrict__ inter, float* __restrict__ part) {
    int bc = blockIdx.x;
    int b = bc / 125, chunk = bc % 125;
    int dh = blockIdx.y;
    int tid = threadIdx.x;
    int d = dh * 128 + tid;
    __shared__ float comp_s[NK][128];
    __shared__ float irow[8][NK];
    for (int l = tid; l < NK * 128; l += 128) {
        int k = l >> 7, dd = l & 127;
        comp_s[k][dd] = comp[((size_t)b * NK + k) * DD + dh * 128 + dd];
    }
    for (int l = tid; l < 8 * NK; l += 128) {
        int ii = l / NK, k = l % NK;
        irow[ii][k] = inter[((size_t)b * NP + chunk * 8 + ii) * NK + k];
    }
    float p2[8];
    #pragma unroll
    for (int ii = 0; ii < 8; ++ii)
        p2[ii] = 2.f * prot[((size_t)b * NP + chunk * 8 + ii) * DD + d];
    __syncthreads();
    float acc0 = 0.f, acc1 = 0.f;
    for (int ii = 0; ii < 8; ++ii) {
        float p = p2[ii];
        #pragma unroll 8
        for (int k = 0; k < NK; k += 2) {
            float x0 = fminf(fmaxf(p * comp_s[k][tid],     -30.f), 30.f);
            float x1 = fminf(fmaxf(p * comp_s[k + 1][tid], -30.f), 30.f);
            float r0 = __builtin_amdgcn_rcpf(__expf(x0) + 1.f);
            float r1 = __builtin_amdgcn_rcpf(__expf(x1) + 1.f);
            acc0 = fmaf(fmaf(-2.f, r0, 1.f), irow[ii][k],     acc0);
            acc1 = fmaf(fmaf(-2.f, r1, 1.f), irow[ii][k + 1], acc1);
        }
    }
    part[((size_t)b * 125 + chunk) * DD + d] = acc0 + acc1;
}

__global__ void cp_reduce_kernel(const float* part, float* cp) {
    int b = blockIdx.x, d = threadIdx.x;
    float s = 0.f;
    for (int c = 0; c < 125; ++c) s += part[((size_t)b * 125 + c) * DD + d];
    cp[b * DD + d] = s;
}

// ---------------------------------------------------------------------------
// conv(k=4,s=2,pad=1) + bias + leaky + maxpool4 -> pooled[b][2048]
__global__ __launch_bounds__(256) void conv_pool_kernel(
    const float* __restrict__ cp, const float* __restrict__ conv_w,
    const float* __restrict__ conv_b, float* __restrict__ pooled) {
    int b = blockIdx.x, t = threadIdx.x;
    __shared__ float x[258];
    __shared__ float convo[64 * 128];
    x[t + 1] = cp[b * DD + t];
    if (t == 0) { x[0] = 0.f; x[257] = 0.f; }
    __syncthreads();
    for (int l = t; l < 64 * 128; l += 256) {
        int o = l / 128, pos = l % 128;
        float acc = conv_b[o];
        int base = pos * 2;
        #pragma unroll
        for (int h = 0; h < 4; ++h)
            acc = fmaf(x[base + h], conv_w[o * 4 + h], acc);
        convo[l] = (acc > 0.f) ? acc : 0.1f * acc;
    }
    __syncthreads();
    for (int l = t; l < 64 * 32; l += 256) {
        int o = l / 32, p = l % 32;
        float m = -INFINITY;
        #pragma unroll
        for (int q = 0; q < 4; ++q)
            m = fmaxf(m, convo[o * 128 + p * 4 + q]);
        pooled[b * 2048 + l] = m;
    }
}

// ---------------------------------------------------------------------------
// FC partial: grid (o_tiles, k_splits), LDS-staged activations, atomic raw.
__global__ __launch_bounds__(256) void fc_partial_kernel(
    const float* __restrict__ in, const float* __restrict__ W,
    float* __restrict__ raw, int K, int N, int kchunk) {
    int t = threadIdx.x;
    int ol = t & 63;
    int o = blockIdx.x * 64 + ol;
    int w = t >> 6;
    int kbeg = blockIdx.y * kchunk;
    int kend = kbeg + kchunk; if (kend > K) kend = K;
    int len = kend - kbeg;
    __shared__ float sin_[B][128];   // kchunk <= 128
    for (int l = t; l < B * len; l += 256) {
        int b = l / len, k = l % len;
        sin_[b][k] = in[(size_t)b * K + kbeg + k];
    }
    __syncthreads();
    float acc[B];
    #pragma unroll
    for (int b = 0; b < B; ++b) acc[b] = 0.f;
    if (o < N) {
        for (int k = kbeg + w; k < kend; k += 4) {
            float wv = W[(size_t)k * N + o];
            int kl = k - kbeg;
            #pragma unroll
            for (int b = 0; b < B; ++b)
                acc[b] = fmaf(sin_[b][kl], wv, acc[b]);
        }
    }
    __shared__ float red[4][64][B];
    #pragma unroll
    for (int b = 0; b < B; ++b) red[w][ol][b] = acc[b];
    __syncthreads();
    for (int p = t; p < 64 * B; p += 256) {
        int oo = p / B, b = p % B;
        int o2 = blockIdx.x * 64 + oo;
        if (o2 < N) {
            float s = red[0][oo][b] + red[1][oo][b] + red[2][oo][b] + red[3][oo][b];
            atomicAdd(&raw[(size_t)b * N + o2], s);
        }
    }
}

template<bool LEAKY>
__global__ void fc_finish_kernel(const float* __restrict__ raw,
                                 const float* __restrict__ bias,
                                 float* __restrict__ out, int N) {
    int idx = blockIdx.x * 256 + threadIdx.x;
    if (idx < B * N) {
        int b = idx / N, o = idx % N;
        float s = raw[(size_t)b * N + o] + bias[o];
        if (LEAKY) s = (s > 0.f) ? s : 0.1f * s;
        out[(size_t)b * N + o] = s;
    }
}

// fc3: N=1, K=300. One block, 8 waves, wave = batch, shuffle reduce.
__global__ __launch_bounds__(512) void fc3_kernel(
    const float* __restrict__ in, const float* __restrict__ W,
    const float* __restrict__ bias, float* __restrict__ affn) {
    int wv = threadIdx.x >> 6, lane = threadIdx.x & 63;
    float acc = 0.f;
    for (int k = lane; k < 300; k += 64)
        acc = fmaf(in[(size_t)wv * 300 + k], W[k], acc);
    #pragma unroll
    for (int off = 32; off; off >>= 1) acc += __shfl_down(acc, off);
    if (lane == 0) affn[wv] = acc + bias[0];
}

// ---------------------------------------------------------------------------
// fused reg, cvt A: inter[b][i][j] -> iTb[i_oct][m=b*56+j][8] bf16, i pad 1024.
__global__ __launch_bounds__(256) void intercvt_kernel(
    const float* __restrict__ inter, short* __restrict__ iTb) {
    int idx = blockIdx.x * 256 + threadIdx.x;
    if (idx >= 128 * 448) return;
    int oct = idx / 448, m = idx % 448;
    int b = m / NK, j = m % NK;
    bf16x8 v;
    #pragma unroll
    for (int e = 0; e < 8; ++e) {
        int i = oct * 8 + e;
        float x = (i < NP) ? inter[((size_t)b * NP + i) * NK + j] : 0.f;
        v[e] = f2bf(x);
    }
    *reinterpret_cast<bf16x8*>(iTb + (size_t)idx * 8) = v;
}

// fused reg, cvt B: fused[t][i] -> fMb[i_oct][t][8] bf16, t pad 1024, i pad 1024.
__global__ __launch_bounds__(256) void fusedcvt_kernel(
    const float* __restrict__ fusedM, short* __restrict__ fMb) {
    int idx = blockIdx.x * 256 + threadIdx.x;
    if (idx >= 128 * 1024) return;
    int oct = idx >> 10, t = idx & 1023;
    bf16x8 v;
    #pragma unroll
    for (int e = 0; e < 8; ++e) {
        int i = oct * 8 + e;
        float x = (t < NT && i < NP) ? fusedM[(size_t)t * NP + i] : 0.f;
        v[e] = f2bf(x);
    }
    *reinterpret_cast<bf16x8*>(fMb + (size_t)idx * 8) = v;
}

// fused reg MFMA: E[m][t] = sum_i iT[m][i] fM[t][i]; fusedAbs[b] += sum |E|.
// Block tile 32(m) x 128(t), full K=1024 in-block. grid (14, 8).
__global__ __launch_bounds__(256) void fused_mfma_abs_kernel(
    const short* __restrict__ iTb,   // [128][448][8]
    const short* __restrict__ fMb,   // [128][1024][8]
    float* __restrict__ fusedAbs) {
    __shared__ float sb[8];
    int tid = threadIdx.x;
    int lane = tid & 63, w = tid >> 6;
    if (tid < 8) sb[tid] = 0.f;
    __syncthreads();
    int m0 = blockIdx.x * 32 + (w >> 1) * 16;
    int n0 = blockIdx.y * 128 + (w & 1) * 64;
    int lrow = lane & 15, lk = lane >> 4;
    f32x4 acc[4] = {{0.f,0.f,0.f,0.f},{0.f,0.f,0.f,0.f},
                    {0.f,0.f,0.f,0.f},{0.f,0.f,0.f,0.f}};
    for (int koct0 = 0; koct0 < 128; koct0 += 4) {
        int koct = koct0 + lk;
        bf16x8 af = *reinterpret_cast<const bf16x8*>(
            iTb + ((size_t)koct * 448 + m0 + lrow) * 8);
        const short* bb = fMb + ((size_t)koct * 1024 + n0 + lrow) * 8;
        #pragma unroll
        for (int nt = 0; nt < 4; ++nt) {
            bf16x8 bf = *reinterpret_cast<const bf16x8*>(bb + nt * 128);
            acc[nt] = __builtin_amdgcn_mfma_f32_16x16x32_bf16(af, bf, acc[nt], 0, 0, 0);
        }
    }
    #pragma unroll
    for (int r = 0; r < 4; ++r) {
        float part = fabsf(acc[0][r]) + fabsf(acc[1][r]) +
                     fabsf(acc[2][r]) + fabsf(acc[3][r]);
        #pragma unroll
        for (int off = 1; off < 16; off <<= 1)
            part += __shfl_xor(part, off);
        if (lrow == 0) {
            int row = m0 + lk * 4 + r;
            atomicAdd(&sb[row / NK], part);
        }
    }
    __syncthreads();
    if (tid < 8 && sb[tid] != 0.f) atomicAdd(&fusedAbs[tid], sb[tid]);
}

// ---------------------------------------------------------------------------
// group: one wave per (b,k): g = contacts[b,k,:] . s[b,:], rs = row sum
__global__ __launch_bounds__(64) void group_kernel(
    const float* __restrict__ contacts, const float* __restrict__ s_bi,
    float* __restrict__ group_val) {
    int bk = blockIdx.x;
    int b = bk / NP, k = bk % NP;
    const float* row = contacts + ((size_t)b * NP + k) * NP;
    const float* sv = s_bi + b * NP;
    float g = 0.f, rs = 0.f;
    for (int i = threadIdx.x; i < NP; i += 64) {
        float c = row[i];
        g = fmaf(c, sv[i], g);
        rs += c;
    }
    #pragma unroll
    for (int off = 32; off; off >>= 1) {
        g += __shfl_down(g, off);
        rs += __shfl_down(rs, off);
    }
    if (threadIdx.x == 0) {
        if (g == 0.f) g += 1e10f;
        group_val[bk] = sqrtf(g) * sqrtf(rs);
    }
}

__global__ __launch_bounds__(256) void reduce1000_kernel(const float* in, float* out) {
    int b = blockIdx.x;
    float s = 0.f;
    for (int l = threadIdx.x; l < NP; l += 256) s += in[b * NP + l];
    __shared__ float r[256];
    r[threadIdx.x] = s;
    __syncthreads();
    for (int st = 128; st; st >>= 1) {
        if (threadIdx.x < st) r[threadIdx.x] += r[threadIdx.x + st];
        __syncthreads();
    }
    if (threadIdx.x == 0) out[b] = r[0];
}

// accums: [0..8)=interSum [8..16)=l1Sum [16..24)=bindSum [24..32)=fusedAbs [32..40)=groupReg
__global__ void final_kernel(const float* __restrict__ accums,
                             const float* __restrict__ affn,
                             const float* __restrict__ label,
                             float* __restrict__ out) {
    if (threadIdx.x == 0 && blockIdx.x == 0) {
        float l0 = 0.f, l1 = 0.f, l2 = 0.f;
        for (int b = 0; b < B; ++b) {
            l0 += accums[8 + b] + accums[24 + b] + accums[32 + b];
            l1 += sqrtf(accums[16 + b]);
            float d = affn[b] - label[b];
            l2 += d * d;
        }
        out[0] = (l0 + l1 + l2) * 0.125f;
    }
}

// ---------------------------------------------------------------------------
extern "C" void kernel_launch(void* const* d_in, const int* in_sizes, int n_in,
                              void* d_out, int out_size, void* d_ws, size_t ws_size,
                              hipStream_t stream) {
    const float* prot_data   = (const float*)d_in[0];
    const float* drug_ver    = (const float*)d_in[1];
    const float* drug_adj    = (const float*)d_in[2];
    const float* contacts    = (const float*)d_in[3];
    const float* prot_inter  = (const float*)d_in[4];
    const float* exist       = (const float*)d_in[5];
    const float* label       = (const float*)d_in[6];
    const float* fused       = (const float*)d_in[7];
    const float* W_prot      = (const float*)d_in[8];
    const float* b_prot      = (const float*)d_in[9];
    const float* gcn_W0      = (const float*)d_in[10];
    const float* gcn_b0      = (const float*)d_in[11];
    const float* gcn_W1      = (const float*)d_in[12];
    const float* gcn_b1      = (const float*)d_in[13];
    const float* gcn_W2      = (const float*)d_in[14];
    const float* gcn_b2      = (const float*)d_in[15];
    const float* gcn_Wf      = (const float*)d_in[16];
    const float* gcn_bf      = (const float*)d_in[17];
    const float* Wjp         = (const float*)d_in[18];
    const float* bjp         = (const float*)d_in[19];
    const float* Wjc         = (const float*)d_in[20];
    const float* bjc         = (const float*)d_in[21];
    const float* conv_w      = (const float*)d_in[22];
    const float* conv_b      = (const float*)d_in[23];
    const float* W_r1        = (const float*)d_in[24];
    const float* b_r1        = (const float*)d_in[25];
    const float* W_r2        = (const float*)d_in[26];
    const float* b_r2        = (const float*)d_in[27];
    const float* W_r3        = (const float*)d_in[28];
    const float* b_r3        = (const float*)d_in[29];

    float* ws = (float*)d_ws;
    size_t off = 0;
    auto alloc = [&](size_t n) { float* p = ws + off; off += n; return p; };
    float* prot     = alloc((size_t)B * NP * DD);   // 2,048,000
    float* qp       = alloc((size_t)B * NP * DD);   // 2,048,000
    float* tbuf     = alloc((size_t)B * NK * DD);
    float* ybuf     = alloc((size_t)B * NK * DD);
    float* comp     = alloc((size_t)B * NK * DD);
    float* qc       = alloc((size_t)B * NK * DD);
    float* inter    = alloc((size_t)B * NP * NK);   // 448,000
    float* s_bi     = alloc((size_t)B * NP);
    float* cp_part  = alloc((size_t)B * 125 * DD);  // 256,000
    float* cp       = alloc((size_t)B * DD);
    float* pooled   = alloc((size_t)B * 2048);
    float* fc1      = alloc((size_t)B * 600);
    float* fc2      = alloc((size_t)B * 300);
    float* affn     = alloc((size_t)B);
    float* groupv   = alloc((size_t)B * NP);
    // bf16 buffers (sizes in f32 units = shorts/2)
    short* Wb1      = (short*)alloc((DP / 8) * DD * 8 / 2);   // 96*256*8 shorts
    short* Wb2      = (short*)alloc((DD / 8) * DD * 8 / 2);   // 32*256*8 shorts
    short* fMb      = (short*)alloc((size_t)128 * 1024 * 8 / 2);
    // zero-region: accums, raw1, raw2 contiguous
    float* accums   = alloc(40);
    float* raw1     = alloc((size_t)B * 600);
    float* raw2     = alloc((size_t)B * 300);

    // iTb[128][448][8] bf16 aliases qp (dead after inter_kernel); 229,376 f32-equiv
    short* iTb = (short*)qp;

    // zero the atomic-accumulated buffers (accums, raw1, raw2 contiguous)
    hipMemsetAsync(accums, 0,
        (40 + (size_t)B * 600 + (size_t)B * 300) * sizeof(float), stream);

    // weight / fused-matrix bf16 pre-conversion (independent of everything)
    wcvt_kernel<<<(DP / 8 * DD + 255) / 256, 256, 0, stream>>>(W_prot, Wb1, DP, DD);
    wcvt_kernel<<<(DD / 8 * DD + 255) / 256, 256, 0, stream>>>(Wjp, Wb2, DD, DD);
    fusedcvt_kernel<<<512, 256, 0, stream>>>(fused, fMb);

    // prot = prot_data @ W_prot + b_prot   (bf16 MFMA)
    mfma_gemm_bias_kernel<false><<<dim3(250, 2), 256, 0, stream>>>(
        prot_data, Wb1, b_prot, prot, B * NP, DD, DP);

    // GCN stack
    rowmm_kernel<false><<<B * NK, 256, DV * sizeof(float), stream>>>(drug_ver, gcn_W0, gcn_b0, tbuf, DV);
    adjmul_relu_kernel<<<B * NK, 256, 0, stream>>>(drug_adj, tbuf, ybuf);
    rowmm_kernel<false><<<B * NK, 256, DD * sizeof(float), stream>>>(ybuf, gcn_W1, gcn_b1, tbuf, DD);
    adjmul_relu_kernel<<<B * NK, 256, 0, stream>>>(drug_adj, tbuf, ybuf);
    rowmm_kernel<false><<<B * NK, 256, DD * sizeof(float), stream>>>(ybuf, gcn_W2, gcn_b2, tbuf, DD);
    adjmul_relu_kernel<<<B * NK, 256, 0, stream>>>(drug_adj, tbuf, ybuf);
    rowmm_kernel<false><<<B * NK, 256, DD * sizeof(float), stream>>>(ybuf, gcn_Wf, gcn_bf, comp, DD);
    rowmm_kernel<true ><<<B * NK, 256, DD * sizeof(float), stream>>>(comp, Wjc, bjc, qc, DD);

    // qp = relu(prot) @ Wjp + bjp   (bf16 MFMA, relu folded into A load)
    mfma_gemm_bias_kernel<true><<<dim3(250, 2), 256, 0, stream>>>(
        prot, Wb2, bjp, qp, B * NP, DD, DD);

    // inter + normalization  (last use of qp)
    inter_kernel<<<B * 125, 256, 0, stream>>>(qp, qc, inter, accums + 0);
    normalize_inter_kernel<<<(B * NP * NK + 255) / 256, 256, 0, stream>>>(inter, accums + 0);
    inter_stats_kernel<<<B * 4, 256, 0, stream>>>(inter, prot_inter, exist, s_bi,
                                                  accums + 8, accums + 16);

    // cp contraction (last use of prot)
    cp_partial_kernel<<<dim3(B * 125, 2), 128, 0, stream>>>(prot, comp, inter, cp_part);
    cp_reduce_kernel<<<B, 256, 0, stream>>>(cp_part, cp);

    // fused regularizer: cvt inter (into dead qp) -> MFMA + abs reduce
    intercvt_kernel<<<(128 * 448 + 255) / 256, 256, 0, stream>>>(inter, iTb);
    fused_mfma_abs_kernel<<<dim3(14, 8), 256, 0, stream>>>(iTb, fMb, accums + 24);

    // conv / pool / FCs
    conv_pool_kernel<<<B, 256, 0, stream>>>(cp, conv_w, conv_b, pooled);
    fc_partial_kernel<<<dim3(10, 16), 256, 0, stream>>>(pooled, W_r1, raw1, 2048, 600, 128);
    fc_finish_kernel<true><<<(B * 600 + 255) / 256, 256, 0, stream>>>(raw1, b_r1, fc1, 600);
    fc_partial_kernel<<<dim3(5, 8), 256, 0, stream>>>(fc1, W_r2, raw2, 600, 300, 75);
    fc_finish_kernel<true><<<(B * 300 + 255) / 256, 256, 0, stream>>>(raw2, b_r2, fc2, 300);
    fc3_kernel<<<1, 512, 0, stream>>>(fc2, W_r3, b_r3, affn);

    // group regularizer
    group_kernel<<<B * NP, 64, 0, stream>>>(contacts, s_bi, groupv);
    reduce1000_kernel<<<B, 256, 0, stream>>>(groupv, accums + 32);

    // final loss
    final_kernel<<<1, 64, 0, stream>>>(accums, affn, label, (float*)d_out);
}

// Round 8
// 260.081 us; speedup vs baseline: 6.1146x; 1.0671x over previous
//
#include <hip/hip_runtime.h>
#include <hip/hip_bf16.h>
#include <math.h>

// ---------------------------------------------------------------------------
// Sizes (fixed by the reference)
#define B 8
#define NP 1000        // protein length
#define NK 56          // drug vertices
#define DP 768         // prot_data feature
#define DV 43          // drug vertex feature
#define DD 256         // D
#define NT 999         // fused_matrix rows

typedef __attribute__((ext_vector_type(8))) short bf16x8;
typedef __attribute__((ext_vector_type(4))) float f32x4;

__device__ inline short f2bf(float x) {
    __hip_bfloat16 h = __float2bfloat16(x);   // RTE via v_cvt_pk_bf16_f32
    return __builtin_bit_cast(short, h);
}

// ---------------------------------------------------------------------------
// W pre-convert: W[K][N] f32 -> Wb[K/8][N][8] bf16 (each lane-frag = 16B chunk)
__global__ __launch_bounds__(256) void wcvt_kernel(
    const float* __restrict__ W, short* __restrict__ Wb, int K, int N) {
    int idx = blockIdx.x * 256 + threadIdx.x;
    int total = (K >> 3) * N;
    if (idx >= total) return;
    int koct = idx / N, n = idx % N;
    bf16x8 v;
    #pragma unroll
    for (int e = 0; e < 8; ++e)
        v[e] = f2bf(W[(size_t)(koct * 8 + e) * N + n]);
    *reinterpret_cast<bf16x8*>(Wb + (size_t)idx * 8) = v;
}

// ---------------------------------------------------------------------------
// MFMA GEMM: C[M,N] = act_in(A[M,K]) @ W + bias.  A f32 [M][K]; Wb swizzled bf16.
// Block 256 thr = 4 waves; block tile 32(M) x 128(N); wave: 16x64 (4 n-tiles).
template<bool RELU_IN>
__global__ __launch_bounds__(256) void mfma_gemm_bias_kernel(
    const float* __restrict__ A, const short* __restrict__ Wb,
    const float* __restrict__ bias, float* __restrict__ C,
    int M, int N, int K) {
    int tid = threadIdx.x;
    int lane = tid & 63, w = tid >> 6;
    int m0 = blockIdx.x * 32 + (w >> 1) * 16;
    int n0 = blockIdx.y * 128 + (w & 1) * 64;
    int lrow = lane & 15, lk = lane >> 4;       // lk in 0..3
    f32x4 acc[4] = {{0.f,0.f,0.f,0.f},{0.f,0.f,0.f,0.f},
                    {0.f,0.f,0.f,0.f},{0.f,0.f,0.f,0.f}};
    const float* arow = A + (size_t)(m0 + lrow) * K + lk * 8;
    for (int k0 = 0; k0 < K; k0 += 32) {
        f32x4 a0 = *reinterpret_cast<const f32x4*>(arow + k0);
        f32x4 a1 = *reinterpret_cast<const f32x4*>(arow + k0 + 4);
        bf16x8 af;
        #pragma unroll
        for (int e = 0; e < 4; ++e) {
            float v0 = a0[e], v1 = a1[e];
            if (RELU_IN) { v0 = fmaxf(v0, 0.f); v1 = fmaxf(v1, 0.f); }
            af[e] = f2bf(v0); af[4 + e] = f2bf(v1);
        }
        const short* bbase = Wb + ((size_t)((k0 >> 3) + lk) * N + n0 + lrow) * 8;
        #pragma unroll
        for (int nt = 0; nt < 4; ++nt) {
            bf16x8 bf = *reinterpret_cast<const bf16x8*>(bbase + nt * 128);
            acc[nt] = __builtin_amdgcn_mfma_f32_16x16x32_bf16(af, bf, acc[nt], 0, 0, 0);
        }
    }
    #pragma unroll
    for (int nt = 0; nt < 4; ++nt) {
        int col = n0 + nt * 16 + lrow;
        float bv = bias[col];
        #pragma unroll
        for (int r = 0; r < 4; ++r) {
            int row = m0 + lk * 4 + r;
            C[(size_t)row * N + col] = acc[nt][r] + bv;
        }
    }
}

// ---------------------------------------------------------------------------
// Small row-matmul: out[r, 0..255] = act_in(in[r, 0..K)) @ W[K,256] + b
template<bool RELU_IN>
__global__ __launch_bounds__(256) void rowmm_kernel(
    const float* __restrict__ in, const float* __restrict__ W,
    const float* __restrict__ bias, float* __restrict__ out, int K) {
    extern __shared__ float srow[];
    int r = blockIdx.x, d = threadIdx.x;
    for (int k = d; k < K; k += 256) {
        float v = in[(size_t)r * K + k];
        if (RELU_IN) v = fmaxf(v, 0.f);
        srow[k] = v;
    }
    __syncthreads();
    float acc = bias[d];
    for (int k = 0; k < K; ++k)
        acc = fmaf(srow[k], W[(size_t)k * DD + d], acc);
    out[(size_t)r * DD + d] = acc;
}

// y[b,i,:] = relu( sum_j adj[b,i,j] * t[b,j,:] )
__global__ __launch_bounds__(256) void adjmul_relu_kernel(
    const float* __restrict__ adj, const float* __restrict__ t,
    float* __restrict__ y) {
    int b = blockIdx.x / NK, i = blockIdx.x % NK, d = threadIdx.x;
    __shared__ float arow[NK];
    if (d < NK) arow[d] = adj[((size_t)b * NK + i) * NK + d];
    __syncthreads();
    float acc = 0.f;
    #pragma unroll 8
    for (int j = 0; j < NK; ++j)
        acc = fmaf(arow[j], t[((size_t)b * NK + j) * DD + d], acc);
    y[((size_t)b * NK + i) * DD + d] = fmaxf(acc, 0.f);
}

// ---------------------------------------------------------------------------
// inter[b,i,k] = sigmoid( qp[b,i,:] . qc[b,k,:] ); atomic add batch sum
__global__ __launch_bounds__(256) void inter_kernel(
    const float* __restrict__ qp, const float* __restrict__ qc,
    float* __restrict__ inter, float* __restrict__ interSum) {
    int b = blockIdx.x / 125, chunk = blockIdx.x % 125;
    __shared__ float qcT[DD * 57];   // [d][k], pad 57
    int tid = threadIdx.x;
    for (int l = tid; l < NK * DD; l += 256) {
        int k = l / DD, d = l % DD;
        qcT[d * 57 + k] = qc[((size_t)b * NK + k) * DD + d];
    }
    __syncthreads();
    int wave = tid >> 6, lane = tid & 63;
    __shared__ float wsum[4];
    float lsum = 0.f;
    for (int ii = 0; ii < 2; ++ii) {
        int i = chunk * 8 + wave * 2 + ii;
        const float* qrow = qp + ((size_t)b * NP + i) * DD;
        if (lane < NK) {
            float acc = 0.f;
            for (int d = 0; d < DD; ++d)
                acc = fmaf(qrow[d], qcT[d * 57 + lane], acc);
            float sg = 1.f / (1.f + __expf(-acc));
            inter[((size_t)b * NP + i) * NK + lane] = sg;
            lsum += sg;
        }
    }
    #pragma unroll
    for (int off = 32; off; off >>= 1) lsum += __shfl_down(lsum, off);
    if (lane == 0) wsum[wave] = lsum;
    __syncthreads();
    if (tid == 0)
        atomicAdd(&interSum[b], wsum[0] + wsum[1] + wsum[2] + wsum[3]);
}

__global__ void normalize_inter_kernel(float* inter, const float* interSum) {
    int idx = blockIdx.x * 256 + threadIdx.x;
    if (idx < B * NP * NK) inter[idx] /= interSum[idx / (NP * NK)];
}

// per-row stats: s[b,i]=sum_k inter^2 ; l1Sum[b]+=sum inter ; bindSum[b]+=sum (inter-lab)^2
__global__ __launch_bounds__(256) void inter_stats_kernel(
    const float* __restrict__ inter, const float* __restrict__ prot_inter,
    const float* __restrict__ exist, float* __restrict__ s_bi,
    float* __restrict__ l1Sum, float* __restrict__ bindSum) {
    int b = blockIdx.x / 4, q = blockIdx.x % 4;
    int i = q * 250 + threadIdx.x;
    float l1 = 0.f, bind = 0.f;
    if (threadIdx.x < 250) {
        float ex = exist[b];
        float ss = 0.f;
        const float* row  = inter      + ((size_t)b * NP + i) * NK;
        const float* prow = prot_inter + ((size_t)b * NP + i) * NK;
        #pragma unroll 8
        for (int k = 0; k < NK; ++k) {
            float v = row[k];
            l1 += v; ss = fmaf(v, v, ss);
            float d = v - ex * prow[k];
            bind = fmaf(d, d, bind);
        }
        s_bi[b * NP + i] = ss;
    }
    __shared__ float r1[256], r2[256];
    r1[threadIdx.x] = l1; r2[threadIdx.x] = bind;
    __syncthreads();
    for (int s = 128; s; s >>= 1) {
        if (threadIdx.x < s) {
            r1[threadIdx.x] += r1[threadIdx.x + s];
            r2[threadIdx.x] += r2[threadIdx.x + s];
        }
        __syncthreads();
    }
    if (threadIdx.x == 0) {
        atomicAdd(&l1Sum[b], r1[0]);
        atomicAdd(&bindSum[b], r2[0]);
    }
}

// ---------------------------------------------------------------------------
// cp partials v3: comp held in 56 VGPRs (no LDS in hot loop), clamp-free tanh:
//   t = 1 - 2*rcp(exp2(p*2*log2e*c) + 1)   (overflow self-correcting)
__global__ __launch_bounds__(128) void cp_partial_kernel(
    const float* __restrict__ prot, const float* __restrict__ comp,
    const float* __restrict__ inter, float* __restrict__ part) {
    int bc = blockIdx.x;
    int b = bc / 125, chunk = bc % 125;
    int dh = blockIdx.y;
    int tid = threadIdx.x;
    int d = dh * 128 + tid;
    __shared__ float irow[8][NK];
    float creg[NK];
    #pragma unroll
    for (int k = 0; k < NK; ++k)
        creg[k] = comp[((size_t)b * NK + k) * DD + d];
    for (int l = tid; l < 8 * NK; l += 128) {
        int ii = l / NK, k = l % NK;
        irow[ii][k] = inter[((size_t)b * NP + chunk * 8 + ii) * NK + k];
    }
    const float C2LOG2E = 2.8853900817779268f;   // 2*log2(e)
    float p2l[8];
    #pragma unroll
    for (int ii = 0; ii < 8; ++ii)
        p2l[ii] = C2LOG2E * prot[((size_t)b * NP + chunk * 8 + ii) * DD + d];
    __syncthreads();
    float acc0 = 0.f, acc1 = 0.f;
    #pragma unroll 1
    for (int ii = 0; ii < 8; ++ii) {
        float p = p2l[ii];
        #pragma unroll
        for (int k = 0; k < NK; k += 2) {
            float e0 = __builtin_amdgcn_exp2f(p * creg[k]);
            float e1 = __builtin_amdgcn_exp2f(p * creg[k + 1]);
            float r0 = __builtin_amdgcn_rcpf(e0 + 1.f);
            float r1 = __builtin_amdgcn_rcpf(e1 + 1.f);
            acc0 = fmaf(fmaf(-2.f, r0, 1.f), irow[ii][k],     acc0);
            acc1 = fmaf(fmaf(-2.f, r1, 1.f), irow[ii][k + 1], acc1);
        }
    }
    part[((size_t)b * 125 + chunk) * DD + d] = acc0 + acc1;
}

__global__ void cp_reduce_kernel(const float* part, float* cp) {
    int b = blockIdx.x, d = threadIdx.x;
    float s = 0.f;
    for (int c = 0; c < 125; ++c) s += part[((size_t)b * 125 + c) * DD + d];
    cp[b * DD + d] = s;
}

// ---------------------------------------------------------------------------
// conv(k=4,s=2,pad=1) + bias + leaky + maxpool4 -> pooled[b][2048]
__global__ __launch_bounds__(256) void conv_pool_kernel(
    const float* __restrict__ cp, const float* __restrict__ conv_w,
    const float* __restrict__ conv_b, float* __restrict__ pooled) {
    int b = blockIdx.x, t = threadIdx.x;
    __shared__ float x[258];
    __shared__ float convo[64 * 128];
    x[t + 1] = cp[b * DD + t];
    if (t == 0) { x[0] = 0.f; x[257] = 0.f; }
    __syncthreads();
    for (int l = t; l < 64 * 128; l += 256) {
        int o = l / 128, pos = l % 128;
        float acc = conv_b[o];
        int base = pos * 2;
        #pragma unroll
        for (int h = 0; h < 4; ++h)
            acc = fmaf(x[base + h], conv_w[o * 4 + h], acc);
        convo[l] = (acc > 0.f) ? acc : 0.1f * acc;
    }
    __syncthreads();
    for (int l = t; l < 64 * 32; l += 256) {
        int o = l / 32, p = l % 32;
        float m = -INFINITY;
        #pragma unroll
        for (int q = 0; q < 4; ++q)
            m = fmaxf(m, convo[o * 128 + p * 4 + q]);
        pooled[b * 2048 + l] = m;
    }
}

// ---------------------------------------------------------------------------
// FC partial: grid (o_tiles, k_splits), LDS-staged activations, atomic raw.
__global__ __launch_bounds__(256) void fc_partial_kernel(
    const float* __restrict__ in, const float* __restrict__ W,
    float* __restrict__ raw, int K, int N, int kchunk) {
    int t = threadIdx.x;
    int ol = t & 63;
    int o = blockIdx.x * 64 + ol;
    int w = t >> 6;
    int kbeg = blockIdx.y * kchunk;
    int kend = kbeg + kchunk; if (kend > K) kend = K;
    int len = kend - kbeg;
    __shared__ float sin_[B][128];   // kchunk <= 128
    for (int l = t; l < B * len; l += 256) {
        int b = l / len, k = l % len;
        sin_[b][k] = in[(size_t)b * K + kbeg + k];
    }
    __syncthreads();
    float acc[B];
    #pragma unroll
    for (int b = 0; b < B; ++b) acc[b] = 0.f;
    if (o < N) {
        for (int k = kbeg + w; k < kend; k += 4) {
            float wv = W[(size_t)k * N + o];
            int kl = k - kbeg;
            #pragma unroll
            for (int b = 0; b < B; ++b)
                acc[b] = fmaf(sin_[b][kl], wv, acc[b]);
        }
    }
    __shared__ float red[4][64][B];
    #pragma unroll
    for (int b = 0; b < B; ++b) red[w][ol][b] = acc[b];
    __syncthreads();
    for (int p = t; p < 64 * B; p += 256) {
        int oo = p / B, b = p % B;
        int o2 = blockIdx.x * 64 + oo;
        if (o2 < N) {
            float s = red[0][oo][b] + red[1][oo][b] + red[2][oo][b] + red[3][oo][b];
            atomicAdd(&raw[(size_t)b * N + o2], s);
        }
    }
}

template<bool LEAKY>
__global__ void fc_finish_kernel(const float* __restrict__ raw,
                                 const float* __restrict__ bias,
                                 float* __restrict__ out, int N) {
    int idx = blockIdx.x * 256 + threadIdx.x;
    if (idx < B * N) {
        int b = idx / N, o = idx % N;
        float s = raw[(size_t)b * N + o] + bias[o];
        if (LEAKY) s = (s > 0.f) ? s : 0.1f * s;
        out[(size_t)b * N + o] = s;
    }
}

// fc3: N=1, K=300. One block, 8 waves, wave = batch, shuffle reduce.
__global__ __launch_bounds__(512) void fc3_kernel(
    const float* __restrict__ in, const float* __restrict__ W,
    const float* __restrict__ bias, float* __restrict__ affn) {
    int wv = threadIdx.x >> 6, lane = threadIdx.x & 63;
    float acc = 0.f;
    for (int k = lane; k < 300; k += 64)
        acc = fmaf(in[(size_t)wv * 300 + k], W[k], acc);
    #pragma unroll
    for (int off = 32; off; off >>= 1) acc += __shfl_down(acc, off);
    if (lane == 0) affn[wv] = acc + bias[0];
}

// ---------------------------------------------------------------------------
// fused reg, cvt A: inter[b][i][j] -> iTb[i_oct][m=b*56+j][8] bf16, i pad 1024.
__global__ __launch_bounds__(256) void intercvt_kernel(
    const float* __restrict__ inter, short* __restrict__ iTb) {
    int idx = blockIdx.x * 256 + threadIdx.x;
    if (idx >= 128 * 448) return;
    int oct = idx / 448, m = idx % 448;
    int b = m / NK, j = m % NK;
    bf16x8 v;
    #pragma unroll
    for (int e = 0; e < 8; ++e) {
        int i = oct * 8 + e;
        float x = (i < NP) ? inter[((size_t)b * NP + i) * NK + j] : 0.f;
        v[e] = f2bf(x);
    }
    *reinterpret_cast<bf16x8*>(iTb + (size_t)idx * 8) = v;
}

// fused reg, cvt B: fused[t][i] -> fMb[i_oct][t][8] bf16, t pad 1024, i pad 1024.
__global__ __launch_bounds__(256) void fusedcvt_kernel(
    const float* __restrict__ fusedM, short* __restrict__ fMb) {
    int idx = blockIdx.x * 256 + threadIdx.x;
    if (idx >= 128 * 1024) return;
    int oct = idx >> 10, t = idx & 1023;
    bf16x8 v;
    #pragma unroll
    for (int e = 0; e < 8; ++e) {
        int i = oct * 8 + e;
        float x = (t < NT && i < NP) ? fusedM[(size_t)t * NP + i] : 0.f;
        v[e] = f2bf(x);
    }
    *reinterpret_cast<bf16x8*>(fMb + (size_t)idx * 8) = v;
}

// fused reg MFMA: E[m][t] = sum_i iT[m][i] fM[t][i]; fusedAbs[b] += sum |E|.
__global__ __launch_bounds__(256) void fused_mfma_abs_kernel(
    const short* __restrict__ iTb,   // [128][448][8]
    const short* __restrict__ fMb,   // [128][1024][8]
    float* __restrict__ fusedAbs) {
    __shared__ float sb[8];
    int tid = threadIdx.x;
    int lane = tid & 63, w = tid >> 6;
    if (tid < 8) sb[tid] = 0.f;
    __syncthreads();
    int m0 = blockIdx.x * 32 + (w >> 1) * 16;
    int n0 = blockIdx.y * 128 + (w & 1) * 64;
    int lrow = lane & 15, lk = lane >> 4;
    f32x4 acc[4] = {{0.f,0.f,0.f,0.f},{0.f,0.f,0.f,0.f},
                    {0.f,0.f,0.f,0.f},{0.f,0.f,0.f,0.f}};
    for (int koct0 = 0; koct0 < 128; koct0 += 4) {
        int koct = koct0 + lk;
        bf16x8 af = *reinterpret_cast<const bf16x8*>(
            iTb + ((size_t)koct * 448 + m0 + lrow) * 8);
        const short* bb = fMb + ((size_t)koct * 1024 + n0 + lrow) * 8;
        #pragma unroll
        for (int nt = 0; nt < 4; ++nt) {
            bf16x8 bf = *reinterpret_cast<const bf16x8*>(bb + nt * 128);
            acc[nt] = __builtin_amdgcn_mfma_f32_16x16x32_bf16(af, bf, acc[nt], 0, 0, 0);
        }
    }
    #pragma unroll
    for (int r = 0; r < 4; ++r) {
        float part = fabsf(acc[0][r]) + fabsf(acc[1][r]) +
                     fabsf(acc[2][r]) + fabsf(acc[3][r]);
        #pragma unroll
        for (int off = 1; off < 16; off <<= 1)
            part += __shfl_xor(part, off);
        if (lrow == 0) {
            int row = m0 + lk * 4 + r;
            atomicAdd(&sb[row / NK], part);
        }
    }
    __syncthreads();
    if (tid < 8 && sb[tid] != 0.f) atomicAdd(&fusedAbs[tid], sb[tid]);
}

// ---------------------------------------------------------------------------
// group: one wave per (b,k): g = contacts[b,k,:] . s[b,:], rs = row sum
__global__ __launch_bounds__(64) void group_kernel(
    const float* __restrict__ contacts, const float* __restrict__ s_bi,
    float* __restrict__ group_val) {
    int bk = blockIdx.x;
    int b = bk / NP, k = bk % NP;
    const float* row = contacts + ((size_t)b * NP + k) * NP;
    const float* sv = s_bi + b * NP;
    float g = 0.f, rs = 0.f;
    for (int i = threadIdx.x; i < NP; i += 64) {
        float c = row[i];
        g = fmaf(c, sv[i], g);
        rs += c;
    }
    #pragma unroll
    for (int off = 32; off; off >>= 1) {
        g += __shfl_down(g, off);
        rs += __shfl_down(rs, off);
    }
    if (threadIdx.x == 0) {
        if (g == 0.f) g += 1e10f;
        group_val[bk] = sqrtf(g) * sqrtf(rs);
    }
}

__global__ __launch_bounds__(256) void reduce1000_kernel(const float* in, float* out) {
    int b = blockIdx.x;
    float s = 0.f;
    for (int l = threadIdx.x; l < NP; l += 256) s += in[b * NP + l];
    __shared__ float r[256];
    r[threadIdx.x] = s;
    __syncthreads();
    for (int st = 128; st; st >>= 1) {
        if (threadIdx.x < st) r[threadIdx.x] += r[threadIdx.x + st];
        __syncthreads();
    }
    if (threadIdx.x == 0) out[b] = r[0];
}

// accums: [0..8)=interSum [8..16)=l1Sum [16..24)=bindSum [24..32)=fusedAbs [32..40)=groupReg
__global__ void final_kernel(const float* __restrict__ accums,
                             const float* __restrict__ affn,
                             const float* __restrict__ label,
                             float* __restrict__ out) {
    if (threadIdx.x == 0 && blockIdx.x == 0) {
        float l0 = 0.f, l1 = 0.f, l2 = 0.f;
        for (int b = 0; b < B; ++b) {
            l0 += accums[8 + b] + accums[24 + b] + accums[32 + b];
            l1 += sqrtf(accums[16 + b]);
            float d = affn[b] - label[b];
            l2 += d * d;
        }
        out[0] = (l0 + l1 + l2) * 0.125f;
    }
}

// ---------------------------------------------------------------------------
extern "C" void kernel_launch(void* const* d_in, const int* in_sizes, int n_in,
                              void* d_out, int out_size, void* d_ws, size_t ws_size,
                              hipStream_t stream) {
    const float* prot_data   = (const float*)d_in[0];
    const float* drug_ver    = (const float*)d_in[1];
    const float* drug_adj    = (const float*)d_in[2];
    const float* contacts    = (const float*)d_in[3];
    const float* prot_inter  = (const float*)d_in[4];
    const float* exist       = (const float*)d_in[5];
    const float* label       = (const float*)d_in[6];
    const float* fused       = (const float*)d_in[7];
    const float* W_prot      = (const float*)d_in[8];
    const float* b_prot      = (const float*)d_in[9];
    const float* gcn_W0      = (const float*)d_in[10];
    const float* gcn_b0      = (const float*)d_in[11];
    const float* gcn_W1      = (const float*)d_in[12];
    const float* gcn_b1      = (const float*)d_in[13];
    const float* gcn_W2      = (const float*)d_in[14];
    const float* gcn_b2      = (const float*)d_in[15];
    const float* gcn_Wf      = (const float*)d_in[16];
    const float* gcn_bf      = (const float*)d_in[17];
    const float* Wjp         = (const float*)d_in[18];
    const float* bjp         = (const float*)d_in[19];
    const float* Wjc         = (const float*)d_in[20];
    const float* bjc         = (const float*)d_in[21];
    const float* conv_w      = (const float*)d_in[22];
    const float* conv_b      = (const float*)d_in[23];
    const float* W_r1        = (const float*)d_in[24];
    const float* b_r1        = (const float*)d_in[25];
    const float* W_r2        = (const float*)d_in[26];
    const float* b_r2        = (const float*)d_in[27];
    const float* W_r3        = (const float*)d_in[28];
    const float* b_r3        = (const float*)d_in[29];

    float* ws = (float*)d_ws;
    size_t off = 0;
    auto alloc = [&](size_t n) { float* p = ws + off; off += n; return p; };
    float* prot     = alloc((size_t)B * NP * DD);   // 2,048,000
    float* qp       = alloc((size_t)B * NP * DD);   // 2,048,000
    float* tbuf     = alloc((size_t)B * NK * DD);
    float* ybuf     = alloc((size_t)B * NK * DD);
    float* comp     = alloc((size_t)B * NK * DD);
    float* qc       = alloc((size_t)B * NK * DD);
    float* inter    = alloc((size_t)B * NP * NK);   // 448,000
    float* s_bi     = alloc((size_t)B * NP);
    float* cp_part  = alloc((size_t)B * 125 * DD);  // 256,000
    float* cp       = alloc((size_t)B * DD);
    float* pooled   = alloc((size_t)B * 2048);
    float* fc1      = alloc((size_t)B * 600);
    float* fc2      = alloc((size_t)B * 300);
    float* affn     = alloc((size_t)B);
    float* groupv   = alloc((size_t)B * NP);
    // bf16 buffers (sizes in f32 units = shorts/2)
    short* Wb1      = (short*)alloc((DP / 8) * DD * 8 / 2);   // 96*256*8 shorts
    short* Wb2      = (short*)alloc((DD / 8) * DD * 8 / 2);   // 32*256*8 shorts
    short* fMb      = (short*)alloc((size_t)128 * 1024 * 8 / 2);
    // zero-region: accums, raw1, raw2 contiguous
    float* accums   = alloc(40);
    float* raw1     = alloc((size_t)B * 600);
    float* raw2     = alloc((size_t)B * 300);

    // iTb[128][448][8] bf16 aliases qp (dead after inter_kernel)
    short* iTb = (short*)qp;

    // zero the atomic-accumulated buffers (accums, raw1, raw2 contiguous)
    hipMemsetAsync(accums, 0,
        (40 + (size_t)B * 600 + (size_t)B * 300) * sizeof(float), stream);

    // weight / fused-matrix bf16 pre-conversion (independent of everything)
    wcvt_kernel<<<(DP / 8 * DD + 255) / 256, 256, 0, stream>>>(W_prot, Wb1, DP, DD);
    wcvt_kernel<<<(DD / 8 * DD + 255) / 256, 256, 0, stream>>>(Wjp, Wb2, DD, DD);
    fusedcvt_kernel<<<512, 256, 0, stream>>>(fused, fMb);

    // prot = prot_data @ W_prot + b_prot   (bf16 MFMA)
    mfma_gemm_bias_kernel<false><<<dim3(250, 2), 256, 0, stream>>>(
        prot_data, Wb1, b_prot, prot, B * NP, DD, DP);

    // GCN stack
    rowmm_kernel<false><<<B * NK, 256, DV * sizeof(float), stream>>>(drug_ver, gcn_W0, gcn_b0, tbuf, DV);
    adjmul_relu_kernel<<<B * NK, 256, 0, stream>>>(drug_adj, tbuf, ybuf);
    rowmm_kernel<false><<<B * NK, 256, DD * sizeof(float), stream>>>(ybuf, gcn_W1, gcn_b1, tbuf, DD);
    adjmul_relu_kernel<<<B * NK, 256, 0, stream>>>(drug_adj, tbuf, ybuf);
    rowmm_kernel<false><<<B * NK, 256, DD * sizeof(float), stream>>>(ybuf, gcn_W2, gcn_b2, tbuf, DD);
    adjmul_relu_kernel<<<B * NK, 256, 0, stream>>>(drug_adj, tbuf, ybuf);
    rowmm_kernel<false><<<B * NK, 256, DD * sizeof(float), stream>>>(ybuf, gcn_Wf, gcn_bf, comp, DD);
    rowmm_kernel<true ><<<B * NK, 256, DD * sizeof(float), stream>>>(comp, Wjc, bjc, qc, DD);

    // qp = relu(prot) @ Wjp + bjp   (bf16 MFMA, relu folded into A load)
    mfma_gemm_bias_kernel<true><<<dim3(250, 2), 256, 0, stream>>>(
        prot, Wb2, bjp, qp, B * NP, DD, DD);

    // inter + normalization  (last use of qp)
    inter_kernel<<<B * 125, 256, 0, stream>>>(qp, qc, inter, accums + 0);
    normalize_inter_kernel<<<(B * NP * NK + 255) / 256, 256, 0, stream>>>(inter, accums + 0);
    inter_stats_kernel<<<B * 4, 256, 0, stream>>>(inter, prot_inter, exist, s_bi,
                                                  accums + 8, accums + 16);

    // cp contraction (last use of prot)
    cp_partial_kernel<<<dim3(B * 125, 2), 128, 0, stream>>>(prot, comp, inter, cp_part);
    cp_reduce_kernel<<<B, 256, 0, stream>>>(cp_part, cp);

    // fused regularizer: cvt inter (into dead qp) -> MFMA + abs reduce
    intercvt_kernel<<<(128 * 448 + 255) / 256, 256, 0, stream>>>(inter, iTb);
    fused_mfma_abs_kernel<<<dim3(14, 8), 256, 0, stream>>>(iTb, fMb, accums + 24);

    // conv / pool / FCs
    conv_pool_kernel<<<B, 256, 0, stream>>>(cp, conv_w, conv_b, pooled);
    fc_partial_kernel<<<dim3(10, 16), 256, 0, stream>>>(pooled, W_r1, raw1, 2048, 600, 128);
    fc_finish_kernel<true><<<(B * 600 + 255) / 256, 256, 0, stream>>>(raw1, b_r1, fc1, 600);
    fc_partial_kernel<<<dim3(5, 8), 256, 0, stream>>>(fc1, W_r2, raw2, 600, 300, 75);
    fc_finish_kernel<true><<<(B * 300 + 255) / 256, 256, 0, stream>>>(raw2, b_r2, fc2, 300);
    fc3_kernel<<<1, 512, 0, stream>>>(fc2, W_r3, b_r3, affn);

    // group regularizer
    group_kernel<<<B * NP, 64, 0, stream>>>(contacts, s_bi, groupv);
    reduce1000_kernel<<<B, 256, 0, stream>>>(groupv, accums + 32);

    // final loss
    final_kernel<<<1, 64, 0, stream>>>(accums, affn, label, (float*)d_out);
}